// Round 1
// baseline (2301.186 us; speedup 1.0000x reference)
//
#include <hip/hip_runtime.h>

#define B_SZ   8
#define N_ANC  36864
#define NPAD   65536
#define N_PRE  12000
#define N_POST 2000
#define TILE   8192

// ---------------- Kernel 1: decode + score + sort keys ------------------
__global__ __launch_bounds__(256) void k_decode(
    const int* __restrict__ imh_p, const int* __restrict__ imw_p,
    const float* __restrict__ anchors, const float* __restrict__ loc,
    const float* __restrict__ obj, float4* __restrict__ boxes,
    unsigned long long* __restrict__ keys)
{
  int n = blockIdx.x * 256 + threadIdx.x;
  int b = blockIdx.y;
  if (n >= N_ANC) {
    if (n < NPAD) keys[(size_t)b * NPAD + n] = ~0ull;  // pad: sorts last
    return;
  }
  float a0 = anchors[n * 4 + 0], a1 = anchors[n * 4 + 1];
  float a2 = anchors[n * 4 + 2], a3 = anchors[n * 4 + 3];
  size_t off = (size_t)b * N_ANC + n;
  float l0 = loc[off * 4 + 0], l1 = loc[off * 4 + 1];
  float l2 = loc[off * 4 + 2], l3 = loc[off * 4 + 3];

  // Exact replication of reference decode: no FMA contraction.
  float w  = __fsub_rn(a2, a0);
  float h  = __fsub_rn(a3, a1);
  float cx = __fadd_rn(a0, __fmul_rn(0.5f, w));
  float cy = __fadd_rn(a1, __fmul_rn(0.5f, h));
  float pcx = __fadd_rn(__fmul_rn(l0, w), cx);
  float pcy = __fadd_rn(__fmul_rn(l1, h), cy);
  float pw  = __fmul_rn(expf(l2), w);
  float ph  = __fmul_rn(expf(l3), h);
  float imw = (float)imw_p[0], imh = (float)imh_p[0];
  float hx = __fmul_rn(0.5f, pw), hy = __fmul_rn(0.5f, ph);
  float x1 = fminf(fmaxf(__fsub_rn(pcx, hx), 0.0f), imw);
  float y1 = fminf(fmaxf(__fsub_rn(pcy, hy), 0.0f), imh);
  float x2 = fminf(fmaxf(__fadd_rn(pcx, hx), 0.0f), imw);
  float y2 = fminf(fmaxf(__fadd_rn(pcy, hy), 0.0f), imh);
  boxes[off] = make_float4(x1, y1, x2, y2);

  bool valid = (__fsub_rn(x2, x1) >= 16.0f) && (__fsub_rn(y2, y1) >= 16.0f);

  // softmax(axis=2)[...,1] exactly like jax.nn.softmax: max-subtract, exp, div
  float o0 = obj[off * 2 + 0], o1 = obj[off * 2 + 1];
  float m  = fmaxf(o0, o1);
  float e0 = expf(__fsub_rn(o0, m));
  float e1 = expf(__fsub_rn(o1, m));
  float s  = e1 / __fadd_rn(e0, e1);
  float sc = valid ? s : -1e9f;

  unsigned u  = __float_as_uint(sc);
  unsigned fk = (u & 0x80000000u) ? ~u : (u | 0x80000000u);  // monotone map
  unsigned sk = ~fk;                                         // ascending == score desc
  keys[(size_t)b * NPAD + n] = ((unsigned long long)sk << 32) | (unsigned)n;
}

// ---------------- Kernel 2: per-batch bitonic sort (1 block/batch) ------
__global__ __launch_bounds__(1024) void k_sort(unsigned long long* __restrict__ keys)
{
  int b = blockIdx.x;
  unsigned long long* a = keys + (size_t)b * NPAD;
  __shared__ unsigned long long lds[TILE];  // 64 KiB

  // Phase 1: fully sort each 8192 tile in LDS (stages k = 2..TILE)
  for (int tile = 0; tile < NPAD / TILE; ++tile) {
    int base = tile * TILE;
    if (base >= N_ANC) continue;  // all-pad tiles are already "sorted" (equal keys)
    for (int i = threadIdx.x; i < TILE; i += 1024) lds[i] = a[base + i];
    __syncthreads();
    for (int k = 2; k <= TILE; k <<= 1) {
      for (int j = k >> 1; j > 0; j >>= 1) {
        for (int p = threadIdx.x; p < TILE / 2; p += 1024) {
          int i = ((p & ~(j - 1)) << 1) | (p & (j - 1));
          int l = i | j;
          bool asc = (((base + i) & k) == 0);
          unsigned long long x = lds[i], y = lds[l];
          if ((x > y) == asc) { lds[i] = y; lds[l] = x; }
        }
        __syncthreads();
      }
    }
    for (int i = threadIdx.x; i < TILE; i += 1024) a[base + i] = lds[i];
    __syncthreads();
  }

  // Phase 2: stages k = 2*TILE .. NPAD
  for (int k = TILE << 1; k <= NPAD; k <<= 1) {
    // global passes (stride >= TILE)
    for (int j = k >> 1; j >= TILE; j >>= 1) {
      for (int p = threadIdx.x; p < NPAD / 2; p += 1024) {
        int i = ((p & ~(j - 1)) << 1) | (p & (j - 1));
        int l = i | j;
        bool asc = ((i & k) == 0);
        unsigned long long x = a[i], y = a[l];
        if ((x > y) == asc) { a[i] = y; a[l] = x; }
      }
      __syncthreads();
    }
    // LDS-fused passes (stride < TILE), per tile
    for (int tile = 0; tile < NPAD / TILE; ++tile) {
      int base = tile * TILE;
      for (int i = threadIdx.x; i < TILE; i += 1024) lds[i] = a[base + i];
      __syncthreads();
      for (int j = TILE >> 1; j > 0; j >>= 1) {
        for (int p = threadIdx.x; p < TILE / 2; p += 1024) {
          int i = ((p & ~(j - 1)) << 1) | (p & (j - 1));
          int l = i | j;
          bool asc = (((base + i) & k) == 0);
          unsigned long long x = lds[i], y = lds[l];
          if ((x > y) == asc) { lds[i] = y; lds[l] = x; }
        }
        __syncthreads();
      }
      for (int i = threadIdx.x; i < TILE; i += 1024) a[base + i] = lds[i];
      __syncthreads();
    }
  }
}

// ---------------- Kernel 3: per-batch chunked greedy NMS ----------------
__device__ __forceinline__ bool iou_gt(float4 p, float4 q)
{
  // bitwise-exact replication of _iou_one_vs_all + (> 0.7)
  float ix1 = fmaxf(p.x, q.x), iy1 = fmaxf(p.y, q.y);
  float ix2 = fminf(p.z, q.z), iy2 = fminf(p.w, q.w);
  float iw = fmaxf(__fsub_rn(ix2, ix1), 0.0f);
  float ih = fmaxf(__fsub_rn(iy2, iy1), 0.0f);
  float inter = __fmul_rn(iw, ih);
  float a0 = __fmul_rn(__fsub_rn(p.z, p.x), __fsub_rn(p.w, p.y));
  float a1 = __fmul_rn(__fsub_rn(q.z, q.x), __fsub_rn(q.w, q.y));
  float den = fmaxf(__fsub_rn(__fadd_rn(a0, a1), inter), 1e-9f);
  return (inter / den) > 0.7f;
}

__global__ __launch_bounds__(1024) void k_nms(
    const unsigned long long* __restrict__ keys,
    const float4* __restrict__ boxes, float* __restrict__ out)
{
  int b = blockIdx.x;
  const unsigned long long* kb = keys + (size_t)b * NPAD;
  const float4* bb = boxes + (size_t)b * N_ANC;
  float* ob = out + (size_t)b * N_POST * 4;
  float* om = out + (size_t)B_SZ * N_POST * 4 + (size_t)b * N_POST;

  __shared__ float4 kept[N_POST];     // 32 KiB
  __shared__ float4 cbox[256];        // 4 KiB
  __shared__ unsigned srow[256 * 8];  // 8 KiB: c-suppresses-j bits (j>c)
  __shared__ unsigned alive[256];
  __shared__ int s_nkept, s_done, s_exh;

  if (threadIdx.x == 0) { s_nkept = 0; s_done = 0; }

  for (int cbase = 0; cbase < N_PRE; cbase += 256) {
    if (threadIdx.x == 0) s_exh = 0;
    __syncthreads();
    if (s_done) break;
    int cnum = min(256, N_PRE - cbase);
    int t = threadIdx.x;
    if (t < 256) {
      float4 bx = make_float4(0.f, 0.f, 0.f, 0.f);
      unsigned v = 0;
      if (t < cnum) {
        unsigned long long kk = kb[cbase + t];
        if ((unsigned)(kk >> 32) < 0x80000000u) {  // valid (score >= 0)
          bx = bb[(unsigned)kk];
          v = 1;
        } else {
          s_exh = 1;  // sorted: nothing valid after this chunk
        }
      }
      cbox[t] = bx;
      alive[t] = v;
#pragma unroll
      for (int wq = 0; wq < 8; ++wq) srow[t * 8 + wq] = 0;
    }
    __syncthreads();

    // cross-suppression vs already-kept boxes (wave-broadcast kept reads)
    int nk = s_nkept;
    int c = threadIdx.x & 255, sl = threadIdx.x >> 8;
    float4 my = cbox[c];
    if (alive[c] && nk > 0) {
      bool sup = false;
      for (int k = sl; k < nk; k += 4) {
        if (iou_gt(kept[k], my)) { sup = true; break; }
      }
      if (sup) alive[c] = 0;  // benign race: all writers store 0
    }
    __syncthreads();

    // intra-chunk pairwise suppression bits
    for (int pp = threadIdx.x; pp < 256 * 256; pp += 1024) {
      int ci = pp >> 8, j = pp & 255;
      if (j > ci && j < cnum && alive[ci] && alive[j]) {
        if (iou_gt(cbox[ci], cbox[j]))
          atomicOr(&srow[ci * 8 + (j >> 5)], 1u << (j & 31));
      }
    }
    __syncthreads();

    // sequential resolve (thread 0, all-LDS)
    if (threadIdx.x == 0) {
      unsigned remw[8] = {0, 0, 0, 0, 0, 0, 0, 0};
      int nkept = s_nkept;
      for (int cc = 0; cc < cnum; ++cc) {
        if (!alive[cc]) continue;
        if (remw[cc >> 5] & (1u << (cc & 31))) continue;
        kept[nkept] = cbox[cc];
        ++nkept;
        if (nkept == N_POST) { s_done = 1; break; }
#pragma unroll
        for (int wq = 0; wq < 8; ++wq) remw[wq] |= srow[cc * 8 + wq];
      }
      s_nkept = nkept;
      if (s_exh) s_done = 1;
    }
  }
  __syncthreads();

  int nk = s_nkept;
  float4 zero = make_float4(0.f, 0.f, 0.f, 0.f);
  for (int i = threadIdx.x; i < N_POST; i += 1024)
    ((float4*)ob)[i] = (i < nk) ? kept[i] : zero;
  for (int i = threadIdx.x; i < N_POST; i += 1024)
    om[i] = (i < nk) ? 1.0f : 0.0f;
}

extern "C" void kernel_launch(void* const* d_in, const int* in_sizes, int n_in,
                              void* d_out, int out_size, void* d_ws, size_t ws_size,
                              hipStream_t stream)
{
  const int*   imh     = (const int*)d_in[0];
  const int*   imw     = (const int*)d_in[1];
  const float* anchors = (const float*)d_in[2];
  const float* loc     = (const float*)d_in[3];
  const float* obj     = (const float*)d_in[4];
  float* out = (float*)d_out;

  float4* boxes = (float4*)d_ws;  // B*N float4 = 4,718,592 B
  unsigned long long* keys =
      (unsigned long long*)((char*)d_ws + (size_t)B_SZ * N_ANC * 16);  // 4 MiB

  dim3 g1(NPAD / 256, B_SZ);
  k_decode<<<g1, 256, 0, stream>>>(imh, imw, anchors, loc, obj, boxes, keys);
  k_sort<<<B_SZ, 1024, 0, stream>>>(keys);
  k_nms<<<B_SZ, 1024, 0, stream>>>(keys, boxes, out);
}

// Round 2
// 1842.360 us; speedup vs baseline: 1.2490x; 1.2490x over previous
//
#include <hip/hip_runtime.h>

typedef unsigned long long u64;

#define B_SZ   8
#define N_ANC  36864
#define NPAD   65536
#define N_PRE  12000
#define N_POST 2000
#define TILE   8192
#define MAXC   12032   // N_PRE rounded up to 64

__device__ __forceinline__ u64 shfl64(u64 v, int src) {
  int lo = __shfl((int)(unsigned)(v & 0xffffffffull), src, 64);
  int hi = __shfl((int)(unsigned)(v >> 32), src, 64);
  return ((u64)(unsigned)hi << 32) | (unsigned)lo;
}

// ---------------- Kernel 1: decode + score + sort keys ------------------
__global__ __launch_bounds__(256) void k_decode(
    const int* __restrict__ imh_p, const int* __restrict__ imw_p,
    const float* __restrict__ anchors, const float* __restrict__ loc,
    const float* __restrict__ obj, float4* __restrict__ boxes,
    u64* __restrict__ keys, int* __restrict__ meta)
{
  if (blockIdx.x == 0 && blockIdx.y == 0 && threadIdx.x < B_SZ) {
    meta[threadIdx.x * 4 + 0] = N_PRE;  // n_valid (atomicMin'd by gather)
    meta[threadIdx.x * 4 + 1] = 0;      // n_kept
  }
  int n = blockIdx.x * 256 + threadIdx.x;
  int b = blockIdx.y;
  if (n >= N_ANC) {
    if (n < NPAD) keys[(size_t)b * NPAD + n] = ~0ull;  // pad: sorts last
    return;
  }
  float a0 = anchors[n * 4 + 0], a1 = anchors[n * 4 + 1];
  float a2 = anchors[n * 4 + 2], a3 = anchors[n * 4 + 3];
  size_t off = (size_t)b * N_ANC + n;
  float l0 = loc[off * 4 + 0], l1 = loc[off * 4 + 1];
  float l2 = loc[off * 4 + 2], l3 = loc[off * 4 + 3];

  // Exact replication of reference decode: no FMA contraction.
  float w  = __fsub_rn(a2, a0);
  float h  = __fsub_rn(a3, a1);
  float cx = __fadd_rn(a0, __fmul_rn(0.5f, w));
  float cy = __fadd_rn(a1, __fmul_rn(0.5f, h));
  float pcx = __fadd_rn(__fmul_rn(l0, w), cx);
  float pcy = __fadd_rn(__fmul_rn(l1, h), cy);
  float pw  = __fmul_rn(expf(l2), w);
  float ph  = __fmul_rn(expf(l3), h);
  float imw = (float)imw_p[0], imh = (float)imh_p[0];
  float hx = __fmul_rn(0.5f, pw), hy = __fmul_rn(0.5f, ph);
  float x1 = fminf(fmaxf(__fsub_rn(pcx, hx), 0.0f), imw);
  float y1 = fminf(fmaxf(__fsub_rn(pcy, hy), 0.0f), imh);
  float x2 = fminf(fmaxf(__fadd_rn(pcx, hx), 0.0f), imw);
  float y2 = fminf(fmaxf(__fadd_rn(pcy, hy), 0.0f), imh);
  boxes[off] = make_float4(x1, y1, x2, y2);

  bool valid = (__fsub_rn(x2, x1) >= 16.0f) && (__fsub_rn(y2, y1) >= 16.0f);

  float o0 = obj[off * 2 + 0], o1 = obj[off * 2 + 1];
  float m  = fmaxf(o0, o1);
  float e0 = expf(__fsub_rn(o0, m));
  float e1 = expf(__fsub_rn(o1, m));
  float s  = e1 / __fadd_rn(e0, e1);
  float sc = valid ? s : -1e9f;

  unsigned u  = __float_as_uint(sc);
  unsigned fk = (u & 0x80000000u) ? ~u : (u | 0x80000000u);
  unsigned sk = ~fk;  // ascending u64 == descending score, stable by index
  keys[(size_t)b * NPAD + n] = ((u64)sk << 32) | (unsigned)n;
}

// ---------------- Sort: multi-block bitonic -----------------------------
__global__ __launch_bounds__(1024) void k_sort_tile(u64* __restrict__ keys)
{
  int b = blockIdx.y, t = blockIdx.x, base = t * TILE;
  u64* a = keys + (size_t)b * NPAD;
  __shared__ u64 lds[TILE];
  for (int i = threadIdx.x; i < TILE; i += 1024) lds[i] = a[base + i];
  __syncthreads();
  for (int k = 2; k <= TILE; k <<= 1) {
    for (int j = k >> 1; j > 0; j >>= 1) {
      for (int p = threadIdx.x; p < TILE / 2; p += 1024) {
        int i = ((p & ~(j - 1)) << 1) | (p & (j - 1));
        int l = i | j;
        bool asc = (((base + i) & k) == 0);
        u64 x = lds[i], y = lds[l];
        if ((x > y) == asc) { lds[i] = y; lds[l] = x; }
      }
      __syncthreads();
    }
  }
  for (int i = threadIdx.x; i < TILE; i += 1024) a[base + i] = lds[i];
}

__global__ __launch_bounds__(256) void k_sort_pass(u64* __restrict__ keys, int k, int j)
{
  int b = blockIdx.y;
  int p = blockIdx.x * 256 + threadIdx.x;
  int i = ((p & ~(j - 1)) << 1) | (p & (j - 1));
  int l = i | j;
  bool asc = ((i & k) == 0);
  u64* a = keys + (size_t)b * NPAD;
  u64 x = a[i], y = a[l];
  if ((x > y) == asc) { a[i] = y; a[l] = x; }
}

__global__ __launch_bounds__(1024) void k_sort_local(u64* __restrict__ keys, int k)
{
  int b = blockIdx.y, base = blockIdx.x * TILE;
  u64* a = keys + (size_t)b * NPAD;
  __shared__ u64 lds[TILE];
  for (int i = threadIdx.x; i < TILE; i += 1024) lds[i] = a[base + i];
  __syncthreads();
  for (int j = TILE >> 1; j > 0; j >>= 1) {
    for (int p = threadIdx.x; p < TILE / 2; p += 1024) {
      int i = ((p & ~(j - 1)) << 1) | (p & (j - 1));
      int l = i | j;
      bool asc = (((base + i) & k) == 0);
      u64 x = lds[i], y = lds[l];
      if ((x > y) == asc) { lds[i] = y; lds[l] = x; }
    }
    __syncthreads();
  }
  for (int i = threadIdx.x; i < TILE; i += 1024) a[base + i] = lds[i];
}

// ---------------- Gather sorted candidate boxes -------------------------
__global__ __launch_bounds__(256) void k_gather(
    const u64* __restrict__ keys, const float4* __restrict__ boxes,
    float4* __restrict__ gbox, int* __restrict__ meta)
{
  int i = blockIdx.x * 256 + threadIdx.x;  // [0, MAXC)
  int b = blockIdx.y;
  u64 k = keys[(size_t)b * NPAD + i];
  unsigned idx = (unsigned)k;
  unsigned sk  = (unsigned)(k >> 32);
  bool valid = sk < 0x80000000u;  // score >= 0 (softmax output)
  float4 bx = make_float4(0.f, 0.f, 0.f, 0.f);
  if (valid) bx = boxes[(size_t)b * N_ANC + idx];
  gbox[(size_t)b * MAXC + i] = bx;
  if (i < N_PRE && !valid) atomicMin(&meta[b * 4 + 0], i);
}

// ---------------- IoU (bit-exact vs reference) --------------------------
__device__ __forceinline__ bool iou_gt(float4 p, float4 q)
{
  float ix1 = fmaxf(p.x, q.x), iy1 = fmaxf(p.y, q.y);
  float ix2 = fminf(p.z, q.z), iy2 = fminf(p.w, q.w);
  float iw = fmaxf(__fsub_rn(ix2, ix1), 0.0f);
  float ih = fmaxf(__fsub_rn(iy2, iy1), 0.0f);
  float inter = __fmul_rn(iw, ih);
  float a0 = __fmul_rn(__fsub_rn(p.z, p.x), __fsub_rn(p.w, p.y));
  float a1 = __fmul_rn(__fsub_rn(q.z, q.x), __fsub_rn(q.w, q.y));
  float den = fmaxf(__fsub_rn(__fadd_rn(a0, a1), inter), 1e-9f);
  return (inter / den) > 0.7f;
}

// ---------------- Suppression bitmask (all-pairs, triangular) -----------
__global__ __launch_bounds__(256) void k_mask(
    const float4* __restrict__ gbox, const int* __restrict__ meta,
    u64* __restrict__ mask, int nmat)
{
  int b = blockIdx.y;
  int rb = blockIdx.x;           // rows rb*64 .. rb*64+63
  int nv = min(meta[b * 4 + 0], N_PRE);
  int rbase = rb * 64;
  if (rbase >= nv) return;
  int nw = nmat >> 6;
  int cl = min(nv, nmat);        // col limit
  const float4* gb = gbox + (size_t)b * MAXC;
  u64* mrow = mask + (size_t)b * nmat * nw;
  __shared__ float4 rbox[64];
  if (threadIdx.x < 64) rbox[threadIdx.x] = gb[rbase + threadIdx.x];
  __syncthreads();
  int wave = threadIdx.x >> 6, lane = threadIdx.x & 63;
  for (int cw = rb; cw < nw; ++cw) {
    if (cw * 64 >= cl) break;
    int c = cw * 64 + lane;
    float4 cb = gb[c];
    bool cv = (c < cl);
    for (int rr = wave; rr < 64; rr += 4) {
      int r = rbase + rr;
      bool p = cv && (c > r) && iou_gt(rbox[rr], cb);
      u64 m = __ballot(p);
      if (lane == 0) mrow[(size_t)r * nw + cw] = m;
    }
  }
}

// ---------------- Serial greedy walk over bitmask (1 wave/batch) --------
__global__ __launch_bounds__(64) void k_walk(
    const float4* __restrict__ gbox, const u64* __restrict__ mask,
    int* __restrict__ meta, float4* __restrict__ kept, int nmat)
{
  int b = blockIdx.x, lane = threadIdx.x;
  int nv = min(meta[b * 4 + 0], N_PRE);
  int nw = nmat >> 6, ng = nw;
  const u64* mb = mask + (size_t)b * nmat * nw;
  const float4* gb = gbox + (size_t)b * MAXC;
  float4* kb = kept + (size_t)b * N_POST;
  u64 rem0 = 0, rem1 = 0, rem2 = 0;  // lane owns words lane, lane+64, lane+128
  int nkept = 0;
  for (int g = 0; g < ng; ++g) {
    int gbase = g << 6;
    if (gbase >= nv || nkept >= N_POST) break;
    u64 intra = mb[(size_t)(gbase + lane) * nw + g];
    u64 rsel = (g < 64) ? rem0 : (g < 128) ? rem1 : rem2;
    u64 rg = shfl64(rsel, g & 63);
    u64 keptm = 0;
    int lim = min(64, nv - gbase);
    for (int ii = 0; ii < lim; ++ii) {
      if ((rg >> ii) & 1) continue;
      keptm |= (1ull << ii);
      ++nkept;
      if (nkept >= N_POST) break;
      rg |= shfl64(intra, ii);
    }
    if ((keptm >> lane) & 1) {
      int pos = (nkept - __popcll(keptm)) + __popcll(keptm & ((1ull << lane) - 1ull));
      kb[pos] = gb[gbase + lane];
    }
    u64 km = keptm;
    while (km) {
      int i0 = __ffsll(km) - 1; km &= km - 1;
      int i1 = i0; bool h1 = (km != 0);
      if (h1) { i1 = __ffsll(km) - 1; km &= km - 1; }
      const u64* r0 = mb + (size_t)(gbase + i0) * nw;
      const u64* r1 = mb + (size_t)(gbase + i1) * nw;
      u64 a0 = 0, a1 = 0, a2 = 0, b0 = 0, b1 = 0, b2 = 0;
      if (lane < nw)        { a0 = r0[lane];        if (h1) b0 = r1[lane]; }
      if (lane + 64 < nw)   { a1 = r0[lane + 64];   if (h1) b1 = r1[lane + 64]; }
      if (lane + 128 < nw)  { a2 = r0[lane + 128];  if (h1) b2 = r1[lane + 128]; }
      rem0 |= a0 | b0; rem1 |= a1 | b1; rem2 |= a2 | b2;
    }
  }
  if (lane == 0) meta[b * 4 + 1] = nkept;
}

// ---------------- Tail: chunked greedy for candidates >= nmat -----------
__global__ __launch_bounds__(1024) void k_tail(
    const float4* __restrict__ gbox, int* __restrict__ meta,
    float4* __restrict__ keptg, int nmat)
{
  int b = blockIdx.x;
  int nv = min(meta[b * 4 + 0], N_PRE);
  int nkept0 = meta[b * 4 + 1];
  if (nkept0 >= N_POST || nv <= nmat) return;

  const float4* gb = gbox + (size_t)b * MAXC;
  float4* kg = keptg + (size_t)b * N_POST;

  __shared__ float4 kept[N_POST];     // 32 KiB
  __shared__ float4 cbox[256];
  __shared__ unsigned srow[256 * 8];
  __shared__ unsigned alive[256];
  __shared__ int s_nkept, s_done;

  for (int i = threadIdx.x; i < nkept0; i += 1024) kept[i] = kg[i];
  if (threadIdx.x == 0) { s_nkept = nkept0; s_done = 0; }
  __syncthreads();

  for (int cbase = nmat; cbase < nv; cbase += 256) {
    if (s_done) break;
    int cnum = min(256, nv - cbase);
    int t = threadIdx.x;
    if (t < 256) {
      cbox[t] = (t < cnum) ? gb[cbase + t] : make_float4(0.f, 0.f, 0.f, 0.f);
      alive[t] = (t < cnum) ? 1u : 0u;
#pragma unroll
      for (int wq = 0; wq < 8; ++wq) srow[t * 8 + wq] = 0;
    }
    __syncthreads();

    int nk = s_nkept;
    int c = threadIdx.x & 255, sl = threadIdx.x >> 8;
    float4 my = cbox[c];
    if (alive[c] && nk > 0) {
      bool sup = false;
      for (int k = sl; k < nk; k += 4) {
        if (iou_gt(kept[k], my)) { sup = true; break; }
      }
      if (sup) alive[c] = 0;
    }
    __syncthreads();

    for (int pp = threadIdx.x; pp < 256 * 256; pp += 1024) {
      int ci = pp >> 8, j = pp & 255;
      if (j > ci && j < cnum && alive[ci] && alive[j]) {
        if (iou_gt(cbox[ci], cbox[j]))
          atomicOr(&srow[ci * 8 + (j >> 5)], 1u << (j & 31));
      }
    }
    __syncthreads();

    if (threadIdx.x == 0) {
      unsigned remw[8] = {0, 0, 0, 0, 0, 0, 0, 0};
      int nkept = s_nkept;
      for (int cc = 0; cc < cnum; ++cc) {
        if (!alive[cc]) continue;
        if (remw[cc >> 5] & (1u << (cc & 31))) continue;
        kept[nkept] = cbox[cc];
        ++nkept;
        if (nkept == N_POST) { s_done = 1; break; }
#pragma unroll
        for (int wq = 0; wq < 8; ++wq) remw[wq] |= srow[cc * 8 + wq];
      }
      s_nkept = nkept;
    }
    __syncthreads();
  }
  __syncthreads();
  int nk = s_nkept;
  for (int i = threadIdx.x; i < nk; i += 1024) kg[i] = kept[i];
  if (threadIdx.x == 0) meta[b * 4 + 1] = nk;
}

// ---------------- Output ------------------------------------------------
__global__ __launch_bounds__(256) void k_out(
    const float4* __restrict__ kept, const int* __restrict__ meta,
    float* __restrict__ out)
{
  int i = blockIdx.x * 256 + threadIdx.x;
  int b = blockIdx.y;
  if (i >= N_POST) return;
  int nk = meta[b * 4 + 1];
  float4 v = (i < nk) ? kept[(size_t)b * N_POST + i]
                      : make_float4(0.f, 0.f, 0.f, 0.f);
  ((float4*)(out + (size_t)b * N_POST * 4))[i] = v;
  out[(size_t)B_SZ * N_POST * 4 + (size_t)b * N_POST + i] = (i < nk) ? 1.0f : 0.0f;
}

extern "C" void kernel_launch(void* const* d_in, const int* in_sizes, int n_in,
                              void* d_out, int out_size, void* d_ws, size_t ws_size,
                              hipStream_t stream)
{
  const int*   imh     = (const int*)d_in[0];
  const int*   imw     = (const int*)d_in[1];
  const float* anchors = (const float*)d_in[2];
  const float* loc     = (const float*)d_in[3];
  const float* obj     = (const float*)d_in[4];
  float* out = (float*)d_out;

  char* ws = (char*)d_ws;
  size_t off_boxes = 0;
  size_t off_keys  = off_boxes + (size_t)B_SZ * N_ANC * 16;   // 4,718,592
  size_t off_gbox  = off_keys  + (size_t)B_SZ * NPAD * 8;     // +4,194,304
  size_t off_kept  = off_gbox  + (size_t)B_SZ * MAXC * 16;    // +1,540,096
  size_t off_meta  = off_kept  + (size_t)B_SZ * N_POST * 16;  // +256,000
  size_t off_mask  = (off_meta + 256 + 255) & ~(size_t)255;

  float4* boxes = (float4*)(ws + off_boxes);
  u64*    keys  = (u64*)   (ws + off_keys);
  float4* gbox  = (float4*)(ws + off_gbox);
  float4* kept  = (float4*)(ws + off_kept);
  int*    meta  = (int*)   (ws + off_meta);
  u64*    mask  = (u64*)   (ws + off_mask);

  // mask bytes = B_SZ * n * (n/64) * 8 = n^2
  static const int cand[] = {12032, 8192, 6144, 4096, 3072, 2048, 1024};
  int nmat = 0;
  for (int ci = 0; ci < 7; ++ci) {
    if (off_mask + (size_t)cand[ci] * cand[ci] <= ws_size) { nmat = cand[ci]; break; }
  }

  k_decode<<<dim3(NPAD / 256, B_SZ), 256, 0, stream>>>(imh, imw, anchors, loc, obj,
                                                       boxes, keys, meta);
  // bitonic sort: tile sorts (tiles 5..7 are all-pad/equal keys -> skip)
  k_sort_tile<<<dim3(5, B_SZ), 1024, 0, stream>>>(keys);
  dim3 gp(NPAD / 2 / 256, B_SZ);
  k_sort_pass<<<gp, 256, 0, stream>>>(keys, 16384, 8192);
  k_sort_local<<<dim3(NPAD / TILE, B_SZ), 1024, 0, stream>>>(keys, 16384);
  k_sort_pass<<<gp, 256, 0, stream>>>(keys, 32768, 16384);
  k_sort_pass<<<gp, 256, 0, stream>>>(keys, 32768, 8192);
  k_sort_local<<<dim3(NPAD / TILE, B_SZ), 1024, 0, stream>>>(keys, 32768);
  k_sort_pass<<<gp, 256, 0, stream>>>(keys, 65536, 32768);
  k_sort_pass<<<gp, 256, 0, stream>>>(keys, 65536, 16384);
  k_sort_pass<<<gp, 256, 0, stream>>>(keys, 65536, 8192);
  k_sort_local<<<dim3(NPAD / TILE, B_SZ), 1024, 0, stream>>>(keys, 65536);

  k_gather<<<dim3(MAXC / 256, B_SZ), 256, 0, stream>>>(keys, boxes, gbox, meta);

  if (nmat > 0) {
    k_mask<<<dim3(nmat / 64, B_SZ), 256, 0, stream>>>(gbox, meta, mask, nmat);
    k_walk<<<B_SZ, 64, 0, stream>>>(gbox, mask, meta, kept, nmat);
  }
  k_tail<<<B_SZ, 1024, 0, stream>>>(gbox, meta, kept, nmat);
  k_out<<<dim3((N_POST + 255) / 256, B_SZ), 256, 0, stream>>>(kept, meta, out);
}

// Round 3
// 903.759 us; speedup vs baseline: 2.5462x; 2.0386x over previous
//
#include <hip/hip_runtime.h>

typedef unsigned long long u64;
typedef unsigned int u32;
typedef unsigned char u8;

#define B_SZ   8
#define N_ANC  36864
#define N_PRE  12000
#define N_POST 2000
#define SEG    2048
#define NSEG   6
#define MAXC   (SEG * NSEG)   // 12288
#define NW     (SEG / 64)     // 32 u64 words per mask row
#define CSORT  16384
#define TILE   8192

__device__ __forceinline__ u64 shfl64(u64 v, int src) {
  int lo = __shfl((int)(u32)(v & 0xffffffffull), src, 64);
  int hi = __shfl((int)(u32)(v >> 32), src, 64);
  return ((u64)(u32)hi << 32) | (u32)lo;
}

__device__ __forceinline__ float area_of(float4 p) {
  return __fmul_rn(__fsub_rn(p.z, p.x), __fsub_rn(p.w, p.y));
}

// bit-exact: a0 = area(first arg of reference iou), a1 = area(second)
__device__ __forceinline__ bool iou_gt_a(float4 p, float4 q, float a0, float a1) {
  float ix1 = fmaxf(p.x, q.x), iy1 = fmaxf(p.y, q.y);
  float ix2 = fminf(p.z, q.z), iy2 = fminf(p.w, q.w);
  float iw = fmaxf(__fsub_rn(ix2, ix1), 0.0f);
  float ih = fmaxf(__fsub_rn(iy2, iy1), 0.0f);
  float inter = __fmul_rn(iw, ih);
  float den = fmaxf(__fsub_rn(__fadd_rn(a0, a1), inter), 1e-9f);
  return (inter / den) > 0.7f;
}

// ---------------- decode + score + sort keys ----------------------------
__global__ __launch_bounds__(256) void k_decode(
    const int* __restrict__ imh_p, const int* __restrict__ imw_p,
    const float* __restrict__ anchors, const float* __restrict__ loc,
    const float* __restrict__ obj, float4* __restrict__ boxes,
    u64* __restrict__ keys)
{
  int n = blockIdx.x * 256 + threadIdx.x;
  int b = blockIdx.y;
  if (n >= N_ANC) return;
  float a0 = anchors[n * 4 + 0], a1 = anchors[n * 4 + 1];
  float a2 = anchors[n * 4 + 2], a3 = anchors[n * 4 + 3];
  size_t off = (size_t)b * N_ANC + n;
  float l0 = loc[off * 4 + 0], l1 = loc[off * 4 + 1];
  float l2 = loc[off * 4 + 2], l3 = loc[off * 4 + 3];

  float w  = __fsub_rn(a2, a0);
  float h  = __fsub_rn(a3, a1);
  float cx = __fadd_rn(a0, __fmul_rn(0.5f, w));
  float cy = __fadd_rn(a1, __fmul_rn(0.5f, h));
  float pcx = __fadd_rn(__fmul_rn(l0, w), cx);
  float pcy = __fadd_rn(__fmul_rn(l1, h), cy);
  float pw  = __fmul_rn(expf(l2), w);
  float ph  = __fmul_rn(expf(l3), h);
  float imw = (float)imw_p[0], imh = (float)imh_p[0];
  float hx = __fmul_rn(0.5f, pw), hy = __fmul_rn(0.5f, ph);
  float x1 = fminf(fmaxf(__fsub_rn(pcx, hx), 0.0f), imw);
  float y1 = fminf(fmaxf(__fsub_rn(pcy, hy), 0.0f), imh);
  float x2 = fminf(fmaxf(__fadd_rn(pcx, hx), 0.0f), imw);
  float y2 = fminf(fmaxf(__fadd_rn(pcy, hy), 0.0f), imh);
  boxes[off] = make_float4(x1, y1, x2, y2);

  bool valid = (__fsub_rn(x2, x1) >= 16.0f) && (__fsub_rn(y2, y1) >= 16.0f);

  float o0 = obj[off * 2 + 0], o1 = obj[off * 2 + 1];
  float m  = fmaxf(o0, o1);
  float e0 = expf(__fsub_rn(o0, m));
  float e1 = expf(__fsub_rn(o1, m));
  float s  = e1 / __fadd_rn(e0, e1);
  float sc = valid ? s : -1e9f;

  u32 u  = __float_as_uint(sc);
  u32 fk = (u & 0x80000000u) ? ~u : (u | 0x80000000u);
  u32 sk = ~fk;  // ascending u64 == descending score, stable by index
  keys[(size_t)b * N_ANC + n] = ((u64)sk << 32) | (u32)n;
}

// ---------------- histogram select (2 levels, 2048 bins) ----------------
__global__ __launch_bounds__(256) void k_hist1(
    const u64* __restrict__ keys, u32* __restrict__ hist)
{
  int b = blockIdx.y;
  __shared__ u32 lh[2048];
  int t = threadIdx.x;
#pragma unroll
  for (int i = 0; i < 8; ++i) lh[t + i * 256] = 0;
  __syncthreads();
#pragma unroll
  for (int k = 0; k < 4; ++k) {
    int i = blockIdx.x * 1024 + k * 256 + t;
    u64 key = keys[(size_t)b * N_ANC + i];
    atomicAdd(&lh[(u32)(key >> 53)], 1u);
  }
  __syncthreads();
#pragma unroll
  for (int i = 0; i < 8; ++i) {
    u32 v = lh[t + i * 256];
    if (v) atomicAdd(&hist[b * 2048 + t + i * 256], v);
  }
}

__global__ __launch_bounds__(256) void k_pick1(
    const u32* __restrict__ hist, u32* __restrict__ T1, u32* __restrict__ Base1)
{
  int b = blockIdx.x, t = threadIdx.x;
  const u32* h = hist + b * 2048;
  __shared__ u32 part[256], pre[256];
  u32 loc[8], s = 0;
#pragma unroll
  for (int i = 0; i < 8; ++i) { loc[i] = h[t * 8 + i]; s += loc[i]; }
  part[t] = s;
  __syncthreads();
  if (t == 0) { u32 acc = 0; for (int i = 0; i < 256; ++i) { pre[i] = acc; acc += part[i]; } }
  __syncthreads();
  u32 acc = pre[t];
#pragma unroll
  for (int i = 0; i < 8; ++i) {
    u32 na = acc + loc[i];
    if (acc < N_PRE && na >= N_PRE) { T1[b] = t * 8 + i; Base1[b] = acc; }
    acc = na;
  }
}

__global__ __launch_bounds__(256) void k_hist2(
    const u64* __restrict__ keys, const u32* __restrict__ T1, u32* __restrict__ hist)
{
  int b = blockIdx.y;
  u32 t1 = T1[b];
  __shared__ u32 lh[2048];
  int t = threadIdx.x;
#pragma unroll
  for (int i = 0; i < 8; ++i) lh[t + i * 256] = 0;
  __syncthreads();
#pragma unroll
  for (int k = 0; k < 4; ++k) {
    int i = blockIdx.x * 1024 + k * 256 + t;
    u64 key = keys[(size_t)b * N_ANC + i];
    if ((u32)(key >> 53) == t1) atomicAdd(&lh[(u32)(key >> 42) & 0x7FFu], 1u);
  }
  __syncthreads();
#pragma unroll
  for (int i = 0; i < 8; ++i) {
    u32 v = lh[t + i * 256];
    if (v) atomicAdd(&hist[b * 2048 + t + i * 256], v);
  }
}

__global__ __launch_bounds__(256) void k_pick2(
    const u32* __restrict__ hist, const u32* __restrict__ T1,
    const u32* __restrict__ Base1, u32* __restrict__ T2)
{
  int b = blockIdx.x, t = threadIdx.x;
  const u32* h = hist + b * 2048;
  __shared__ u32 part[256], pre[256];
  u32 loc[8], s = 0;
#pragma unroll
  for (int i = 0; i < 8; ++i) { loc[i] = h[t * 8 + i]; s += loc[i]; }
  part[t] = s;
  __syncthreads();
  if (t == 0) { u32 acc = Base1[b]; for (int i = 0; i < 256; ++i) { pre[i] = acc; acc += part[i]; } }
  __syncthreads();
  u32 acc = pre[t];
#pragma unroll
  for (int i = 0; i < 8; ++i) {
    u32 na = acc + loc[i];
    if (acc < N_PRE && na >= N_PRE) T2[b] = (T1[b] << 11) | (u32)(t * 8 + i);
    acc = na;
  }
}

__global__ __launch_bounds__(256) void k_compact(
    const u64* __restrict__ keys, const u32* __restrict__ T2,
    u64* __restrict__ cand, u32* __restrict__ cnt)
{
  int b = blockIdx.y;
  int i = blockIdx.x * 256 + threadIdx.x;
  u64 key = keys[(size_t)b * N_ANC + i];
  if ((u32)(key >> 42) <= T2[b]) {
    u32 pos = atomicAdd(&cnt[b], 1u);
    if (pos < CSORT) cand[(size_t)b * CSORT + pos] = key;
  }
}

// ---------------- bitonic sort of 16384 ---------------------------------
__global__ __launch_bounds__(1024) void k_sort_tile(u64* __restrict__ a)
{
  int b = blockIdx.y, base = blockIdx.x * TILE;
  u64* p = a + (size_t)b * CSORT;
  __shared__ u64 lds[TILE];
  for (int i = threadIdx.x; i < TILE; i += 1024) lds[i] = p[base + i];
  __syncthreads();
  for (int k = 2; k <= TILE; k <<= 1) {
    for (int j = k >> 1; j > 0; j >>= 1) {
      for (int q = threadIdx.x; q < TILE / 2; q += 1024) {
        int i = ((q & ~(j - 1)) << 1) | (q & (j - 1));
        int l = i | j;
        bool asc = (((base + i) & k) == 0);
        u64 x = lds[i], y = lds[l];
        if ((x > y) == asc) { lds[i] = y; lds[l] = x; }
      }
      __syncthreads();
    }
  }
  for (int i = threadIdx.x; i < TILE; i += 1024) p[base + i] = lds[i];
}

__global__ __launch_bounds__(256) void k_sort_pass(u64* __restrict__ a, int k, int j)
{
  int b = blockIdx.y;
  int q = blockIdx.x * 256 + threadIdx.x;
  int i = ((q & ~(j - 1)) << 1) | (q & (j - 1));
  int l = i | j;
  bool asc = ((i & k) == 0);
  u64* p = a + (size_t)b * CSORT;
  u64 x = p[i], y = p[l];
  if ((x > y) == asc) { p[i] = y; p[l] = x; }
}

__global__ __launch_bounds__(1024) void k_sort_local(u64* __restrict__ a, int k)
{
  int b = blockIdx.y, base = blockIdx.x * TILE;
  u64* p = a + (size_t)b * CSORT;
  __shared__ u64 lds[TILE];
  for (int i = threadIdx.x; i < TILE; i += 1024) lds[i] = p[base + i];
  __syncthreads();
  for (int j = TILE >> 1; j > 0; j >>= 1) {
    for (int q = threadIdx.x; q < TILE / 2; q += 1024) {
      int i = ((q & ~(j - 1)) << 1) | (q & (j - 1));
      int l = i | j;
      bool asc = (((base + i) & k) == 0);
      u64 x = lds[i], y = lds[l];
      if ((x > y) == asc) { lds[i] = y; lds[l] = x; }
    }
    __syncthreads();
  }
  for (int i = threadIdx.x; i < TILE; i += 1024) p[base + i] = lds[i];
}

// ---------------- gather sorted boxes + dead flags ----------------------
__global__ __launch_bounds__(256) void k_gather(
    const u64* __restrict__ cand, const float4* __restrict__ boxes,
    float4* __restrict__ gbox, u8* __restrict__ dead)
{
  int i = blockIdx.x * 256 + threadIdx.x;  // [0, MAXC)
  int b = blockIdx.y;
  u64 k = cand[(size_t)b * CSORT + i];
  u32 sk = (u32)(k >> 32);
  bool valid = sk < 0x80000000u;
  float4 bx = make_float4(0.f, 0.f, 0.f, 0.f);
  if (valid) bx = boxes[(size_t)b * N_ANC + (u32)k];
  gbox[(size_t)b * MAXC + i] = bx;
  dead[(size_t)b * MAXC + i] = (!valid || i >= N_PRE) ? 1 : 0;
}

// ---------------- intra-segment triangular masks (all segments) ---------
__global__ __launch_bounds__(256) void k_segmask(
    const float4* __restrict__ gbox, u64* __restrict__ smask)
{
  int b = blockIdx.y;
  int sg = blockIdx.x >> 5;   // segment
  int rg = blockIdx.x & 31;   // row group of 64
  const float4* gb = gbox + (size_t)b * MAXC;
  __shared__ float4 rbox[64];
  __shared__ float rarea[64];
  int t = threadIdx.x;
  if (t < 64) {
    float4 r = gb[sg * SEG + rg * 64 + t];
    rbox[t] = r;
    rarea[t] = area_of(r);
  }
  __syncthreads();
  int wv = t >> 6, lane = t & 63;
  u64* srow = smask + ((size_t)(b * NSEG + sg) * SEG + rg * 64) * NW;
  for (int cw = rg; cw < NW; ++cw) {
    int cl = cw * 64 + lane;
    float4 cb = gb[sg * SEG + cl];
    float ca = area_of(cb);
    for (int rr = wv; rr < 64; rr += 4) {
      int rl = rg * 64 + rr;
      bool p = (cl > rl) && iou_gt_a(rbox[rr], cb, rarea[rr], ca);
      u64 m = __ballot(p);
      if (lane == 0) srow[(size_t)rr * NW + cw] = m;
    }
  }
}

// ---------------- cross: segment candidates vs kept list ----------------
__global__ __launch_bounds__(256) void k_cross(
    const float4* __restrict__ gbox, const float4* __restrict__ kept,
    const int* __restrict__ meta, u8* __restrict__ dead, int sg)
{
  int b = blockIdx.y;
  if (meta[b * 8 + 1]) return;              // done
  int kc = blockIdx.x >> 3, cbk = blockIdx.x & 7;
  int nkept = meta[b * 8 + 0];
  int kbase = kc * 256;
  if (kbase >= nkept) return;
  int kcnt = min(256, nkept - kbase);
  __shared__ float4 kb[256];
  __shared__ float ka[256];
  int t = threadIdx.x;
  if (t < kcnt) {
    float4 k4 = kept[(size_t)b * SEG + kbase + t];
    kb[t] = k4;
    ka[t] = area_of(k4);
  }
  __syncthreads();
  int c = sg * SEG + cbk * 256 + t;
  if (dead[(size_t)b * MAXC + c]) return;
  float4 my = gbox[(size_t)b * MAXC + c];
  float ma = area_of(my);
  for (int kk = 0; kk < kcnt; ++kk) {
    if (iou_gt_a(kb[kk], my, ka[kk], ma)) {
      dead[(size_t)b * MAXC + c] = 1;
      break;
    }
  }
}

// ---------------- serial greedy walk within a segment -------------------
__global__ __launch_bounds__(256) void k_walk(
    const float4* __restrict__ gbox, const u64* __restrict__ smask,
    const u8* __restrict__ dead, int* __restrict__ meta,
    float4* __restrict__ kept, int sg)
{
  int b = blockIdx.x;
  if (meta[b * 8 + 1]) return;  // done (uniform)
  int t = threadIdx.x, lane = t & 63, wv = t >> 6;
  __shared__ u32 remv[64];      // 2048 suppression bits (this segment)
  __shared__ u32 klist[64];
  __shared__ int s_kcnt, s_nkept, s_stop;
  if (t < 64) remv[t] = 0;
  if (t == 0) { s_nkept = meta[b * 8 + 0]; s_stop = 0; s_kcnt = 0; }
  __syncthreads();
  const u64* smb = smask + (size_t)(b * NSEG + sg) * SEG * NW;
  const float4* gb = gbox + (size_t)b * MAXC;
  float4* kb = kept + (size_t)b * SEG;

  for (int g = 0; g < NW; ++g) {
    int rl = g * 64 + lane;
    if (wv == 0) {
      u64 intra = smb[(size_t)rl * NW + g];
      int df = dead[(size_t)b * MAXC + sg * SEG + rl];
      u64 rg = ((u64)remv[2 * g + 1] << 32) | remv[2 * g];
      rg |= __ballot(df != 0);
      int nk0 = s_nkept;
      u64 keptm = 0;
      int nk = nk0, stopped = 0;
      for (int ii = 0; ii < 64; ++ii) {
        if (!((rg >> ii) & 1)) {
          keptm |= (1ull << ii);
          ++nk;
          if (nk >= N_POST) { stopped = 1; break; }
          rg |= shfl64(intra, ii);
        }
      }
      if ((keptm >> lane) & 1) {
        int idx = __popcll(keptm & ((1ull << lane) - 1ull));
        kb[nk0 + idx] = gb[sg * SEG + rl];
        klist[idx] = rl;
      }
      if (lane == 0) {
        int c = __popcll(keptm);
        s_kcnt = c;
        s_nkept = nk0 + c;
        s_stop = stopped;
      }
    }
    __syncthreads();
    if (s_stop) break;
    int cnt = s_kcnt;
    for (int task = t; task < cnt * 64; task += 256) {
      int row = klist[task >> 6];
      int w = task & 63;
      u32 v = ((const u32*)(smb + (size_t)row * NW))[w];
      if (v) atomicOr(&remv[w], v);
    }
    __syncthreads();
  }
  if (t == 0) {
    meta[b * 8 + 0] = s_nkept;
    meta[b * 8 + 1] = (s_stop || sg == NSEG - 1) ? 1 : 0;
  }
}

// ---------------- output ------------------------------------------------
__global__ __launch_bounds__(256) void k_out(
    const float4* __restrict__ kept, const int* __restrict__ meta,
    float* __restrict__ out)
{
  int i = blockIdx.x * 256 + threadIdx.x;
  int b = blockIdx.y;
  if (i >= N_POST) return;
  int nk = meta[b * 8 + 0];
  float4 v = (i < nk) ? kept[(size_t)b * SEG + i]
                      : make_float4(0.f, 0.f, 0.f, 0.f);
  ((float4*)(out + (size_t)b * N_POST * 4))[i] = v;
  out[(size_t)B_SZ * N_POST * 4 + (size_t)b * N_POST + i] = (i < nk) ? 1.0f : 0.0f;
}

extern "C" void kernel_launch(void* const* d_in, const int* in_sizes, int n_in,
                              void* d_out, int out_size, void* d_ws, size_t ws_size,
                              hipStream_t stream)
{
  const int*   imh     = (const int*)d_in[0];
  const int*   imw     = (const int*)d_in[1];
  const float* anchors = (const float*)d_in[2];
  const float* loc     = (const float*)d_in[3];
  const float* obj     = (const float*)d_in[4];
  float* out = (float*)d_out;

  char* ws = (char*)d_ws;
  size_t off = 0;
  float4* boxes = (float4*)(ws + off); off += (size_t)B_SZ * N_ANC * 16;   // 4.72 MB
  u64*    keys  = (u64*)   (ws + off); off += (size_t)B_SZ * N_ANC * 8;    // 2.36 MB
  u64*    cand  = (u64*)   (ws + off); off += (size_t)B_SZ * CSORT * 8;    // 1.05 MB
  float4* gbox  = (float4*)(ws + off); off += (size_t)B_SZ * MAXC * 16;    // 1.57 MB
  float4* kept  = (float4*)(ws + off); off += (size_t)B_SZ * SEG * 16;     // 0.26 MB
  u8*     dead  = (u8*)    (ws + off); off += (size_t)B_SZ * MAXC;         // 96 KB
  off = (off + 255) & ~(size_t)255;
  char*   zr    = ws + off;  // zero region start
  u32*    hist1 = (u32*)(zr);
  u32*    hist2 = (u32*)(zr + 65536);
  u32*    T1    = (u32*)(zr + 131072);
  u32*    Base1 = (u32*)(zr + 131072 + 64);
  u32*    T2    = (u32*)(zr + 131072 + 128);
  u32*    cnt   = (u32*)(zr + 131072 + 192);
  int*    meta  = (int*)(zr + 131072 + 256);   // 8*8 ints
  size_t zr_sz  = 131072 + 256 + B_SZ * 8 * 4;
  off += (zr_sz + 255) & ~(size_t)255;
  u64*    smask = (u64*)(ws + off);            // 8*6*2048*32*8 = 25.2 MB

  hipMemsetAsync(zr, 0, zr_sz, stream);
  hipMemsetAsync(cand, 0xFF, (size_t)B_SZ * CSORT * 8, stream);

  k_decode<<<dim3(144, B_SZ), 256, 0, stream>>>(imh, imw, anchors, loc, obj, boxes, keys);
  k_hist1<<<dim3(36, B_SZ), 256, 0, stream>>>(keys, hist1);
  k_pick1<<<B_SZ, 256, 0, stream>>>(hist1, T1, Base1);
  k_hist2<<<dim3(36, B_SZ), 256, 0, stream>>>(keys, T1, hist2);
  k_pick2<<<B_SZ, 256, 0, stream>>>(hist2, T1, Base1, T2);
  k_compact<<<dim3(144, B_SZ), 256, 0, stream>>>(keys, T2, cand, cnt);

  k_sort_tile<<<dim3(2, B_SZ), 1024, 0, stream>>>(cand);
  k_sort_pass<<<dim3(CSORT / 2 / 256, B_SZ), 256, 0, stream>>>(cand, 16384, 8192);
  k_sort_local<<<dim3(2, B_SZ), 1024, 0, stream>>>(cand, 16384);

  k_gather<<<dim3(MAXC / 256, B_SZ), 256, 0, stream>>>(cand, boxes, gbox, dead);
  k_segmask<<<dim3(NSEG * 32, B_SZ), 256, 0, stream>>>(gbox, smask);

  k_walk<<<B_SZ, 256, 0, stream>>>(gbox, smask, dead, meta, kept, 0);
  for (int sg = 1; sg < NSEG; ++sg) {
    k_cross<<<dim3(64, B_SZ), 256, 0, stream>>>(gbox, kept, meta, dead, sg);
    k_walk<<<B_SZ, 256, 0, stream>>>(gbox, smask, dead, meta, kept, sg);
  }
  k_out<<<dim3((N_POST + 255) / 256, B_SZ), 256, 0, stream>>>(kept, meta, out);
}

// Round 4
// 417.082 us; speedup vs baseline: 5.5173x; 2.1669x over previous
//
#include <hip/hip_runtime.h>

typedef unsigned long long u64;
typedef unsigned int u32;
typedef unsigned char u8;

#define B_SZ   8
#define N_ANC  36864
#define N_PRE  12000
#define N_POST 2000
#define SEG    2048
#define NSEG   6
#define MAXC   (SEG * NSEG)   // 12288
#define NW     (SEG / 64)     // 32 u64 words per mask row
#define CSORT  16384
#define TILE   8192

__device__ __forceinline__ float area_of(float4 p) {
  return __fmul_rn(__fsub_rn(p.z, p.x), __fsub_rn(p.w, p.y));
}

// bit-exact: a0 = area(first arg of reference iou), a1 = area(second)
__device__ __forceinline__ bool iou_gt_a(float4 p, float4 q, float a0, float a1) {
  float ix1 = fmaxf(p.x, q.x), iy1 = fmaxf(p.y, q.y);
  float ix2 = fminf(p.z, q.z), iy2 = fminf(p.w, q.w);
  float iw = fmaxf(__fsub_rn(ix2, ix1), 0.0f);
  float ih = fmaxf(__fsub_rn(iy2, iy1), 0.0f);
  float inter = __fmul_rn(iw, ih);
  float den = fmaxf(__fsub_rn(__fadd_rn(a0, a1), inter), 1e-9f);
  return (inter / den) > 0.7f;
}

// ---------------- decode + score + sort keys ----------------------------
__global__ __launch_bounds__(256) void k_decode(
    const int* __restrict__ imh_p, const int* __restrict__ imw_p,
    const float* __restrict__ anchors, const float* __restrict__ loc,
    const float* __restrict__ obj, float4* __restrict__ boxes,
    u64* __restrict__ keys)
{
  int n = blockIdx.x * 256 + threadIdx.x;
  int b = blockIdx.y;
  if (n >= N_ANC) return;
  float a0 = anchors[n * 4 + 0], a1 = anchors[n * 4 + 1];
  float a2 = anchors[n * 4 + 2], a3 = anchors[n * 4 + 3];
  size_t off = (size_t)b * N_ANC + n;
  float l0 = loc[off * 4 + 0], l1 = loc[off * 4 + 1];
  float l2 = loc[off * 4 + 2], l3 = loc[off * 4 + 3];

  float w  = __fsub_rn(a2, a0);
  float h  = __fsub_rn(a3, a1);
  float cx = __fadd_rn(a0, __fmul_rn(0.5f, w));
  float cy = __fadd_rn(a1, __fmul_rn(0.5f, h));
  float pcx = __fadd_rn(__fmul_rn(l0, w), cx);
  float pcy = __fadd_rn(__fmul_rn(l1, h), cy);
  float pw  = __fmul_rn(expf(l2), w);
  float ph  = __fmul_rn(expf(l3), h);
  float imw = (float)imw_p[0], imh = (float)imh_p[0];
  float hx = __fmul_rn(0.5f, pw), hy = __fmul_rn(0.5f, ph);
  float x1 = fminf(fmaxf(__fsub_rn(pcx, hx), 0.0f), imw);
  float y1 = fminf(fmaxf(__fsub_rn(pcy, hy), 0.0f), imh);
  float x2 = fminf(fmaxf(__fadd_rn(pcx, hx), 0.0f), imw);
  float y2 = fminf(fmaxf(__fadd_rn(pcy, hy), 0.0f), imh);
  boxes[off] = make_float4(x1, y1, x2, y2);

  bool valid = (__fsub_rn(x2, x1) >= 16.0f) && (__fsub_rn(y2, y1) >= 16.0f);

  float o0 = obj[off * 2 + 0], o1 = obj[off * 2 + 1];
  float m  = fmaxf(o0, o1);
  float e0 = expf(__fsub_rn(o0, m));
  float e1 = expf(__fsub_rn(o1, m));
  float s  = e1 / __fadd_rn(e0, e1);
  float sc = valid ? s : -1e9f;

  u32 u  = __float_as_uint(sc);
  u32 fk = (u & 0x80000000u) ? ~u : (u | 0x80000000u);
  u32 sk = ~fk;  // ascending u64 == descending score, stable by index
  keys[(size_t)b * N_ANC + n] = ((u64)sk << 32) | (u32)n;
}

// ---------------- histogram select (2 levels, 2048 bins) ----------------
__global__ __launch_bounds__(256) void k_hist1(
    const u64* __restrict__ keys, u32* __restrict__ hist)
{
  int b = blockIdx.y;
  __shared__ u32 lh[2048];
  int t = threadIdx.x;
#pragma unroll
  for (int i = 0; i < 8; ++i) lh[t + i * 256] = 0;
  __syncthreads();
#pragma unroll
  for (int k = 0; k < 4; ++k) {
    int i = blockIdx.x * 1024 + k * 256 + t;
    u64 key = keys[(size_t)b * N_ANC + i];
    atomicAdd(&lh[(u32)(key >> 53)], 1u);
  }
  __syncthreads();
#pragma unroll
  for (int i = 0; i < 8; ++i) {
    u32 v = lh[t + i * 256];
    if (v) atomicAdd(&hist[b * 2048 + t + i * 256], v);
  }
}

__global__ __launch_bounds__(256) void k_pick1(
    const u32* __restrict__ hist, u32* __restrict__ T1, u32* __restrict__ Base1)
{
  int b = blockIdx.x, t = threadIdx.x;
  const u32* h = hist + b * 2048;
  __shared__ u32 part[256], pre[256];
  u32 loc[8], s = 0;
#pragma unroll
  for (int i = 0; i < 8; ++i) { loc[i] = h[t * 8 + i]; s += loc[i]; }
  part[t] = s;
  __syncthreads();
  if (t == 0) { u32 acc = 0; for (int i = 0; i < 256; ++i) { pre[i] = acc; acc += part[i]; } }
  __syncthreads();
  u32 acc = pre[t];
#pragma unroll
  for (int i = 0; i < 8; ++i) {
    u32 na = acc + loc[i];
    if (acc < N_PRE && na >= N_PRE) { T1[b] = t * 8 + i; Base1[b] = acc; }
    acc = na;
  }
}

__global__ __launch_bounds__(256) void k_hist2(
    const u64* __restrict__ keys, const u32* __restrict__ T1, u32* __restrict__ hist)
{
  int b = blockIdx.y;
  u32 t1 = T1[b];
  __shared__ u32 lh[2048];
  int t = threadIdx.x;
#pragma unroll
  for (int i = 0; i < 8; ++i) lh[t + i * 256] = 0;
  __syncthreads();
#pragma unroll
  for (int k = 0; k < 4; ++k) {
    int i = blockIdx.x * 1024 + k * 256 + t;
    u64 key = keys[(size_t)b * N_ANC + i];
    if ((u32)(key >> 53) == t1) atomicAdd(&lh[(u32)(key >> 42) & 0x7FFu], 1u);
  }
  __syncthreads();
#pragma unroll
  for (int i = 0; i < 8; ++i) {
    u32 v = lh[t + i * 256];
    if (v) atomicAdd(&hist[b * 2048 + t + i * 256], v);
  }
}

__global__ __launch_bounds__(256) void k_pick2(
    const u32* __restrict__ hist, const u32* __restrict__ T1,
    const u32* __restrict__ Base1, u32* __restrict__ T2)
{
  int b = blockIdx.x, t = threadIdx.x;
  const u32* h = hist + b * 2048;
  __shared__ u32 part[256], pre[256];
  u32 loc[8], s = 0;
#pragma unroll
  for (int i = 0; i < 8; ++i) { loc[i] = h[t * 8 + i]; s += loc[i]; }
  part[t] = s;
  __syncthreads();
  if (t == 0) { u32 acc = Base1[b]; for (int i = 0; i < 256; ++i) { pre[i] = acc; acc += part[i]; } }
  __syncthreads();
  u32 acc = pre[t];
#pragma unroll
  for (int i = 0; i < 8; ++i) {
    u32 na = acc + loc[i];
    if (acc < N_PRE && na >= N_PRE) T2[b] = (T1[b] << 11) | (u32)(t * 8 + i);
    acc = na;
  }
}

__global__ __launch_bounds__(256) void k_compact(
    const u64* __restrict__ keys, const u32* __restrict__ T2,
    u64* __restrict__ cand, u32* __restrict__ cnt)
{
  int b = blockIdx.y;
  int i = blockIdx.x * 256 + threadIdx.x;
  u64 key = keys[(size_t)b * N_ANC + i];
  if ((u32)(key >> 42) <= T2[b]) {
    u32 pos = atomicAdd(&cnt[b], 1u);
    if (pos < CSORT) cand[(size_t)b * CSORT + pos] = key;
  }
}

// ---------------- bitonic sort of 16384 ---------------------------------
__global__ __launch_bounds__(1024) void k_sort_tile(u64* __restrict__ a)
{
  int b = blockIdx.y, base = blockIdx.x * TILE;
  u64* p = a + (size_t)b * CSORT;
  __shared__ u64 lds[TILE];
  for (int i = threadIdx.x; i < TILE; i += 1024) lds[i] = p[base + i];
  __syncthreads();
  for (int k = 2; k <= TILE; k <<= 1) {
    for (int j = k >> 1; j > 0; j >>= 1) {
      for (int q = threadIdx.x; q < TILE / 2; q += 1024) {
        int i = ((q & ~(j - 1)) << 1) | (q & (j - 1));
        int l = i | j;
        bool asc = (((base + i) & k) == 0);
        u64 x = lds[i], y = lds[l];
        if ((x > y) == asc) { lds[i] = y; lds[l] = x; }
      }
      __syncthreads();
    }
  }
  for (int i = threadIdx.x; i < TILE; i += 1024) p[base + i] = lds[i];
}

__global__ __launch_bounds__(256) void k_sort_pass(u64* __restrict__ a, int k, int j)
{
  int b = blockIdx.y;
  int q = blockIdx.x * 256 + threadIdx.x;
  int i = ((q & ~(j - 1)) << 1) | (q & (j - 1));
  int l = i | j;
  bool asc = ((i & k) == 0);
  u64* p = a + (size_t)b * CSORT;
  u64 x = p[i], y = p[l];
  if ((x > y) == asc) { p[i] = y; p[l] = x; }
}

__global__ __launch_bounds__(1024) void k_sort_local(u64* __restrict__ a, int k)
{
  int b = blockIdx.y, base = blockIdx.x * TILE;
  u64* p = a + (size_t)b * CSORT;
  __shared__ u64 lds[TILE];
  for (int i = threadIdx.x; i < TILE; i += 1024) lds[i] = p[base + i];
  __syncthreads();
  for (int j = TILE >> 1; j > 0; j >>= 1) {
    for (int q = threadIdx.x; q < TILE / 2; q += 1024) {
      int i = ((q & ~(j - 1)) << 1) | (q & (j - 1));
      int l = i | j;
      bool asc = (((base + i) & k) == 0);
      u64 x = lds[i], y = lds[l];
      if ((x > y) == asc) { lds[i] = y; lds[l] = x; }
    }
    __syncthreads();
  }
  for (int i = threadIdx.x; i < TILE; i += 1024) p[base + i] = lds[i];
}

// ---------------- gather sorted boxes + dead flags ----------------------
__global__ __launch_bounds__(256) void k_gather(
    const u64* __restrict__ cand, const float4* __restrict__ boxes,
    float4* __restrict__ gbox, u8* __restrict__ dead)
{
  int i = blockIdx.x * 256 + threadIdx.x;  // [0, MAXC)
  int b = blockIdx.y;
  u64 k = cand[(size_t)b * CSORT + i];
  u32 sk = (u32)(k >> 32);
  bool valid = sk < 0x80000000u;
  float4 bx = make_float4(0.f, 0.f, 0.f, 0.f);
  if (valid) bx = boxes[(size_t)b * N_ANC + (u32)k];
  gbox[(size_t)b * MAXC + i] = bx;
  dead[(size_t)b * MAXC + i] = (!valid || i >= N_PRE) ? 1 : 0;
}

// ---------------- intra-segment masks: rows + transposed diagonal -------
__global__ __launch_bounds__(256) void k_segmask(
    const float4* __restrict__ gbox, const int* __restrict__ meta,
    u64* __restrict__ smask, u64* __restrict__ smaskT, int sgBase)
{
  int b = blockIdx.y;
  if (meta[b * 8 + 1]) return;  // done (safe: 0 before any walk)
  int sg = sgBase + (blockIdx.x >> 5);
  int rg = blockIdx.x & 31;
  const float4* gb = gbox + (size_t)b * MAXC + sg * SEG;
  __shared__ float4 rbox[64];
  __shared__ float rarea[64];
  __shared__ u64 diag[64];
  int t = threadIdx.x;
  if (t < 64) {
    float4 r = gb[rg * 64 + t];
    rbox[t] = r;
    rarea[t] = area_of(r);
  }
  __syncthreads();
  int wv = t >> 6, lane = t & 63;
  u64* srow = smask + (size_t)(b * NSEG + sg) * SEG * NW + (size_t)rg * 64 * NW;

  // diagonal block (cols == rows of this group)
  {
    float4 cb = rbox[lane];
    float ca = rarea[lane];
    for (int rr = wv; rr < 64; rr += 4) {
      bool p = (lane > rr) && iou_gt_a(rbox[rr], cb, rarea[rr], ca);
      u64 m = __ballot(p);
      if (lane == 0) { srow[(size_t)rr * NW + rg] = m; diag[rr] = m; }
    }
  }
  __syncthreads();
  if (t < 64) {  // transpose diagonal: S_col = who suppresses col
    u64 s = 0;
    for (int r = 0; r < 64; ++r) s |= ((diag[r] >> t) & 1ull) << r;
    smaskT[(size_t)(b * NSEG + sg) * SEG + rg * 64 + t] = s;
  }
  // off-diagonal column words
  for (int cw = rg + 1; cw < NW; ++cw) {
    float4 cb = gb[cw * 64 + lane];
    float ca = area_of(cb);
    for (int rr = wv; rr < 64; rr += 4) {
      bool p = iou_gt_a(rbox[rr], cb, rarea[rr], ca);
      u64 m = __ballot(p);
      if (lane == 0) srow[(size_t)rr * NW + cw] = m;
    }
  }
}

// ---------------- cross: segment candidates vs kept list ----------------
__global__ __launch_bounds__(256) void k_cross(
    const float4* __restrict__ gbox, const float4* __restrict__ kept,
    const int* __restrict__ meta, u8* __restrict__ dead, int sg)
{
  int b = blockIdx.y;
  if (meta[b * 8 + 1]) return;              // done
  int kc = blockIdx.x >> 3, cbk = blockIdx.x & 7;
  int nkept = meta[b * 8 + 0];
  int kbase = kc * 256;
  if (kbase >= nkept) return;
  int kcnt = min(256, nkept - kbase);
  __shared__ float4 kb[256];
  __shared__ float ka[256];
  int t = threadIdx.x;
  if (t < kcnt) {
    float4 k4 = kept[(size_t)b * SEG + kbase + t];
    kb[t] = k4;
    ka[t] = area_of(k4);
  }
  __syncthreads();
  int c = sg * SEG + cbk * 256 + t;
  if (dead[(size_t)b * MAXC + c]) return;
  float4 my = gbox[(size_t)b * MAXC + c];
  float ma = area_of(my);
  for (int kk = 0; kk < kcnt; ++kk) {
    if (iou_gt_a(kb[kk], my, ka[kk], ma)) {
      dead[(size_t)b * MAXC + c] = 1;
      break;
    }
  }
}

// ---------------- greedy walk: ballot resolve + LDS prefetch ------------
__global__ __launch_bounds__(1024) void k_walk(
    const float4* __restrict__ gbox, const u64* __restrict__ smask,
    const u64* __restrict__ smaskT, const u8* __restrict__ dead,
    int* __restrict__ meta, float4* __restrict__ kept, int sg)
{
  int b = blockIdx.x;
  if (meta[b * 8 + 1]) return;  // done (uniform)
  int t = threadIdx.x;

  __shared__ u64 rowbuf[2][2048];   // 32 KiB: 64 rows x 32 words, dbuf
  __shared__ u64 stbuf[2][64];      // transposed intra-group masks
  __shared__ float4 bbox[2][64];
  __shared__ u8  dd[2][64];
  __shared__ u32 remv[64];          // 2048 suppression bits (u32 halves)
  __shared__ u32 klist[64];
  __shared__ int s_nkept, s_stop, s_kcnt;

  const u64* smb = smask + (size_t)(b * NSEG + sg) * SEG * NW;
  const u64* stb = smaskT + (size_t)(b * NSEG + sg) * SEG;
  const u8*  db  = dead + (size_t)b * MAXC + sg * SEG;
  const float4* gb = gbox + (size_t)b * MAXC + sg * SEG;
  float4* kb = kept + (size_t)b * SEG;

  if (t == 0) { s_nkept = meta[b * 8 + 0]; s_stop = 0; s_kcnt = 0; }
  if (t < 64) remv[t] = 0;
  // prologue: prefetch group 0
  for (int i = t; i < 2048; i += 1024) rowbuf[0][i] = smb[i];
  if (t < 64) { stbuf[0][t] = stb[t]; dd[0][t] = db[t]; bbox[0][t] = gb[t]; }
  __syncthreads();

  for (int g = 0; g < 32; ++g) {
    int cb = g & 1, nb = cb ^ 1;
    if (t >= 64) {                    // stage A: prefetch group g+1
      if (g < 31) {
        int gg = g + 1;
        for (int i = t - 64; i < 2048; i += 960)
          rowbuf[nb][i] = smb[(size_t)gg * 2048 + i];
        int j = t - 64;
        if (j < 64) {
          stbuf[nb][j] = stb[gg * 64 + j];
          dd[nb][j] = db[gg * 64 + j];
          bbox[nb][j] = gb[gg * 64 + j];
        }
      }
    } else {                          // stage B: wave 0 resolves group g
      int l = t;
      u64 S = stbuf[cb][l];
      int df = dd[cb][l];
      u64 rg = ((u64)remv[2 * g + 1] << 32) | remv[2 * g];
      u64 avail = ~(rg | __ballot(df != 0));
      u64 km = 0;
      while (avail) {
        bool al = (avail >> l) & 1;
        u64 newk = __ballot(al && (S & avail) == 0);
        u64 nd   = __ballot(al && (S & newk) != 0);
        km |= newk;
        avail &= ~(newk | nd);
      }
      int nk0 = s_nkept;
      int rem = N_POST - nk0;
      int kc = __popcll(km);
      int stop = (kc >= rem);
      int rank = __popcll(km & ((1ull << l) - 1ull));
      bool mykeep = ((km >> l) & 1) && (rank < rem);
      if (mykeep) {
        kb[nk0 + rank] = bbox[cb][l];
        klist[rank] = (u32)l;
      }
      if (l == 0) {
        int eff = stop ? rem : kc;
        s_kcnt = eff;
        s_nkept = nk0 + eff;
        s_stop = stop;
      }
    }
    __syncthreads();
    if (s_stop) break;
    // stage C: OR kept rows (from LDS) into remv for future groups
    int kcnt = s_kcnt;
    u32* rb32 = (u32*)rowbuf[cb];
    for (int i = t; i < kcnt * 64; i += 1024) {
      int kk = i >> 6, w = i & 63;
      if ((w >> 1) > g) {
        u32 v = rb32[klist[kk] * 64 + w];
        if (v) atomicOr(&remv[w], v);
      }
    }
    __syncthreads();
  }
  if (t == 0) {
    meta[b * 8 + 0] = s_nkept;
    meta[b * 8 + 1] = (s_stop || sg == NSEG - 1) ? 1 : 0;
  }
}

// ---------------- output ------------------------------------------------
__global__ __launch_bounds__(256) void k_out(
    const float4* __restrict__ kept, const int* __restrict__ meta,
    float* __restrict__ out)
{
  int i = blockIdx.x * 256 + threadIdx.x;
  int b = blockIdx.y;
  if (i >= N_POST) return;
  int nk = meta[b * 8 + 0];
  float4 v = (i < nk) ? kept[(size_t)b * SEG + i]
                      : make_float4(0.f, 0.f, 0.f, 0.f);
  ((float4*)(out + (size_t)b * N_POST * 4))[i] = v;
  out[(size_t)B_SZ * N_POST * 4 + (size_t)b * N_POST + i] = (i < nk) ? 1.0f : 0.0f;
}

extern "C" void kernel_launch(void* const* d_in, const int* in_sizes, int n_in,
                              void* d_out, int out_size, void* d_ws, size_t ws_size,
                              hipStream_t stream)
{
  const int*   imh     = (const int*)d_in[0];
  const int*   imw     = (const int*)d_in[1];
  const float* anchors = (const float*)d_in[2];
  const float* loc     = (const float*)d_in[3];
  const float* obj     = (const float*)d_in[4];
  float* out = (float*)d_out;

  char* ws = (char*)d_ws;
  size_t off = 0;
  float4* boxes = (float4*)(ws + off); off += (size_t)B_SZ * N_ANC * 16;   // 4.72 MB
  u64*    keys  = (u64*)   (ws + off); off += (size_t)B_SZ * N_ANC * 8;    // 2.36 MB
  u64*    cand  = (u64*)   (ws + off); off += (size_t)B_SZ * CSORT * 8;    // 1.05 MB
  float4* gbox  = (float4*)(ws + off); off += (size_t)B_SZ * MAXC * 16;    // 1.57 MB
  float4* kept  = (float4*)(ws + off); off += (size_t)B_SZ * SEG * 16;     // 0.26 MB
  u8*     dead  = (u8*)    (ws + off); off += (size_t)B_SZ * MAXC;         // 96 KB
  off = (off + 255) & ~(size_t)255;
  char*   zr    = ws + off;  // zero region
  u32*    hist1 = (u32*)(zr);
  u32*    hist2 = (u32*)(zr + 65536);
  u32*    T1    = (u32*)(zr + 131072);
  u32*    Base1 = (u32*)(zr + 131072 + 64);
  u32*    T2    = (u32*)(zr + 131072 + 128);
  u32*    cnt   = (u32*)(zr + 131072 + 192);
  int*    meta  = (int*)(zr + 131072 + 256);   // 8*8 ints
  size_t zr_sz  = 131072 + 256 + B_SZ * 8 * 4;
  off += (zr_sz + 255) & ~(size_t)255;
  u64*    smask  = (u64*)(ws + off); off += (size_t)B_SZ * NSEG * SEG * NW * 8; // 25.2 MB
  u64*    smaskT = (u64*)(ws + off); off += (size_t)B_SZ * NSEG * SEG * 8;      // 0.79 MB

  hipMemsetAsync(zr, 0, zr_sz, stream);
  hipMemsetAsync(cand, 0xFF, (size_t)B_SZ * CSORT * 8, stream);

  k_decode<<<dim3(144, B_SZ), 256, 0, stream>>>(imh, imw, anchors, loc, obj, boxes, keys);
  k_hist1<<<dim3(36, B_SZ), 256, 0, stream>>>(keys, hist1);
  k_pick1<<<B_SZ, 256, 0, stream>>>(hist1, T1, Base1);
  k_hist2<<<dim3(36, B_SZ), 256, 0, stream>>>(keys, T1, hist2);
  k_pick2<<<B_SZ, 256, 0, stream>>>(hist2, T1, Base1, T2);
  k_compact<<<dim3(144, B_SZ), 256, 0, stream>>>(keys, T2, cand, cnt);

  k_sort_tile<<<dim3(2, B_SZ), 1024, 0, stream>>>(cand);
  k_sort_pass<<<dim3(CSORT / 2 / 256, B_SZ), 256, 0, stream>>>(cand, 16384, 8192);
  k_sort_local<<<dim3(2, B_SZ), 1024, 0, stream>>>(cand, 16384);

  k_gather<<<dim3(MAXC / 256, B_SZ), 256, 0, stream>>>(cand, boxes, gbox, dead);

  // masks for segments 0,1 upfront; segments >=2 gated on done flag
  k_segmask<<<dim3(64, B_SZ), 256, 0, stream>>>(gbox, meta, smask, smaskT, 0);

  k_walk<<<B_SZ, 1024, 0, stream>>>(gbox, smask, smaskT, dead, meta, kept, 0);
  for (int sg = 1; sg < NSEG; ++sg) {
    k_cross<<<dim3(64, B_SZ), 256, 0, stream>>>(gbox, kept, meta, dead, sg);
    if (sg >= 2)
      k_segmask<<<dim3(32, B_SZ), 256, 0, stream>>>(gbox, meta, smask, smaskT, sg);
    k_walk<<<B_SZ, 1024, 0, stream>>>(gbox, smask, smaskT, dead, meta, kept, sg);
  }
  k_out<<<dim3((N_POST + 255) / 256, B_SZ), 256, 0, stream>>>(kept, meta, out);
}

// Round 5
// 407.073 us; speedup vs baseline: 5.6530x; 1.0246x over previous
//
#include <hip/hip_runtime.h>

typedef unsigned long long u64;
typedef unsigned int u32;

#define B_SZ   8
#define N_ANC  36864
#define N_PRE  12000
#define N_POST 2000
#define SEG    2048
#define NSEG   6
#define MAXC   (SEG * NSEG)   // 12288
#define NW     (SEG / 64)     // 32 u64 words per mask row
#define NDW    (MAXC / 64)    // 192 dead-mask words per batch
#define CSORT  16384
#define TILE   8192

__device__ __forceinline__ u64 shfl64(u64 v, int src) {
  int lo = __shfl((int)(u32)(v & 0xffffffffull), src, 64);
  int hi = __shfl((int)(u32)(v >> 32), src, 64);
  return ((u64)(u32)hi << 32) | (u32)lo;
}

__device__ __forceinline__ float area_of(float4 p) {
  return __fmul_rn(__fsub_rn(p.z, p.x), __fsub_rn(p.w, p.y));
}

// bit-exact replication: a0 = area(first reference arg), a1 = area(second)
__device__ __forceinline__ bool iou_gt_a(float4 p, float4 q, float a0, float a1) {
  float ix1 = fmaxf(p.x, q.x), iy1 = fmaxf(p.y, q.y);
  float ix2 = fminf(p.z, q.z), iy2 = fminf(p.w, q.w);
  float iw = fmaxf(__fsub_rn(ix2, ix1), 0.0f);
  float ih = fmaxf(__fsub_rn(iy2, iy1), 0.0f);
  float inter = __fmul_rn(iw, ih);
  float den = fmaxf(__fsub_rn(__fadd_rn(a0, a1), inter), 1e-9f);
  return (inter / den) > 0.7f;
}

// ---------------- decode + score + keys + fused level-1 histogram -------
__global__ __launch_bounds__(256) void k_decode(
    const int* __restrict__ imh_p, const int* __restrict__ imw_p,
    const float* __restrict__ anchors, const float* __restrict__ loc,
    const float* __restrict__ obj, float4* __restrict__ boxes,
    u64* __restrict__ keys, u32* __restrict__ hist)
{
  __shared__ u32 lh[2048];
  int t = threadIdx.x;
#pragma unroll
  for (int i = 0; i < 8; ++i) lh[t + i * 256] = 0;
  __syncthreads();

  int n = blockIdx.x * 256 + t;
  int b = blockIdx.y;
  float a0 = anchors[n * 4 + 0], a1 = anchors[n * 4 + 1];
  float a2 = anchors[n * 4 + 2], a3 = anchors[n * 4 + 3];
  size_t off = (size_t)b * N_ANC + n;
  float l0 = loc[off * 4 + 0], l1 = loc[off * 4 + 1];
  float l2 = loc[off * 4 + 2], l3 = loc[off * 4 + 3];

  float w  = __fsub_rn(a2, a0);
  float h  = __fsub_rn(a3, a1);
  float cx = __fadd_rn(a0, __fmul_rn(0.5f, w));
  float cy = __fadd_rn(a1, __fmul_rn(0.5f, h));
  float pcx = __fadd_rn(__fmul_rn(l0, w), cx);
  float pcy = __fadd_rn(__fmul_rn(l1, h), cy);
  float pw  = __fmul_rn(expf(l2), w);
  float ph  = __fmul_rn(expf(l3), h);
  float imw = (float)imw_p[0], imh = (float)imh_p[0];
  float hx = __fmul_rn(0.5f, pw), hy = __fmul_rn(0.5f, ph);
  float x1 = fminf(fmaxf(__fsub_rn(pcx, hx), 0.0f), imw);
  float y1 = fminf(fmaxf(__fsub_rn(pcy, hy), 0.0f), imh);
  float x2 = fminf(fmaxf(__fadd_rn(pcx, hx), 0.0f), imw);
  float y2 = fminf(fmaxf(__fadd_rn(pcy, hy), 0.0f), imh);
  boxes[off] = make_float4(x1, y1, x2, y2);

  bool valid = (__fsub_rn(x2, x1) >= 16.0f) && (__fsub_rn(y2, y1) >= 16.0f);

  float o0 = obj[off * 2 + 0], o1 = obj[off * 2 + 1];
  float m  = fmaxf(o0, o1);
  float e0 = expf(__fsub_rn(o0, m));
  float e1 = expf(__fsub_rn(o1, m));
  float s  = e1 / __fadd_rn(e0, e1);
  float sc = valid ? s : -1e9f;

  u32 u  = __float_as_uint(sc);
  u32 fk = (u & 0x80000000u) ? ~u : (u | 0x80000000u);
  u32 sk = ~fk;  // ascending u64 == descending score, stable by index
  u64 key = ((u64)sk << 32) | (u32)n;
  keys[off] = key;
  atomicAdd(&lh[(u32)(key >> 53)], 1u);
  __syncthreads();
#pragma unroll
  for (int i = 0; i < 8; ++i) {
    u32 v = lh[t + i * 256];
    if (v) atomicAdd(&hist[b * 2048 + t + i * 256], v);
  }
}

// ---------------- pick level-1 threshold (gate level 2 on overflow) -----
__global__ __launch_bounds__(256) void k_pick1(
    const u32* __restrict__ hist, u32* __restrict__ T1, u32* __restrict__ Base1,
    u32* __restrict__ T2, u32* __restrict__ need2)
{
  int b = blockIdx.x, t = threadIdx.x;
  const u32* h = hist + b * 2048;
  __shared__ u32 part[256], pre[256];
  u32 loc[8], s = 0;
#pragma unroll
  for (int i = 0; i < 8; ++i) { loc[i] = h[t * 8 + i]; s += loc[i]; }
  part[t] = s;
  __syncthreads();
  if (t == 0) { u32 acc = 0; for (int i = 0; i < 256; ++i) { pre[i] = acc; acc += part[i]; } }
  __syncthreads();
  u32 acc = pre[t];
#pragma unroll
  for (int i = 0; i < 8; ++i) {
    u32 na = acc + loc[i];
    if (acc < N_PRE && na >= N_PRE) {
      u32 bin = (u32)(t * 8 + i);
      T1[b] = bin; Base1[b] = acc;
      if (na <= CSORT) T2[b] = (bin << 11) | 0x7FFu;  // whole bin fits
      else need2[b] = 1;                               // refine (rare)
    }
    acc = na;
  }
}

__global__ __launch_bounds__(256) void k_hist2(
    const u64* __restrict__ keys, const u32* __restrict__ T1,
    const u32* __restrict__ need2, u32* __restrict__ hist)
{
  int b = blockIdx.y;
  if (!need2[b]) return;
  u32 t1 = T1[b];
  __shared__ u32 lh[2048];
  int t = threadIdx.x;
#pragma unroll
  for (int i = 0; i < 8; ++i) lh[t + i * 256] = 0;
  __syncthreads();
#pragma unroll
  for (int k = 0; k < 4; ++k) {
    int i = blockIdx.x * 1024 + k * 256 + t;
    u64 key = keys[(size_t)b * N_ANC + i];
    if ((u32)(key >> 53) == t1) atomicAdd(&lh[(u32)(key >> 42) & 0x7FFu], 1u);
  }
  __syncthreads();
#pragma unroll
  for (int i = 0; i < 8; ++i) {
    u32 v = lh[t + i * 256];
    if (v) atomicAdd(&hist[b * 2048 + t + i * 256], v);
  }
}

__global__ __launch_bounds__(256) void k_pick2(
    const u32* __restrict__ hist, const u32* __restrict__ T1,
    const u32* __restrict__ Base1, const u32* __restrict__ need2,
    u32* __restrict__ T2)
{
  int b = blockIdx.x, t = threadIdx.x;
  if (!need2[b]) return;
  const u32* h = hist + b * 2048;
  __shared__ u32 part[256], pre[256];
  u32 loc[8], s = 0;
#pragma unroll
  for (int i = 0; i < 8; ++i) { loc[i] = h[t * 8 + i]; s += loc[i]; }
  part[t] = s;
  __syncthreads();
  if (t == 0) { u32 acc = Base1[b]; for (int i = 0; i < 256; ++i) { pre[i] = acc; acc += part[i]; } }
  __syncthreads();
  u32 acc = pre[t];
#pragma unroll
  for (int i = 0; i < 8; ++i) {
    u32 na = acc + loc[i];
    if (acc < N_PRE && na >= N_PRE) T2[b] = (T1[b] << 11) | (u32)(t * 8 + i);
    acc = na;
  }
}

__global__ __launch_bounds__(256) void k_compact(
    const u64* __restrict__ keys, const u32* __restrict__ T2,
    u64* __restrict__ cand, u32* __restrict__ cnt)
{
  int b = blockIdx.y;
  int i = blockIdx.x * 256 + threadIdx.x;
  u64 key = keys[(size_t)b * N_ANC + i];
  if ((u32)(key >> 42) <= T2[b]) {
    u32 pos = atomicAdd(&cnt[b], 1u);
    if (pos < CSORT) cand[(size_t)b * CSORT + pos] = key;
  }
}

// ---------------- bitonic sort of 16384 ---------------------------------
__global__ __launch_bounds__(1024) void k_sort_tile(u64* __restrict__ a)
{
  int b = blockIdx.y, base = blockIdx.x * TILE;
  u64* p = a + (size_t)b * CSORT;
  __shared__ u64 lds[TILE];
  for (int i = threadIdx.x; i < TILE; i += 1024) lds[i] = p[base + i];
  __syncthreads();
  for (int k = 2; k <= TILE; k <<= 1) {
    for (int j = k >> 1; j > 0; j >>= 1) {
      for (int q = threadIdx.x; q < TILE / 2; q += 1024) {
        int i = ((q & ~(j - 1)) << 1) | (q & (j - 1));
        int l = i | j;
        bool asc = (((base + i) & k) == 0);
        u64 x = lds[i], y = lds[l];
        if ((x > y) == asc) { lds[i] = y; lds[l] = x; }
      }
      __syncthreads();
    }
  }
  for (int i = threadIdx.x; i < TILE; i += 1024) p[base + i] = lds[i];
}

__global__ __launch_bounds__(256) void k_sort_pass(u64* __restrict__ a, int k, int j)
{
  int b = blockIdx.y;
  int q = blockIdx.x * 256 + threadIdx.x;
  int i = ((q & ~(j - 1)) << 1) | (q & (j - 1));
  int l = i | j;
  bool asc = ((i & k) == 0);
  u64* p = a + (size_t)b * CSORT;
  u64 x = p[i], y = p[l];
  if ((x > y) == asc) { p[i] = y; p[l] = x; }
}

// final local merge + fused gather (reads sorted keys straight from LDS)
__global__ __launch_bounds__(1024) void k_sort_local_gather(
    const u64* __restrict__ cand, const float4* __restrict__ boxes,
    float4* __restrict__ gbox, u64* __restrict__ deadm)
{
  int b = blockIdx.y, base = blockIdx.x * TILE;
  const u64* p = cand + (size_t)b * CSORT;
  __shared__ u64 lds[TILE];
  for (int i = threadIdx.x; i < TILE; i += 1024) lds[i] = p[base + i];
  __syncthreads();
  for (int j = TILE >> 1; j > 0; j >>= 1) {
    for (int q = threadIdx.x; q < TILE / 2; q += 1024) {
      int i = ((q & ~(j - 1)) << 1) | (q & (j - 1));
      int l = i | j;
      u64 x = lds[i], y = lds[l];
      if (x > y) { lds[i] = y; lds[l] = x; }   // k=16384: all ascending
    }
    __syncthreads();
  }
  int lane = threadIdx.x & 63;
  for (int i = threadIdx.x; i < TILE; i += 1024) {
    int gi = base + i;                 // wave-uniform 64-aligned chunks
    if (gi < MAXC) {
      u64 key = lds[i];
      bool valid = ((u32)(key >> 32) < 0x80000000u) && (gi < N_PRE);
      float4 bx = make_float4(0.f, 0.f, 0.f, 0.f);
      if (valid) bx = boxes[(size_t)b * N_ANC + (u32)key];
      gbox[(size_t)b * MAXC + gi] = bx;
      u64 dm = __ballot(!valid);
      if (lane == 0) deadm[b * NDW + (gi >> 6)] = dm;
    }
  }
}

// ---------------- balanced 64x64 mask tile ------------------------------
__device__ __forceinline__ void segmask_tile(
    int b, int sg, int tile, const float4* __restrict__ gbox,
    u64* __restrict__ smask, u64* __restrict__ smaskT,
    float4* rbox, float* rarea, u64* diag)
{
  int r = tile, rg = 0;
  while (r >= 32 - rg) { r -= 32 - rg; ++rg; }
  int cw = rg + r;
  const float4* gb = gbox + (size_t)b * MAXC + sg * SEG;
  int t = threadIdx.x;
  if (t < 64) { float4 bx = gb[rg * 64 + t]; rbox[t] = bx; rarea[t] = area_of(bx); }
  __syncthreads();
  int wv = t >> 6, lane = t & 63;
  u64* srow = smask + (size_t)(b * NSEG + sg) * SEG * NW + (size_t)rg * 64 * NW;
  float4 cb4 = gb[cw * 64 + lane];
  float ca = area_of(cb4);
  bool isdiag = (cw == rg);
  for (int rr = wv * 16; rr < wv * 16 + 16; ++rr) {
    bool p = iou_gt_a(rbox[rr], cb4, rarea[rr], ca);
    if (isdiag) p = p && (lane > rr);
    u64 m = __ballot(p);
    if (lane == 0) { srow[(size_t)rr * NW + cw] = m; if (isdiag) diag[rr] = m; }
  }
  if (isdiag) {
    __syncthreads();
    if (t < 64) {
      u64 s = 0;
      for (int q = 0; q < 64; ++q) s |= ((diag[q] >> t) & 1ull) << q;
      smaskT[(size_t)(b * NSEG + sg) * SEG + rg * 64 + t] = s;
    }
  }
}

__global__ __launch_bounds__(256) void k_segmask01(
    const float4* __restrict__ gbox, u64* __restrict__ smask,
    u64* __restrict__ smaskT)
{
  __shared__ float4 rbox[64]; __shared__ float rarea[64]; __shared__ u64 diag[64];
  int b = blockIdx.y;
  int sg = blockIdx.x / 528, tile = blockIdx.x % 528;
  segmask_tile(b, sg, tile, gbox, smask, smaskT, rbox, rarea, diag);
}

// cross (sg candidates vs kept list) -- standalone for sg=1
__device__ __forceinline__ void cross_work(
    int b, int sg, int bx, const float4* __restrict__ gbox,
    const float4* __restrict__ keptb, const int* __restrict__ meta,
    u64* __restrict__ deadm, float4* kb, float* ka)
{
  int kc = bx >> 3, cbk = bx & 7;
  int nkept = meta[b * 8 + 0];
  int kbase = kc * 256;
  if (kbase >= nkept) return;
  int kcnt = min(256, nkept - kbase);
  int t = threadIdx.x;
  if (t < kcnt) {
    float4 k4 = keptb[(size_t)b * SEG + kbase + t];
    kb[t] = k4; ka[t] = area_of(k4);
  }
  __syncthreads();
  int gi = sg * SEG + cbk * 256 + t;
  float4 my = gbox[(size_t)b * MAXC + gi];
  float ma = area_of(my);
  bool sup = false;
  for (int kk = 0; kk < kcnt; ++kk) {
    if (iou_gt_a(kb[kk], my, ka[kk], ma)) { sup = true; break; }
  }
  u64 bm = __ballot(sup);
  if ((t & 63) == 0 && bm) atomicOr(&deadm[b * NDW + (gi >> 6)], bm);
}

__global__ __launch_bounds__(256) void k_cross(
    const float4* __restrict__ gbox, const float4* __restrict__ keptb,
    const int* __restrict__ meta, u64* __restrict__ deadm, int sg)
{
  int b = blockIdx.y;
  if (meta[b * 8 + 1]) return;
  __shared__ float4 kb[256]; __shared__ float ka[256];
  cross_work(b, sg, blockIdx.x, gbox, keptb, meta, deadm, kb, ka);
}

// fused cross + gated segmask for sg>=2
__global__ __launch_bounds__(256) void k_crossmask(
    const float4* __restrict__ gbox, const float4* __restrict__ keptb,
    const int* __restrict__ meta, u64* __restrict__ deadm,
    u64* __restrict__ smask, u64* __restrict__ smaskT, int sg)
{
  int b = blockIdx.y;
  if (meta[b * 8 + 1]) return;
  __shared__ float4 kb[256]; __shared__ float ka[256]; __shared__ u64 diag[64];
  if (blockIdx.x < 64) {
    cross_work(b, sg, blockIdx.x, gbox, keptb, meta, deadm, kb, ka);
  } else {
    segmask_tile(b, sg, blockIdx.x - 64, gbox, smask, smaskT,
                 kb, ka, diag);
  }
}

// ---------------- greedy walk: ballot fixpoint + register remv ----------
__global__ __launch_bounds__(1024) void k_walk(
    const float4* __restrict__ gbox, const u64* __restrict__ smask,
    const u64* __restrict__ smaskT, const u64* __restrict__ deadm,
    int* __restrict__ meta, float4* __restrict__ keptb,
    float* __restrict__ out, int sg)
{
  int b = blockIdx.x;
  if (meta[b * 8 + 1]) return;
  int t = threadIdx.x, wv = t >> 6, lane = t & 63;

  __shared__ u64 rowbuf[2][2048];   // 32 KiB: 64 rows x 32 words, dbuf
  __shared__ u64 stbuf[2][64];
  __shared__ float4 bbox[2][64];
  __shared__ u64 sdead[2];
  __shared__ int s_stop, s_nkept;

  const u64* smb = smask + (size_t)(b * NSEG + sg) * SEG * NW;
  const u64* stb = smaskT + (size_t)(b * NSEG + sg) * SEG;
  const u64* dmb = deadm + b * NDW + sg * NW;
  const float4* gb = gbox + (size_t)b * MAXC + sg * SEG;
  float4* kbuf = keptb + (size_t)b * SEG;
  float4* ob = (float4*)(out + (size_t)b * N_POST * 4);
  float* om = out + (size_t)B_SZ * N_POST * 4 + (size_t)b * N_POST;

  for (int i = t; i < 2048; i += 1024) rowbuf[0][i] = smb[i];
  if (t < 64) { stbuf[0][t] = stb[t]; bbox[0][t] = gb[t]; }
  if (t == 0) { sdead[0] = dmb[0]; s_stop = 0; s_nkept = meta[b * 8 + 0]; }
  __syncthreads();

  u64 myrem = 0;  // wave0 lane l (<32) owns suppression word l
  for (int g = 0; g < NW; ++g) {
    int cb = g & 1, nb = cb ^ 1;
    if (wv > 0) {                       // prefetch group g+1
      if (g < NW - 1) {
        for (int i = t - 64; i < 2048; i += 960)
          rowbuf[nb][i] = smb[(size_t)(g + 1) * 2048 + i];
        int j = t - 64;
        if (j < 64) { stbuf[nb][j] = stb[(g + 1) * 64 + j];
                      bbox[nb][j] = gb[(g + 1) * 64 + j]; }
        if (t == 64) sdead[nb] = dmb[g + 1];
      }
    } else {                            // wave 0: resolve group g
      int l = lane;
      u64 S = stbuf[cb][l];
      u64 remg = shfl64(myrem, g);
      u64 avail = ~(remg | sdead[cb]);
      u64 km = 0;
      while (avail) {
        bool al = (avail >> l) & 1;
        u64 newk = __ballot(al && (S & avail) == 0ull);
        u64 nd   = __ballot(al && (S & newk) != 0ull);
        km |= newk;
        avail &= ~(newk | nd);
      }
      int nk0 = s_nkept;
      int rem = N_POST - nk0;
      int kc = __popcll(km);
      bool stop = (kc >= rem);
      int rank = __popcll(km & ((1ull << l) - 1ull));
      if (((km >> l) & 1) && rank < rem) {
        float4 bx = bbox[cb][l];
        kbuf[nk0 + rank] = bx;
        ob[nk0 + rank] = bx;            // write output directly
        om[nk0 + rank] = 1.0f;
      }
      if (!stop && l > g && l < 32) {   // fold kept rows into future words
        u64 kk = km;
        const u64* rb = rowbuf[cb];
        while (kk) {
          int i0 = __ffsll((long long)kk) - 1; kk &= kk - 1;
          myrem |= rb[i0 * 32 + l];
        }
      }
      if (l == 0) { s_nkept = nk0 + (stop ? rem : kc); if (stop) s_stop = 1; }
    }
    __syncthreads();
    if (s_stop) break;
  }
  int nk = s_nkept;
  bool fin = s_stop || (sg == NSEG - 1);
  if (t == 0) { meta[b * 8 + 0] = nk; if (fin) meta[b * 8 + 1] = 1; }
  if (fin) {  // zero-pad tail of outputs
    float4 zero = make_float4(0.f, 0.f, 0.f, 0.f);
    for (int i = nk + t; i < N_POST; i += 1024) { ob[i] = zero; om[i] = 0.0f; }
  }
}

extern "C" void kernel_launch(void* const* d_in, const int* in_sizes, int n_in,
                              void* d_out, int out_size, void* d_ws, size_t ws_size,
                              hipStream_t stream)
{
  const int*   imh     = (const int*)d_in[0];
  const int*   imw     = (const int*)d_in[1];
  const float* anchors = (const float*)d_in[2];
  const float* loc     = (const float*)d_in[3];
  const float* obj     = (const float*)d_in[4];
  float* out = (float*)d_out;

  char* ws = (char*)d_ws;
  size_t off = 0;
  float4* boxes = (float4*)(ws + off); off += (size_t)B_SZ * N_ANC * 16;
  u64*    keys  = (u64*)   (ws + off); off += (size_t)B_SZ * N_ANC * 8;
  u64*    cand  = (u64*)   (ws + off); off += (size_t)B_SZ * CSORT * 8;
  float4* gbox  = (float4*)(ws + off); off += (size_t)B_SZ * MAXC * 16;
  float4* keptb = (float4*)(ws + off); off += (size_t)B_SZ * SEG * 16;
  u64*    deadm = (u64*)   (ws + off); off += (size_t)B_SZ * NDW * 8;
  off = (off + 255) & ~(size_t)255;
  char*   zr    = ws + off;
  u32*    hist1 = (u32*)(zr);
  u32*    hist2 = (u32*)(zr + 65536);
  u32*    T1    = (u32*)(zr + 131072);
  u32*    Base1 = (u32*)(zr + 131072 + 32);
  u32*    T2    = (u32*)(zr + 131072 + 64);
  u32*    need2 = (u32*)(zr + 131072 + 96);
  u32*    cnt   = (u32*)(zr + 131072 + 128);
  int*    meta  = (int*)(zr + 131072 + 160);
  size_t  zr_sz = 131072 + 160 + B_SZ * 8 * 4;
  off += (zr_sz + 255) & ~(size_t)255;
  u64*    smask  = (u64*)(ws + off); off += (size_t)B_SZ * NSEG * SEG * NW * 8;
  u64*    smaskT = (u64*)(ws + off); off += (size_t)B_SZ * NSEG * SEG * 8;

  hipMemsetAsync(zr, 0, zr_sz, stream);

  k_decode<<<dim3(144, B_SZ), 256, 0, stream>>>(imh, imw, anchors, loc, obj,
                                                boxes, keys, hist1);
  k_pick1<<<B_SZ, 256, 0, stream>>>(hist1, T1, Base1, T2, need2);
  k_hist2<<<dim3(36, B_SZ), 256, 0, stream>>>(keys, T1, need2, hist2);
  k_pick2<<<B_SZ, 256, 0, stream>>>(hist2, T1, Base1, need2, T2);
  k_compact<<<dim3(144, B_SZ), 256, 0, stream>>>(keys, T2, cand, cnt);

  k_sort_tile<<<dim3(2, B_SZ), 1024, 0, stream>>>(cand);
  k_sort_pass<<<dim3(CSORT / 2 / 256, B_SZ), 256, 0, stream>>>(cand, 16384, 8192);
  k_sort_local_gather<<<dim3(2, B_SZ), 1024, 0, stream>>>(cand, boxes, gbox, deadm);

  k_segmask01<<<dim3(1056, B_SZ), 256, 0, stream>>>(gbox, smask, smaskT);

  k_walk<<<B_SZ, 1024, 0, stream>>>(gbox, smask, smaskT, deadm, meta, keptb, out, 0);
  k_cross<<<dim3(64, B_SZ), 256, 0, stream>>>(gbox, keptb, meta, deadm, 1);
  k_walk<<<B_SZ, 1024, 0, stream>>>(gbox, smask, smaskT, deadm, meta, keptb, out, 1);
  for (int sg = 2; sg < NSEG; ++sg) {
    k_crossmask<<<dim3(592, B_SZ), 256, 0, stream>>>(gbox, keptb, meta, deadm,
                                                     smask, smaskT, sg);
    k_walk<<<B_SZ, 1024, 0, stream>>>(gbox, smask, smaskT, deadm, meta, keptb, out, sg);
  }
}

// Round 6
// 351.777 us; speedup vs baseline: 6.5416x; 1.1572x over previous
//
#include <hip/hip_runtime.h>

typedef unsigned long long u64;
typedef unsigned int u32;

#define B_SZ   8
#define N_ANC  36864
#define N_PRE  12000
#define N_POST 2000
#define SEG    2048
#define NSEG   6
#define MAXC   (SEG * NSEG)   // 12288
#define NW     (SEG / 64)     // 32 u64 words per mask row
#define NDW    (MAXC / 64)    // 192 dead-mask words per batch
#define CSORT  16384
#define TILE   8192

__device__ __forceinline__ float area_of(float4 p) {
  return __fmul_rn(__fsub_rn(p.z, p.x), __fsub_rn(p.w, p.y));
}

// bit-exact replication: a0 = area(first reference arg), a1 = area(second)
__device__ __forceinline__ bool iou_gt_a(float4 p, float4 q, float a0, float a1) {
  float ix1 = fmaxf(p.x, q.x), iy1 = fmaxf(p.y, q.y);
  float ix2 = fminf(p.z, q.z), iy2 = fminf(p.w, q.w);
  float iw = fmaxf(__fsub_rn(ix2, ix1), 0.0f);
  float ih = fmaxf(__fsub_rn(iy2, iy1), 0.0f);
  float inter = __fmul_rn(iw, ih);
  float den = fmaxf(__fsub_rn(__fadd_rn(a0, a1), inter), 1e-9f);
  return (inter / den) > 0.7f;
}

// ---------------- decode + score + keys + fused level-1 histogram -------
__global__ __launch_bounds__(256) void k_decode(
    const int* __restrict__ imh_p, const int* __restrict__ imw_p,
    const float* __restrict__ anchors, const float* __restrict__ loc,
    const float* __restrict__ obj, float4* __restrict__ boxes,
    u64* __restrict__ keys, u32* __restrict__ hist)
{
  __shared__ u32 lh[2048];
  int t = threadIdx.x;
#pragma unroll
  for (int i = 0; i < 8; ++i) lh[t + i * 256] = 0;
  __syncthreads();

  int n = blockIdx.x * 256 + t;
  int b = blockIdx.y;
  float a0 = anchors[n * 4 + 0], a1 = anchors[n * 4 + 1];
  float a2 = anchors[n * 4 + 2], a3 = anchors[n * 4 + 3];
  size_t off = (size_t)b * N_ANC + n;
  float l0 = loc[off * 4 + 0], l1 = loc[off * 4 + 1];
  float l2 = loc[off * 4 + 2], l3 = loc[off * 4 + 3];

  float w  = __fsub_rn(a2, a0);
  float h  = __fsub_rn(a3, a1);
  float cx = __fadd_rn(a0, __fmul_rn(0.5f, w));
  float cy = __fadd_rn(a1, __fmul_rn(0.5f, h));
  float pcx = __fadd_rn(__fmul_rn(l0, w), cx);
  float pcy = __fadd_rn(__fmul_rn(l1, h), cy);
  float pw  = __fmul_rn(expf(l2), w);
  float ph  = __fmul_rn(expf(l3), h);
  float imw = (float)imw_p[0], imh = (float)imh_p[0];
  float hx = __fmul_rn(0.5f, pw), hy = __fmul_rn(0.5f, ph);
  float x1 = fminf(fmaxf(__fsub_rn(pcx, hx), 0.0f), imw);
  float y1 = fminf(fmaxf(__fsub_rn(pcy, hy), 0.0f), imh);
  float x2 = fminf(fmaxf(__fadd_rn(pcx, hx), 0.0f), imw);
  float y2 = fminf(fmaxf(__fadd_rn(pcy, hy), 0.0f), imh);
  boxes[off] = make_float4(x1, y1, x2, y2);

  bool valid = (__fsub_rn(x2, x1) >= 16.0f) && (__fsub_rn(y2, y1) >= 16.0f);

  float o0 = obj[off * 2 + 0], o1 = obj[off * 2 + 1];
  float m  = fmaxf(o0, o1);
  float e0 = expf(__fsub_rn(o0, m));
  float e1 = expf(__fsub_rn(o1, m));
  float s  = e1 / __fadd_rn(e0, e1);
  float sc = valid ? s : -1e9f;

  u32 u  = __float_as_uint(sc);
  u32 fk = (u & 0x80000000u) ? ~u : (u | 0x80000000u);
  u32 sk = ~fk;  // ascending u64 == descending score, stable by index
  u64 key = ((u64)sk << 32) | (u32)n;
  keys[off] = key;
  atomicAdd(&lh[(u32)(key >> 53)], 1u);
  __syncthreads();
#pragma unroll
  for (int i = 0; i < 8; ++i) {
    u32 v = lh[t + i * 256];
    if (v) atomicAdd(&hist[b * 2048 + t + i * 256], v);
  }
}

// ---------------- pick level-1 threshold (gate level 2 on overflow) -----
__global__ __launch_bounds__(256) void k_pick1(
    const u32* __restrict__ hist, u32* __restrict__ T1, u32* __restrict__ Base1,
    u32* __restrict__ T2, u32* __restrict__ need2)
{
  int b = blockIdx.x, t = threadIdx.x;
  const u32* h = hist + b * 2048;
  __shared__ u32 part[256], pre[256];
  u32 loc[8], s = 0;
#pragma unroll
  for (int i = 0; i < 8; ++i) { loc[i] = h[t * 8 + i]; s += loc[i]; }
  part[t] = s;
  __syncthreads();
  if (t == 0) { u32 acc = 0; for (int i = 0; i < 256; ++i) { pre[i] = acc; acc += part[i]; } }
  __syncthreads();
  u32 acc = pre[t];
#pragma unroll
  for (int i = 0; i < 8; ++i) {
    u32 na = acc + loc[i];
    if (acc < N_PRE && na >= N_PRE) {
      u32 bin = (u32)(t * 8 + i);
      T1[b] = bin; Base1[b] = acc;
      if (na <= CSORT) T2[b] = (bin << 11) | 0x7FFu;  // whole bin fits
      else need2[b] = 1;                               // refine (rare)
    }
    acc = na;
  }
}

__global__ __launch_bounds__(256) void k_hist2(
    const u64* __restrict__ keys, const u32* __restrict__ T1,
    const u32* __restrict__ need2, u32* __restrict__ hist)
{
  int b = blockIdx.y;
  if (!need2[b]) return;
  u32 t1 = T1[b];
  __shared__ u32 lh[2048];
  int t = threadIdx.x;
#pragma unroll
  for (int i = 0; i < 8; ++i) lh[t + i * 256] = 0;
  __syncthreads();
#pragma unroll
  for (int k = 0; k < 4; ++k) {
    int i = blockIdx.x * 1024 + k * 256 + t;
    u64 key = keys[(size_t)b * N_ANC + i];
    if ((u32)(key >> 53) == t1) atomicAdd(&lh[(u32)(key >> 42) & 0x7FFu], 1u);
  }
  __syncthreads();
#pragma unroll
  for (int i = 0; i < 8; ++i) {
    u32 v = lh[t + i * 256];
    if (v) atomicAdd(&hist[b * 2048 + t + i * 256], v);
  }
}

__global__ __launch_bounds__(256) void k_pick2(
    const u32* __restrict__ hist, const u32* __restrict__ T1,
    const u32* __restrict__ Base1, const u32* __restrict__ need2,
    u32* __restrict__ T2)
{
  int b = blockIdx.x, t = threadIdx.x;
  if (!need2[b]) return;
  const u32* h = hist + b * 2048;
  __shared__ u32 part[256], pre[256];
  u32 loc[8], s = 0;
#pragma unroll
  for (int i = 0; i < 8; ++i) { loc[i] = h[t * 8 + i]; s += loc[i]; }
  part[t] = s;
  __syncthreads();
  if (t == 0) { u32 acc = Base1[b]; for (int i = 0; i < 256; ++i) { pre[i] = acc; acc += part[i]; } }
  __syncthreads();
  u32 acc = pre[t];
#pragma unroll
  for (int i = 0; i < 8; ++i) {
    u32 na = acc + loc[i];
    if (acc < N_PRE && na >= N_PRE) T2[b] = (T1[b] << 11) | (u32)(t * 8 + i);
    acc = na;
  }
}

__global__ __launch_bounds__(256) void k_compact(
    const u64* __restrict__ keys, const u32* __restrict__ T2,
    u64* __restrict__ cand, u32* __restrict__ cnt)
{
  int b = blockIdx.y;
  int i = blockIdx.x * 256 + threadIdx.x;
  u64 key = keys[(size_t)b * N_ANC + i];
  if ((u32)(key >> 42) <= T2[b]) {
    u32 pos = atomicAdd(&cnt[b], 1u);
    if (pos < CSORT) cand[(size_t)b * CSORT + pos] = key;
  }
}

// ---------------- bitonic sort of 16384 ---------------------------------
__global__ __launch_bounds__(1024) void k_sort_tile(u64* __restrict__ a)
{
  int b = blockIdx.y, base = blockIdx.x * TILE;
  u64* p = a + (size_t)b * CSORT;
  __shared__ u64 lds[TILE];
  for (int i = threadIdx.x; i < TILE; i += 1024) lds[i] = p[base + i];
  __syncthreads();
  for (int k = 2; k <= TILE; k <<= 1) {
    for (int j = k >> 1; j > 0; j >>= 1) {
      for (int q = threadIdx.x; q < TILE / 2; q += 1024) {
        int i = ((q & ~(j - 1)) << 1) | (q & (j - 1));
        int l = i | j;
        bool asc = (((base + i) & k) == 0);
        u64 x = lds[i], y = lds[l];
        if ((x > y) == asc) { lds[i] = y; lds[l] = x; }
      }
      __syncthreads();
    }
  }
  for (int i = threadIdx.x; i < TILE; i += 1024) p[base + i] = lds[i];
}

__global__ __launch_bounds__(256) void k_sort_pass(u64* __restrict__ a, int k, int j)
{
  int b = blockIdx.y;
  int q = blockIdx.x * 256 + threadIdx.x;
  int i = ((q & ~(j - 1)) << 1) | (q & (j - 1));
  int l = i | j;
  bool asc = ((i & k) == 0);
  u64* p = a + (size_t)b * CSORT;
  u64 x = p[i], y = p[l];
  if ((x > y) == asc) { p[i] = y; p[l] = x; }
}

// final local merge + fused gather (reads sorted keys straight from LDS)
__global__ __launch_bounds__(1024) void k_sort_local_gather(
    const u64* __restrict__ cand, const float4* __restrict__ boxes,
    float4* __restrict__ gbox, u64* __restrict__ deadm)
{
  int b = blockIdx.y, base = blockIdx.x * TILE;
  const u64* p = cand + (size_t)b * CSORT;
  __shared__ u64 lds[TILE];
  for (int i = threadIdx.x; i < TILE; i += 1024) lds[i] = p[base + i];
  __syncthreads();
  for (int j = TILE >> 1; j > 0; j >>= 1) {
    for (int q = threadIdx.x; q < TILE / 2; q += 1024) {
      int i = ((q & ~(j - 1)) << 1) | (q & (j - 1));
      int l = i | j;
      u64 x = lds[i], y = lds[l];
      if (x > y) { lds[i] = y; lds[l] = x; }   // k=16384: all ascending
    }
    __syncthreads();
  }
  int lane = threadIdx.x & 63;
  for (int i = threadIdx.x; i < TILE; i += 1024) {
    int gi = base + i;                 // wave-uniform 64-aligned chunks
    if (gi < MAXC) {
      u64 key = lds[i];
      bool valid = ((u32)(key >> 32) < 0x80000000u) && (gi < N_PRE);
      float4 bx = make_float4(0.f, 0.f, 0.f, 0.f);
      if (valid) bx = boxes[(size_t)b * N_ANC + (u32)key];
      gbox[(size_t)b * MAXC + gi] = bx;
      u64 dm = __ballot(!valid);
      if (lane == 0) deadm[b * NDW + (gi >> 6)] = dm;
    }
  }
}

// ---------------- balanced 64x64 mask tile ------------------------------
__device__ __forceinline__ void segmask_tile(
    int b, int sg, int tile, const float4* __restrict__ gbox,
    u64* __restrict__ smask, u64* __restrict__ smaskT,
    float4* rbox, float* rarea, u64* diag)
{
  int r = tile, rg = 0;
  while (r >= 32 - rg) { r -= 32 - rg; ++rg; }
  int cw = rg + r;
  const float4* gb = gbox + (size_t)b * MAXC + sg * SEG;
  int t = threadIdx.x;
  if (t < 64) { float4 bx = gb[rg * 64 + t]; rbox[t] = bx; rarea[t] = area_of(bx); }
  __syncthreads();
  int wv = t >> 6, lane = t & 63;
  u64* srow = smask + (size_t)(b * NSEG + sg) * SEG * NW + (size_t)rg * 64 * NW;
  float4 cb4 = gb[cw * 64 + lane];
  float ca = area_of(cb4);
  bool isdiag = (cw == rg);
  for (int rr = wv * 16; rr < wv * 16 + 16; ++rr) {
    bool p = iou_gt_a(rbox[rr], cb4, rarea[rr], ca);
    if (isdiag) p = p && (lane > rr);
    u64 m = __ballot(p);
    if (lane == 0) { srow[(size_t)rr * NW + cw] = m; if (isdiag) diag[rr] = m; }
  }
  if (isdiag) {
    __syncthreads();
    if (t < 64) {
      u64 s = 0;
      for (int q = 0; q < 64; ++q) s |= ((diag[q] >> t) & 1ull) << q;
      smaskT[(size_t)(b * NSEG + sg) * SEG + rg * 64 + t] = s;
    }
  }
}

__global__ __launch_bounds__(256) void k_segmask01(
    const float4* __restrict__ gbox, u64* __restrict__ smask,
    u64* __restrict__ smaskT)
{
  __shared__ float4 rbox[64]; __shared__ float rarea[64]; __shared__ u64 diag[64];
  int b = blockIdx.y;
  int sg = blockIdx.x / 528, tile = blockIdx.x % 528;
  segmask_tile(b, sg, tile, gbox, smask, smaskT, rbox, rarea, diag);
}

// cross (sg candidates vs kept list)
__device__ __forceinline__ void cross_work(
    int b, int sg, int bx, const float4* __restrict__ gbox,
    const float4* __restrict__ keptb, const int* __restrict__ meta,
    u64* __restrict__ deadm, float4* kb, float* ka)
{
  int kc = bx >> 3, cbk = bx & 7;
  int nkept = meta[b * 8 + 0];
  int kbase = kc * 256;
  if (kbase >= nkept) return;
  int kcnt = min(256, nkept - kbase);
  int t = threadIdx.x;
  if (t < kcnt) {
    float4 k4 = keptb[(size_t)b * SEG + kbase + t];
    kb[t] = k4; ka[t] = area_of(k4);
  }
  __syncthreads();
  int gi = sg * SEG + cbk * 256 + t;
  float4 my = gbox[(size_t)b * MAXC + gi];
  float ma = area_of(my);
  bool sup = false;
  for (int kk = 0; kk < kcnt; ++kk) {
    if (iou_gt_a(kb[kk], my, ka[kk], ma)) { sup = true; break; }
  }
  u64 bm = __ballot(sup);
  if ((t & 63) == 0 && bm) atomicOr(&deadm[b * NDW + (gi >> 6)], bm);
}

__global__ __launch_bounds__(256) void k_cross(
    const float4* __restrict__ gbox, const float4* __restrict__ keptb,
    const int* __restrict__ meta, u64* __restrict__ deadm, int sg)
{
  int b = blockIdx.y;
  if (meta[b * 8 + 1]) return;
  __shared__ float4 kb[256]; __shared__ float ka[256];
  cross_work(b, sg, blockIdx.x, gbox, keptb, meta, deadm, kb, ka);
}

// fused cross + gated segmask for sg>=2
__global__ __launch_bounds__(256) void k_crossmask(
    const float4* __restrict__ gbox, const float4* __restrict__ keptb,
    const int* __restrict__ meta, u64* __restrict__ deadm,
    u64* __restrict__ smask, u64* __restrict__ smaskT, int sg)
{
  int b = blockIdx.y;
  if (meta[b * 8 + 1]) return;
  __shared__ float4 kb[256]; __shared__ float ka[256]; __shared__ u64 diag[64];
  if (blockIdx.x < 64) {
    cross_work(b, sg, blockIdx.x, gbox, keptb, meta, deadm, kb, ka);
  } else {
    segmask_tile(b, sg, blockIdx.x - 64, gbox, smask, smaskT,
                 kb, ka, diag);
  }
}

// ---------------- greedy walk: ballot fixpoint + parallel remv OR -------
__global__ __launch_bounds__(1024) void k_walk(
    const float4* __restrict__ gbox, const u64* __restrict__ smask,
    const u64* __restrict__ smaskT, const u64* __restrict__ deadm,
    int* __restrict__ meta, float4* __restrict__ keptb,
    float* __restrict__ out, int sg)
{
  int b = blockIdx.x;
  if (meta[b * 8 + 1]) return;
  int t = threadIdx.x, wv = t >> 6, lane = t & 63;

  __shared__ u64 rowbuf[2][2048];   // 32 KiB: 64 rows x 32 words, dbuf
  __shared__ u64 stbuf[2][64];
  __shared__ float4 bbox[2][64];
  __shared__ u64 sdead[2];
  __shared__ u32 remv[64];          // 2048 suppression bits (u32 halves)
  __shared__ u32 klist[64];
  __shared__ int s_stop, s_nkept, s_kcnt;

  const u64* smb = smask + (size_t)(b * NSEG + sg) * SEG * NW;
  const u64* stb = smaskT + (size_t)(b * NSEG + sg) * SEG;
  const u64* dmb = deadm + b * NDW + sg * NW;
  const float4* gb = gbox + (size_t)b * MAXC + sg * SEG;
  float4* kbuf = keptb + (size_t)b * SEG;
  float4* ob = (float4*)(out + (size_t)b * N_POST * 4);
  float* om = out + (size_t)B_SZ * N_POST * 4 + (size_t)b * N_POST;

  for (int i = t; i < 2048; i += 1024) rowbuf[0][i] = smb[i];
  if (t < 64) { stbuf[0][t] = stb[t]; bbox[0][t] = gb[t]; remv[t] = 0; }
  if (t == 0) { sdead[0] = dmb[0]; s_stop = 0; s_nkept = meta[b * 8 + 0]; }
  __syncthreads();

  for (int g = 0; g < NW; ++g) {
    int cb = g & 1, nb = cb ^ 1;
    if (wv > 0) {                       // waves 1..15: prefetch group g+1
      if (g < NW - 1) {
        for (int i = t - 64; i < 2048; i += 960)
          rowbuf[nb][i] = smb[(size_t)(g + 1) * 2048 + i];
        int j = t - 64;
        if (j < 64) { stbuf[nb][j] = stb[(g + 1) * 64 + j];
                      bbox[nb][j] = gb[(g + 1) * 64 + j]; }
        if (t == 64) sdead[nb] = dmb[g + 1];
      }
    } else {                            // wave 0: resolve group g
      int l = lane;
      u64 S = stbuf[cb][l];
      u64 remg = ((u64)remv[2 * g + 1] << 32) | remv[2 * g];
      u64 avail = ~(remg | sdead[cb]);
      u64 km = 0;
      while (avail) {
        bool al = (avail >> l) & 1;
        u64 newk = __ballot(al && (S & avail) == 0ull);
        u64 nd   = __ballot(al && (S & newk) != 0ull);
        km |= newk;
        avail &= ~(newk | nd);
      }
      int nk0 = s_nkept;
      int rem = N_POST - nk0;
      int kc = __popcll(km);
      bool stop = (kc >= rem);
      int rank = __popcll(km & ((1ull << l) - 1ull));
      if (((km >> l) & 1) && rank < rem) {
        float4 bx = bbox[cb][l];
        kbuf[nk0 + rank] = bx;
        ob[nk0 + rank] = bx;            // write output directly
        om[nk0 + rank] = 1.0f;
        klist[rank] = (u32)l;
      }
      if (l == 0) {
        int eff = stop ? rem : kc;
        s_kcnt = eff;
        s_nkept = nk0 + eff;
        if (stop) s_stop = 1;
      }
    }
    __syncthreads();
    if (s_stop) break;
    // stage C: all 1024 threads OR kept rows' future words into remv
    int kcnt = s_kcnt;
    u32* rb32 = (u32*)rowbuf[cb];
    for (int i = t; i < kcnt * 64; i += 1024) {
      int kk = i >> 6, w = i & 63;
      if ((w >> 1) > g) {
        u32 v = rb32[klist[kk] * 64 + w];
        if (v) atomicOr(&remv[w], v);
      }
    }
    __syncthreads();
  }
  int nk = s_nkept;
  bool fin = s_stop || (sg == NSEG - 1);
  if (t == 0) { meta[b * 8 + 0] = nk; if (fin) meta[b * 8 + 1] = 1; }
  if (fin) {  // zero-pad tail of outputs
    float4 zero = make_float4(0.f, 0.f, 0.f, 0.f);
    for (int i = nk + t; i < N_POST; i += 1024) { ob[i] = zero; om[i] = 0.0f; }
  }
}

extern "C" void kernel_launch(void* const* d_in, const int* in_sizes, int n_in,
                              void* d_out, int out_size, void* d_ws, size_t ws_size,
                              hipStream_t stream)
{
  const int*   imh     = (const int*)d_in[0];
  const int*   imw     = (const int*)d_in[1];
  const float* anchors = (const float*)d_in[2];
  const float* loc     = (const float*)d_in[3];
  const float* obj     = (const float*)d_in[4];
  float* out = (float*)d_out;

  char* ws = (char*)d_ws;
  size_t off = 0;
  float4* boxes = (float4*)(ws + off); off += (size_t)B_SZ * N_ANC * 16;
  u64*    keys  = (u64*)   (ws + off); off += (size_t)B_SZ * N_ANC * 8;
  u64*    cand  = (u64*)   (ws + off); off += (size_t)B_SZ * CSORT * 8;
  float4* gbox  = (float4*)(ws + off); off += (size_t)B_SZ * MAXC * 16;
  float4* keptb = (float4*)(ws + off); off += (size_t)B_SZ * SEG * 16;
  u64*    deadm = (u64*)   (ws + off); off += (size_t)B_SZ * NDW * 8;
  off = (off + 255) & ~(size_t)255;
  char*   zr    = ws + off;
  u32*    hist1 = (u32*)(zr);
  u32*    hist2 = (u32*)(zr + 65536);
  u32*    T1    = (u32*)(zr + 131072);
  u32*    Base1 = (u32*)(zr + 131072 + 32);
  u32*    T2    = (u32*)(zr + 131072 + 64);
  u32*    need2 = (u32*)(zr + 131072 + 96);
  u32*    cnt   = (u32*)(zr + 131072 + 128);
  int*    meta  = (int*)(zr + 131072 + 160);
  size_t  zr_sz = 131072 + 160 + B_SZ * 8 * 4;
  off += (zr_sz + 255) & ~(size_t)255;
  u64*    smask  = (u64*)(ws + off); off += (size_t)B_SZ * NSEG * SEG * NW * 8;
  u64*    smaskT = (u64*)(ws + off); off += (size_t)B_SZ * NSEG * SEG * 8;

  hipMemsetAsync(zr, 0, zr_sz, stream);

  k_decode<<<dim3(144, B_SZ), 256, 0, stream>>>(imh, imw, anchors, loc, obj,
                                                boxes, keys, hist1);
  k_pick1<<<B_SZ, 256, 0, stream>>>(hist1, T1, Base1, T2, need2);
  k_hist2<<<dim3(36, B_SZ), 256, 0, stream>>>(keys, T1, need2, hist2);
  k_pick2<<<B_SZ, 256, 0, stream>>>(hist2, T1, Base1, need2, T2);
  k_compact<<<dim3(144, B_SZ), 256, 0, stream>>>(keys, T2, cand, cnt);

  k_sort_tile<<<dim3(2, B_SZ), 1024, 0, stream>>>(cand);
  k_sort_pass<<<dim3(CSORT / 2 / 256, B_SZ), 256, 0, stream>>>(cand, 16384, 8192);
  k_sort_local_gather<<<dim3(2, B_SZ), 1024, 0, stream>>>(cand, boxes, gbox, deadm);

  k_segmask01<<<dim3(1056, B_SZ), 256, 0, stream>>>(gbox, smask, smaskT);

  k_walk<<<B_SZ, 1024, 0, stream>>>(gbox, smask, smaskT, deadm, meta, keptb, out, 0);
  k_cross<<<dim3(64, B_SZ), 256, 0, stream>>>(gbox, keptb, meta, deadm, 1);
  k_walk<<<B_SZ, 1024, 0, stream>>>(gbox, smask, smaskT, deadm, meta, keptb, out, 1);
  for (int sg = 2; sg < NSEG; ++sg) {
    k_crossmask<<<dim3(592, B_SZ), 256, 0, stream>>>(gbox, keptb, meta, deadm,
                                                     smask, smaskT, sg);
    k_walk<<<B_SZ, 1024, 0, stream>>>(gbox, smask, smaskT, deadm, meta, keptb, out, sg);
  }
}

// Round 7
// 297.838 us; speedup vs baseline: 7.7263x; 1.1811x over previous
//
#include <hip/hip_runtime.h>

typedef unsigned long long u64;
typedef unsigned int u32;

#define B_SZ   8
#define N_ANC  36864
#define N_PRE  12000
#define N_POST 2000
#define SEG    2048
#define NSEG   6
#define MAXC   (SEG * NSEG)   // 12288
#define NW     (SEG / 64)     // 32 u64 words per mask row
#define NDW    (MAXC / 64)    // 192 dead-mask words per batch

__device__ __forceinline__ float area_of(float4 p) {
  return __fmul_rn(__fsub_rn(p.z, p.x), __fsub_rn(p.w, p.y));
}

// bit-exact replication: a0 = area(first reference arg), a1 = area(second)
__device__ __forceinline__ bool iou_gt_a(float4 p, float4 q, float a0, float a1) {
  float ix1 = fmaxf(p.x, q.x), iy1 = fmaxf(p.y, q.y);
  float ix2 = fminf(p.z, q.z), iy2 = fminf(p.w, q.w);
  float iw = fmaxf(__fsub_rn(ix2, ix1), 0.0f);
  float ih = fmaxf(__fsub_rn(iy2, iy1), 0.0f);
  float inter = __fmul_rn(iw, ih);
  float den = fmaxf(__fsub_rn(__fadd_rn(a0, a1), inter), 1e-9f);
  return (inter / den) > 0.7f;
}

// ---------------- decode + score + keys + fused level-1 histogram -------
__global__ __launch_bounds__(256) void k_decode(
    const int* __restrict__ imh_p, const int* __restrict__ imw_p,
    const float* __restrict__ anchors, const float* __restrict__ loc,
    const float* __restrict__ obj, float4* __restrict__ boxes,
    u64* __restrict__ keys, u32* __restrict__ hist)
{
  __shared__ u32 lh[2048];
  int t = threadIdx.x;
#pragma unroll
  for (int i = 0; i < 8; ++i) lh[t + i * 256] = 0;
  __syncthreads();

  int n = blockIdx.x * 256 + t;
  int b = blockIdx.y;
  float a0 = anchors[n * 4 + 0], a1 = anchors[n * 4 + 1];
  float a2 = anchors[n * 4 + 2], a3 = anchors[n * 4 + 3];
  size_t off = (size_t)b * N_ANC + n;
  float l0 = loc[off * 4 + 0], l1 = loc[off * 4 + 1];
  float l2 = loc[off * 4 + 2], l3 = loc[off * 4 + 3];

  float w  = __fsub_rn(a2, a0);
  float h  = __fsub_rn(a3, a1);
  float cx = __fadd_rn(a0, __fmul_rn(0.5f, w));
  float cy = __fadd_rn(a1, __fmul_rn(0.5f, h));
  float pcx = __fadd_rn(__fmul_rn(l0, w), cx);
  float pcy = __fadd_rn(__fmul_rn(l1, h), cy);
  float pw  = __fmul_rn(expf(l2), w);
  float ph  = __fmul_rn(expf(l3), h);
  float imw = (float)imw_p[0], imh = (float)imh_p[0];
  float hx = __fmul_rn(0.5f, pw), hy = __fmul_rn(0.5f, ph);
  float x1 = fminf(fmaxf(__fsub_rn(pcx, hx), 0.0f), imw);
  float y1 = fminf(fmaxf(__fsub_rn(pcy, hy), 0.0f), imh);
  float x2 = fminf(fmaxf(__fadd_rn(pcx, hx), 0.0f), imw);
  float y2 = fminf(fmaxf(__fadd_rn(pcy, hy), 0.0f), imh);
  boxes[off] = make_float4(x1, y1, x2, y2);

  bool valid = (__fsub_rn(x2, x1) >= 16.0f) && (__fsub_rn(y2, y1) >= 16.0f);

  float o0 = obj[off * 2 + 0], o1 = obj[off * 2 + 1];
  float m  = fmaxf(o0, o1);
  float e0 = expf(__fsub_rn(o0, m));
  float e1 = expf(__fsub_rn(o1, m));
  float s  = e1 / __fadd_rn(e0, e1);
  float sc = valid ? s : -1e9f;

  u32 u  = __float_as_uint(sc);
  u32 fk = (u & 0x80000000u) ? ~u : (u | 0x80000000u);
  u32 sk = ~fk;  // ascending u64 == descending score, stable by index
  u64 key = ((u64)sk << 32) | (u32)n;
  keys[off] = key;
  atomicAdd(&lh[(u32)(key >> 53)], 1u);
  __syncthreads();
#pragma unroll
  for (int i = 0; i < 8; ++i) {
    u32 v = lh[t + i * 256];
    if (v) atomicAdd(&hist[b * 2048 + t + i * 256], v);
  }
}

// ---------------- level-1 pick ------------------------------------------
__global__ __launch_bounds__(256) void k_pick1(
    const u32* __restrict__ hist, u32* __restrict__ T1, u32* __restrict__ Base1)
{
  int b = blockIdx.x, t = threadIdx.x;
  const u32* h = hist + b * 2048;
  __shared__ u32 part[256], pre[256];
  u32 loc[8], s = 0;
#pragma unroll
  for (int i = 0; i < 8; ++i) { loc[i] = h[t * 8 + i]; s += loc[i]; }
  part[t] = s;
  __syncthreads();
  if (t == 0) { u32 acc = 0; for (int i = 0; i < 256; ++i) { pre[i] = acc; acc += part[i]; } }
  __syncthreads();
  u32 acc = pre[t];
#pragma unroll
  for (int i = 0; i < 8; ++i) {
    u32 na = acc + loc[i];
    if (acc < N_PRE && na >= N_PRE) { T1[b] = (u32)(t * 8 + i); Base1[b] = acc; }
    acc = na;
  }
}

// ---------------- level-2 histogram (always on) -------------------------
__global__ __launch_bounds__(256) void k_hist2(
    const u64* __restrict__ keys, const u32* __restrict__ T1,
    u32* __restrict__ hist)
{
  int b = blockIdx.y;
  u32 t1 = T1[b];
  __shared__ u32 lh[2048];
  int t = threadIdx.x;
#pragma unroll
  for (int i = 0; i < 8; ++i) lh[t + i * 256] = 0;
  __syncthreads();
#pragma unroll
  for (int k = 0; k < 4; ++k) {
    int i = blockIdx.x * 1024 + k * 256 + t;
    u64 key = keys[(size_t)b * N_ANC + i];
    if ((u32)(key >> 53) == t1) atomicAdd(&lh[(u32)(key >> 42) & 0x7FFu], 1u);
  }
  __syncthreads();
#pragma unroll
  for (int i = 0; i < 8; ++i) {
    u32 v = lh[t + i * 256];
    if (v) atomicAdd(&hist[b * 2048 + t + i * 256], v);
  }
}

__global__ __launch_bounds__(256) void k_pick2(
    const u32* __restrict__ hist, const u32* __restrict__ T1,
    const u32* __restrict__ Base1, u32* __restrict__ T2)
{
  int b = blockIdx.x, t = threadIdx.x;
  const u32* h = hist + b * 2048;
  __shared__ u32 part[256], pre[256];
  u32 loc[8], s = 0;
#pragma unroll
  for (int i = 0; i < 8; ++i) { loc[i] = h[t * 8 + i]; s += loc[i]; }
  part[t] = s;
  __syncthreads();
  if (t == 0) { u32 acc = Base1[b]; for (int i = 0; i < 256; ++i) { pre[i] = acc; acc += part[i]; } }
  __syncthreads();
  u32 acc = pre[t];
#pragma unroll
  for (int i = 0; i < 8; ++i) {
    u32 na = acc + loc[i];
    if (acc < N_PRE && na >= N_PRE) T2[b] = (T1[b] << 11) | (u32)(t * 8 + i);
    acc = na;
  }
}

__global__ __launch_bounds__(256) void k_compact(
    const u64* __restrict__ keys, const u32* __restrict__ T2,
    u64* __restrict__ cand, u32* __restrict__ cnt)
{
  int b = blockIdx.y;
  int i = blockIdx.x * 256 + threadIdx.x;
  u64 key = keys[(size_t)b * N_ANC + i];
  if ((u32)(key >> 42) <= T2[b]) {
    u32 pos = atomicAdd(&cnt[b], 1u);
    if (pos < MAXC) cand[(size_t)b * MAXC + pos] = key;
  }
}

// ---------------- tile sort: 2048-element bitonic in LDS ----------------
#define SIDX(x) ((x) + ((x) >> 5))   // pad every 32 u64 to break bank aliasing
__global__ __launch_bounds__(1024) void k_sort_tile(u64* __restrict__ a)
{
  int b = blockIdx.y, base = blockIdx.x * 2048;
  u64* p = a + (size_t)b * MAXC + base;
  __shared__ u64 lds[2048 + 64];
  int t = threadIdx.x;
  lds[SIDX(t)] = p[t];
  lds[SIDX(t + 1024)] = p[t + 1024];
  __syncthreads();
  for (int k = 2; k <= 2048; k <<= 1) {
    for (int j = k >> 1; j > 0; j >>= 1) {
      int i = ((t & ~(j - 1)) << 1) | (t & (j - 1));
      int l = i | j;
      bool asc = ((i & k) == 0);
      u64 x = lds[SIDX(i)], y = lds[SIDX(l)];
      if ((x > y) == asc) { lds[SIDX(i)] = y; lds[SIDX(l)] = x; }
      __syncthreads();
    }
  }
  p[t] = lds[SIDX(t)];
  p[t + 1024] = lds[SIDX(t + 1024)];
}

// ---------------- merge-path ranking + fused gather ---------------------
// Each position p in the 6 tile-sorted runs computes its global rank via
// 5 binary searches, then scatters box + dead bit. Keys are unique (real
// keys carry the index; all pads land in run 5 with distinct local ranks),
// so ranks form an exact permutation of [0, MAXC).
__global__ __launch_bounds__(256) void k_merge_gather(
    const u64* __restrict__ cand, const float4* __restrict__ boxes,
    float4* __restrict__ gbox, u64* __restrict__ deadm)
{
  int b = blockIdx.y;
  int p = blockIdx.x * 256 + threadIdx.x;   // [0, MAXC)
  const u64* cb = cand + (size_t)b * MAXC;
  u64 key = cb[p];
  int r = p >> 11;
  int rank = p & 2047;
#pragma unroll
  for (int s = 0; s < NSEG; ++s) {
    if (s == r) continue;
    const u64* run = cb + (s << 11);
    int lo = 0;
#pragma unroll
    for (int step = 2048; step >= 1; step >>= 1) {
      int np = lo + step;
      if (np <= 2048 && run[np - 1] < key) lo = np;
    }
    rank += lo;
  }
  bool valid = ((u32)(key >> 32) < 0x80000000u) && (rank < N_PRE);
  float4 bx = make_float4(0.f, 0.f, 0.f, 0.f);
  if (valid) bx = boxes[(size_t)b * N_ANC + (u32)key];
  gbox[(size_t)b * MAXC + rank] = bx;
  if (!valid) atomicOr(&deadm[b * NDW + (rank >> 6)], 1ull << (rank & 63));
}

// ---------------- balanced 64x64 mask tile ------------------------------
__device__ __forceinline__ void segmask_tile(
    int b, int sg, int tile, const float4* __restrict__ gbox,
    u64* __restrict__ smask, u64* __restrict__ smaskT,
    float4* rbox, float* rarea, u64* diag)
{
  int r = tile, rg = 0;
  while (r >= 32 - rg) { r -= 32 - rg; ++rg; }
  int cw = rg + r;
  const float4* gb = gbox + (size_t)b * MAXC + sg * SEG;
  int t = threadIdx.x;
  if (t < 64) { float4 bx = gb[rg * 64 + t]; rbox[t] = bx; rarea[t] = area_of(bx); }
  __syncthreads();
  int wv = t >> 6, lane = t & 63;
  u64* srow = smask + (size_t)(b * NSEG + sg) * SEG * NW + (size_t)rg * 64 * NW;
  float4 cb4 = gb[cw * 64 + lane];
  float ca = area_of(cb4);
  bool isdiag = (cw == rg);
  for (int rr = wv * 16; rr < wv * 16 + 16; ++rr) {
    bool p = iou_gt_a(rbox[rr], cb4, rarea[rr], ca);
    if (isdiag) p = p && (lane > rr);
    u64 m = __ballot(p);
    if (lane == 0) { srow[(size_t)rr * NW + cw] = m; if (isdiag) diag[rr] = m; }
  }
  if (isdiag) {
    __syncthreads();
    if (t < 64) {
      u64 s = 0;
      for (int q = 0; q < 64; ++q) s |= ((diag[q] >> t) & 1ull) << q;
      smaskT[(size_t)(b * NSEG + sg) * SEG + rg * 64 + t] = s;
    }
  }
}

__global__ __launch_bounds__(256) void k_segmask01(
    const float4* __restrict__ gbox, u64* __restrict__ smask,
    u64* __restrict__ smaskT)
{
  __shared__ float4 rbox[64]; __shared__ float rarea[64]; __shared__ u64 diag[64];
  int b = blockIdx.y;
  int sg = blockIdx.x / 528, tile = blockIdx.x % 528;
  segmask_tile(b, sg, tile, gbox, smask, smaskT, rbox, rarea, diag);
}

// cross (sg candidates vs kept list)
__device__ __forceinline__ void cross_work(
    int b, int sg, int bx, const float4* __restrict__ gbox,
    const float4* __restrict__ keptb, const int* __restrict__ meta,
    u64* __restrict__ deadm, float4* kb, float* ka)
{
  int kc = bx >> 3, cbk = bx & 7;
  int nkept = meta[b * 8 + 0];
  int kbase = kc * 256;
  if (kbase >= nkept) return;
  int kcnt = min(256, nkept - kbase);
  int t = threadIdx.x;
  if (t < kcnt) {
    float4 k4 = keptb[(size_t)b * SEG + kbase + t];
    kb[t] = k4; ka[t] = area_of(k4);
  }
  __syncthreads();
  int gi = sg * SEG + cbk * 256 + t;
  float4 my = gbox[(size_t)b * MAXC + gi];
  float ma = area_of(my);
  bool sup = false;
  for (int kk = 0; kk < kcnt; ++kk) {
    if (iou_gt_a(kb[kk], my, ka[kk], ma)) { sup = true; break; }
  }
  u64 bm = __ballot(sup);
  if ((t & 63) == 0 && bm) atomicOr(&deadm[b * NDW + (gi >> 6)], bm);
}

__global__ __launch_bounds__(256) void k_cross(
    const float4* __restrict__ gbox, const float4* __restrict__ keptb,
    const int* __restrict__ meta, u64* __restrict__ deadm, int sg)
{
  int b = blockIdx.y;
  if (meta[b * 8 + 1]) return;
  __shared__ float4 kb[256]; __shared__ float ka[256];
  cross_work(b, sg, blockIdx.x, gbox, keptb, meta, deadm, kb, ka);
}

// fused cross + gated segmask for sg>=2
__global__ __launch_bounds__(256) void k_crossmask(
    const float4* __restrict__ gbox, const float4* __restrict__ keptb,
    const int* __restrict__ meta, u64* __restrict__ deadm,
    u64* __restrict__ smask, u64* __restrict__ smaskT, int sg)
{
  int b = blockIdx.y;
  if (meta[b * 8 + 1]) return;
  __shared__ float4 kb[256]; __shared__ float ka[256]; __shared__ u64 diag[64];
  if (blockIdx.x < 64) {
    cross_work(b, sg, blockIdx.x, gbox, keptb, meta, deadm, kb, ka);
  } else {
    segmask_tile(b, sg, blockIdx.x - 64, gbox, smask, smaskT,
                 kb, ka, diag);
  }
}

// ---------------- greedy walk: ballot fixpoint + parallel remv OR -------
__global__ __launch_bounds__(1024) void k_walk(
    const float4* __restrict__ gbox, const u64* __restrict__ smask,
    const u64* __restrict__ smaskT, const u64* __restrict__ deadm,
    int* __restrict__ meta, float4* __restrict__ keptb,
    float* __restrict__ out, int sg)
{
  int b = blockIdx.x;
  if (meta[b * 8 + 1]) return;
  int t = threadIdx.x, wv = t >> 6, lane = t & 63;

  __shared__ u64 rowbuf[2][2048];   // 32 KiB: 64 rows x 32 words, dbuf
  __shared__ u64 stbuf[2][64];
  __shared__ float4 bbox[2][64];
  __shared__ u64 sdead[2];
  __shared__ u32 remv[64];          // 2048 suppression bits (u32 halves)
  __shared__ u32 klist[64];
  __shared__ int s_stop, s_nkept, s_kcnt;

  const u64* smb = smask + (size_t)(b * NSEG + sg) * SEG * NW;
  const u64* stb = smaskT + (size_t)(b * NSEG + sg) * SEG;
  const u64* dmb = deadm + b * NDW + sg * NW;
  const float4* gb = gbox + (size_t)b * MAXC + sg * SEG;
  float4* kbuf = keptb + (size_t)b * SEG;
  float4* ob = (float4*)(out + (size_t)b * N_POST * 4);
  float* om = out + (size_t)B_SZ * N_POST * 4 + (size_t)b * N_POST;

  for (int i = t; i < 2048; i += 1024) rowbuf[0][i] = smb[i];
  if (t < 64) { stbuf[0][t] = stb[t]; bbox[0][t] = gb[t]; remv[t] = 0; }
  if (t == 0) { sdead[0] = dmb[0]; s_stop = 0; s_nkept = meta[b * 8 + 0]; }
  __syncthreads();

  for (int g = 0; g < NW; ++g) {
    int cb = g & 1, nb = cb ^ 1;
    if (wv > 0) {                       // waves 1..15: prefetch group g+1
      if (g < NW - 1) {
        for (int i = t - 64; i < 2048; i += 960)
          rowbuf[nb][i] = smb[(size_t)(g + 1) * 2048 + i];
        int j = t - 64;
        if (j < 64) { stbuf[nb][j] = stb[(g + 1) * 64 + j];
                      bbox[nb][j] = gb[(g + 1) * 64 + j]; }
        if (t == 64) sdead[nb] = dmb[g + 1];
      }
    } else {                            // wave 0: resolve group g
      int l = lane;
      u64 S = stbuf[cb][l];
      u64 remg = ((u64)remv[2 * g + 1] << 32) | remv[2 * g];
      u64 avail = ~(remg | sdead[cb]);
      u64 km = 0;
      while (avail) {
        bool al = (avail >> l) & 1;
        u64 newk = __ballot(al && (S & avail) == 0ull);
        u64 nd   = __ballot(al && (S & newk) != 0ull);
        km |= newk;
        avail &= ~(newk | nd);
      }
      int nk0 = s_nkept;
      int rem = N_POST - nk0;
      int kc = __popcll(km);
      bool stop = (kc >= rem);
      int rank = __popcll(km & ((1ull << l) - 1ull));
      if (((km >> l) & 1) && rank < rem) {
        float4 bx = bbox[cb][l];
        kbuf[nk0 + rank] = bx;
        ob[nk0 + rank] = bx;            // write output directly
        om[nk0 + rank] = 1.0f;
        klist[rank] = (u32)l;
      }
      if (l == 0) {
        int eff = stop ? rem : kc;
        s_kcnt = eff;
        s_nkept = nk0 + eff;
        if (stop) s_stop = 1;
      }
    }
    __syncthreads();
    if (s_stop) break;
    // stage C: all 1024 threads OR kept rows' future words into remv
    int kcnt = s_kcnt;
    u32* rb32 = (u32*)rowbuf[cb];
    for (int i = t; i < kcnt * 64; i += 1024) {
      int kk = i >> 6, w = i & 63;
      if ((w >> 1) > g) {
        u32 v = rb32[klist[kk] * 64 + w];
        if (v) atomicOr(&remv[w], v);
      }
    }
    __syncthreads();
  }
  int nk = s_nkept;
  bool fin = s_stop || (sg == NSEG - 1);
  if (t == 0) { meta[b * 8 + 0] = nk; if (fin) meta[b * 8 + 1] = 1; }
  if (fin) {  // zero-pad tail of outputs
    float4 zero = make_float4(0.f, 0.f, 0.f, 0.f);
    for (int i = nk + t; i < N_POST; i += 1024) { ob[i] = zero; om[i] = 0.0f; }
  }
}

extern "C" void kernel_launch(void* const* d_in, const int* in_sizes, int n_in,
                              void* d_out, int out_size, void* d_ws, size_t ws_size,
                              hipStream_t stream)
{
  const int*   imh     = (const int*)d_in[0];
  const int*   imw     = (const int*)d_in[1];
  const float* anchors = (const float*)d_in[2];
  const float* loc     = (const float*)d_in[3];
  const float* obj     = (const float*)d_in[4];
  float* out = (float*)d_out;

  char* ws = (char*)d_ws;
  size_t off = 0;
  float4* boxes = (float4*)(ws + off); off += (size_t)B_SZ * N_ANC * 16;
  u64*    keys  = (u64*)   (ws + off); off += (size_t)B_SZ * N_ANC * 8;
  u64*    cand  = (u64*)   (ws + off); off += (size_t)B_SZ * MAXC * 8;
  float4* gbox  = (float4*)(ws + off); off += (size_t)B_SZ * MAXC * 16;
  float4* keptb = (float4*)(ws + off); off += (size_t)B_SZ * SEG * 16;
  off = (off + 255) & ~(size_t)255;
  char*   zr    = ws + off;  // zeroed region
  u32*    hist1 = (u32*)(zr);
  u32*    hist2 = (u32*)(zr + 65536);
  u32*    T1    = (u32*)(zr + 131072);
  u32*    Base1 = (u32*)(zr + 131072 + 32);
  u32*    T2    = (u32*)(zr + 131072 + 64);
  u32*    cnt   = (u32*)(zr + 131072 + 96);
  int*    meta  = (int*)(zr + 131072 + 128);                 // 8*8 ints
  u64*    deadm = (u64*)(zr + 131072 + 128 + 256);           // 12 KiB
  size_t  zr_sz = 131072 + 128 + 256 + (size_t)B_SZ * NDW * 8;
  off += (zr_sz + 255) & ~(size_t)255;
  u64*    smask  = (u64*)(ws + off); off += (size_t)B_SZ * NSEG * SEG * NW * 8;
  u64*    smaskT = (u64*)(ws + off); off += (size_t)B_SZ * NSEG * SEG * 8;

  hipMemsetAsync(zr, 0, zr_sz, stream);
  hipMemsetAsync(cand, 0xFF, (size_t)B_SZ * MAXC * 8, stream);

  k_decode<<<dim3(144, B_SZ), 256, 0, stream>>>(imh, imw, anchors, loc, obj,
                                                boxes, keys, hist1);
  k_pick1<<<B_SZ, 256, 0, stream>>>(hist1, T1, Base1);
  k_hist2<<<dim3(36, B_SZ), 256, 0, stream>>>(keys, T1, hist2);
  k_pick2<<<B_SZ, 256, 0, stream>>>(hist2, T1, Base1, T2);
  k_compact<<<dim3(144, B_SZ), 256, 0, stream>>>(keys, T2, cand, cnt);

  k_sort_tile<<<dim3(NSEG, B_SZ), 1024, 0, stream>>>(cand);
  k_merge_gather<<<dim3(MAXC / 256, B_SZ), 256, 0, stream>>>(cand, boxes, gbox, deadm);

  k_segmask01<<<dim3(1056, B_SZ), 256, 0, stream>>>(gbox, smask, smaskT);

  k_walk<<<B_SZ, 1024, 0, stream>>>(gbox, smask, smaskT, deadm, meta, keptb, out, 0);
  k_cross<<<dim3(64, B_SZ), 256, 0, stream>>>(gbox, keptb, meta, deadm, 1);
  k_walk<<<B_SZ, 1024, 0, stream>>>(gbox, smask, smaskT, deadm, meta, keptb, out, 1);
  for (int sg = 2; sg < NSEG; ++sg) {
    k_crossmask<<<dim3(592, B_SZ), 256, 0, stream>>>(gbox, keptb, meta, deadm,
                                                     smask, smaskT, sg);
    k_walk<<<B_SZ, 1024, 0, stream>>>(gbox, smask, smaskT, deadm, meta, keptb, out, sg);
  }
}

// Round 8
// 269.326 us; speedup vs baseline: 8.5443x; 1.1059x over previous
//
#include <hip/hip_runtime.h>

typedef unsigned long long u64;
typedef unsigned int u32;

#define B_SZ   8
#define N_ANC  36864
#define N_PRE  12000
#define N_POST 2000
#define SEG    2048
#define NSEG   6
#define MAXC   (SEG * NSEG)   // 12288
#define NW     (SEG / 64)     // 32 u64 words per mask row
#define NDW    (MAXC / 64)    // 192 dead-mask words per batch

__device__ __forceinline__ float area_of(float4 p) {
  return __fmul_rn(__fsub_rn(p.z, p.x), __fsub_rn(p.w, p.y));
}

// bit-exact replication: a0 = area(first reference arg), a1 = area(second)
__device__ __forceinline__ bool iou_gt_a(float4 p, float4 q, float a0, float a1) {
  float ix1 = fmaxf(p.x, q.x), iy1 = fmaxf(p.y, q.y);
  float ix2 = fminf(p.z, q.z), iy2 = fminf(p.w, q.w);
  float iw = fmaxf(__fsub_rn(ix2, ix1), 0.0f);
  float ih = fmaxf(__fsub_rn(iy2, iy1), 0.0f);
  float inter = __fmul_rn(iw, ih);
  float den = fmaxf(__fsub_rn(__fadd_rn(a0, a1), inter), 1e-9f);
  return (inter / den) > 0.7f;
}

// ---------------- decode + score + keys + fused level-1 histogram -------
__global__ __launch_bounds__(256) void k_decode(
    const int* __restrict__ imh_p, const int* __restrict__ imw_p,
    const float* __restrict__ anchors, const float* __restrict__ loc,
    const float* __restrict__ obj, float4* __restrict__ boxes,
    u64* __restrict__ keys, u32* __restrict__ hist)
{
  __shared__ u32 lh[2048];
  int t = threadIdx.x;
#pragma unroll
  for (int i = 0; i < 8; ++i) lh[t + i * 256] = 0;
  __syncthreads();

  int n = blockIdx.x * 256 + t;
  int b = blockIdx.y;
  float a0 = anchors[n * 4 + 0], a1 = anchors[n * 4 + 1];
  float a2 = anchors[n * 4 + 2], a3 = anchors[n * 4 + 3];
  size_t off = (size_t)b * N_ANC + n;
  float l0 = loc[off * 4 + 0], l1 = loc[off * 4 + 1];
  float l2 = loc[off * 4 + 2], l3 = loc[off * 4 + 3];

  float w  = __fsub_rn(a2, a0);
  float h  = __fsub_rn(a3, a1);
  float cx = __fadd_rn(a0, __fmul_rn(0.5f, w));
  float cy = __fadd_rn(a1, __fmul_rn(0.5f, h));
  float pcx = __fadd_rn(__fmul_rn(l0, w), cx);
  float pcy = __fadd_rn(__fmul_rn(l1, h), cy);
  float pw  = __fmul_rn(expf(l2), w);
  float ph  = __fmul_rn(expf(l3), h);
  float imw = (float)imw_p[0], imh = (float)imh_p[0];
  float hx = __fmul_rn(0.5f, pw), hy = __fmul_rn(0.5f, ph);
  float x1 = fminf(fmaxf(__fsub_rn(pcx, hx), 0.0f), imw);
  float y1 = fminf(fmaxf(__fsub_rn(pcy, hy), 0.0f), imh);
  float x2 = fminf(fmaxf(__fadd_rn(pcx, hx), 0.0f), imw);
  float y2 = fminf(fmaxf(__fadd_rn(pcy, hy), 0.0f), imh);
  boxes[off] = make_float4(x1, y1, x2, y2);

  bool valid = (__fsub_rn(x2, x1) >= 16.0f) && (__fsub_rn(y2, y1) >= 16.0f);

  float o0 = obj[off * 2 + 0], o1 = obj[off * 2 + 1];
  float m  = fmaxf(o0, o1);
  float e0 = expf(__fsub_rn(o0, m));
  float e1 = expf(__fsub_rn(o1, m));
  float s  = e1 / __fadd_rn(e0, e1);
  float sc = valid ? s : -1e9f;

  u32 u  = __float_as_uint(sc);
  u32 fk = (u & 0x80000000u) ? ~u : (u | 0x80000000u);
  u32 sk = ~fk;  // ascending u64 == descending score, stable by index
  u64 key = ((u64)sk << 32) | (u32)n;
  keys[off] = key;
  atomicAdd(&lh[(u32)(key >> 53)], 1u);
  __syncthreads();
#pragma unroll
  for (int i = 0; i < 8; ++i) {
    u32 v = lh[t + i * 256];
    if (v) atomicAdd(&hist[b * 2048 + t + i * 256], v);
  }
}

// ---------------- level-1 pick ------------------------------------------
__global__ __launch_bounds__(256) void k_pick1(
    const u32* __restrict__ hist, u32* __restrict__ T1, u32* __restrict__ Base1)
{
  int b = blockIdx.x, t = threadIdx.x;
  const u32* h = hist + b * 2048;
  __shared__ u32 part[256], pre[256];
  u32 loc[8], s = 0;
#pragma unroll
  for (int i = 0; i < 8; ++i) { loc[i] = h[t * 8 + i]; s += loc[i]; }
  part[t] = s;
  __syncthreads();
  if (t == 0) { u32 acc = 0; for (int i = 0; i < 256; ++i) { pre[i] = acc; acc += part[i]; } }
  __syncthreads();
  u32 acc = pre[t];
#pragma unroll
  for (int i = 0; i < 8; ++i) {
    u32 na = acc + loc[i];
    if (acc < N_PRE && na >= N_PRE) { T1[b] = (u32)(t * 8 + i); Base1[b] = acc; }
    acc = na;
  }
}

// ---------------- level-2 histogram (always on) -------------------------
__global__ __launch_bounds__(256) void k_hist2(
    const u64* __restrict__ keys, const u32* __restrict__ T1,
    u32* __restrict__ hist)
{
  int b = blockIdx.y;
  u32 t1 = T1[b];
  __shared__ u32 lh[2048];
  int t = threadIdx.x;
#pragma unroll
  for (int i = 0; i < 8; ++i) lh[t + i * 256] = 0;
  __syncthreads();
#pragma unroll
  for (int k = 0; k < 4; ++k) {
    int i = blockIdx.x * 1024 + k * 256 + t;
    u64 key = keys[(size_t)b * N_ANC + i];
    if ((u32)(key >> 53) == t1) atomicAdd(&lh[(u32)(key >> 42) & 0x7FFu], 1u);
  }
  __syncthreads();
#pragma unroll
  for (int i = 0; i < 8; ++i) {
    u32 v = lh[t + i * 256];
    if (v) atomicAdd(&hist[b * 2048 + t + i * 256], v);
  }
}

__global__ __launch_bounds__(256) void k_pick2(
    const u32* __restrict__ hist, const u32* __restrict__ T1,
    const u32* __restrict__ Base1, u32* __restrict__ T2)
{
  int b = blockIdx.x, t = threadIdx.x;
  const u32* h = hist + b * 2048;
  __shared__ u32 part[256], pre[256];
  u32 loc[8], s = 0;
#pragma unroll
  for (int i = 0; i < 8; ++i) { loc[i] = h[t * 8 + i]; s += loc[i]; }
  part[t] = s;
  __syncthreads();
  if (t == 0) { u32 acc = Base1[b]; for (int i = 0; i < 256; ++i) { pre[i] = acc; acc += part[i]; } }
  __syncthreads();
  u32 acc = pre[t];
#pragma unroll
  for (int i = 0; i < 8; ++i) {
    u32 na = acc + loc[i];
    if (acc < N_PRE && na >= N_PRE) T2[b] = (T1[b] << 11) | (u32)(t * 8 + i);
    acc = na;
  }
}

__global__ __launch_bounds__(256) void k_compact(
    const u64* __restrict__ keys, const u32* __restrict__ T2,
    u64* __restrict__ cand, u32* __restrict__ cnt)
{
  int b = blockIdx.y;
  int i = blockIdx.x * 256 + threadIdx.x;
  u64 key = keys[(size_t)b * N_ANC + i];
  if ((u32)(key >> 42) <= T2[b]) {
    u32 pos = atomicAdd(&cnt[b], 1u);
    if (pos < MAXC) cand[(size_t)b * MAXC + pos] = key;
  }
}

// ---------------- tile sort: 2048-element bitonic in LDS ----------------
#define SIDX(x) ((x) + ((x) >> 5))   // pad every 32 u64 to break bank aliasing
__global__ __launch_bounds__(1024) void k_sort_tile(u64* __restrict__ a)
{
  int b = blockIdx.y, base = blockIdx.x * 2048;
  u64* p = a + (size_t)b * MAXC + base;
  __shared__ u64 lds[2048 + 64];
  int t = threadIdx.x;
  lds[SIDX(t)] = p[t];
  lds[SIDX(t + 1024)] = p[t + 1024];
  __syncthreads();
  for (int k = 2; k <= 2048; k <<= 1) {
    for (int j = k >> 1; j > 0; j >>= 1) {
      int i = ((t & ~(j - 1)) << 1) | (t & (j - 1));
      int l = i | j;
      bool asc = ((i & k) == 0);
      u64 x = lds[SIDX(i)], y = lds[SIDX(l)];
      if ((x > y) == asc) { lds[SIDX(i)] = y; lds[SIDX(l)] = x; }
      __syncthreads();
    }
  }
  p[t] = lds[SIDX(t)];
  p[t + 1024] = lds[SIDX(t + 1024)];
}

// ---------------- merge-path ranking + fused gather ---------------------
__global__ __launch_bounds__(256) void k_merge_gather(
    const u64* __restrict__ cand, const float4* __restrict__ boxes,
    float4* __restrict__ gbox, u64* __restrict__ deadm)
{
  int b = blockIdx.y;
  int p = blockIdx.x * 256 + threadIdx.x;   // [0, MAXC)
  const u64* cb = cand + (size_t)b * MAXC;
  u64 key = cb[p];
  int r = p >> 11;
  int rank = p & 2047;
#pragma unroll
  for (int s = 0; s < NSEG; ++s) {
    if (s == r) continue;
    const u64* run = cb + (s << 11);
    int lo = 0;
#pragma unroll
    for (int step = 2048; step >= 1; step >>= 1) {
      int np = lo + step;
      if (np <= 2048 && run[np - 1] < key) lo = np;
    }
    rank += lo;
  }
  bool valid = ((u32)(key >> 32) < 0x80000000u) && (rank < N_PRE);
  float4 bx = make_float4(0.f, 0.f, 0.f, 0.f);
  if (valid) bx = boxes[(size_t)b * N_ANC + (u32)key];
  gbox[(size_t)b * MAXC + rank] = bx;
  if (!valid) atomicOr(&deadm[b * NDW + (rank >> 6)], 1ull << (rank & 63));
}

// ---------------- balanced 64x64 mask tile ------------------------------
__device__ __forceinline__ void segmask_tile(
    int b, int sg, int tile, const float4* __restrict__ gbox,
    u64* __restrict__ smask, u64* __restrict__ smaskT,
    float4* rbox, float* rarea, u64* diag)
{
  int r = tile, rg = 0;
  while (r >= 32 - rg) { r -= 32 - rg; ++rg; }
  int cw = rg + r;
  const float4* gb = gbox + (size_t)b * MAXC + sg * SEG;
  int t = threadIdx.x;
  if (t < 64) { float4 bx = gb[rg * 64 + t]; rbox[t] = bx; rarea[t] = area_of(bx); }
  __syncthreads();
  int wv = t >> 6, lane = t & 63;
  u64* srow = smask + (size_t)(b * NSEG + sg) * SEG * NW + (size_t)rg * 64 * NW;
  float4 cb4 = gb[cw * 64 + lane];
  float ca = area_of(cb4);
  bool isdiag = (cw == rg);
  for (int rr = wv * 16; rr < wv * 16 + 16; ++rr) {
    bool p = iou_gt_a(rbox[rr], cb4, rarea[rr], ca);
    if (isdiag) p = p && (lane > rr);
    u64 m = __ballot(p);
    if (lane == 0) { srow[(size_t)rr * NW + cw] = m; if (isdiag) diag[rr] = m; }
  }
  if (isdiag) {
    __syncthreads();
    if (t < 64) {
      u64 s = 0;
      for (int q = 0; q < 64; ++q) s |= ((diag[q] >> t) & 1ull) << q;
      smaskT[(size_t)(b * NSEG + sg) * SEG + rg * 64 + t] = s;
    }
  }
}

__global__ __launch_bounds__(256) void k_segmask01(
    const float4* __restrict__ gbox, u64* __restrict__ smask,
    u64* __restrict__ smaskT)
{
  __shared__ float4 rbox[64]; __shared__ float rarea[64]; __shared__ u64 diag[64];
  int b = blockIdx.y;
  int sg = blockIdx.x / 528, tile = blockIdx.x % 528;
  segmask_tile(b, sg, tile, gbox, smask, smaskT, rbox, rarea, diag);
}

// cross (sg candidates vs kept list)
__device__ __forceinline__ void cross_work(
    int b, int sg, int bx, const float4* __restrict__ gbox,
    const float4* __restrict__ keptb, const int* __restrict__ meta,
    u64* __restrict__ deadm, float4* kb, float* ka)
{
  int kc = bx >> 3, cbk = bx & 7;
  int nkept = meta[b * 8 + 0];
  int kbase = kc * 256;
  if (kbase >= nkept) return;
  int kcnt = min(256, nkept - kbase);
  int t = threadIdx.x;
  if (t < kcnt) {
    float4 k4 = keptb[(size_t)b * SEG + kbase + t];
    kb[t] = k4; ka[t] = area_of(k4);
  }
  __syncthreads();
  int gi = sg * SEG + cbk * 256 + t;
  float4 my = gbox[(size_t)b * MAXC + gi];
  float ma = area_of(my);
  bool sup = false;
  for (int kk = 0; kk < kcnt; ++kk) {
    if (iou_gt_a(kb[kk], my, ka[kk], ma)) { sup = true; break; }
  }
  u64 bm = __ballot(sup);
  if ((t & 63) == 0 && bm) atomicOr(&deadm[b * NDW + (gi >> 6)], bm);
}

__global__ __launch_bounds__(256) void k_cross(
    const float4* __restrict__ gbox, const float4* __restrict__ keptb,
    const int* __restrict__ meta, u64* __restrict__ deadm, int sg)
{
  int b = blockIdx.y;
  if (meta[b * 8 + 1]) return;
  __shared__ float4 kb[256]; __shared__ float ka[256];
  cross_work(b, sg, blockIdx.x, gbox, keptb, meta, deadm, kb, ka);
}

// fused cross + gated segmask for sg>=2
__global__ __launch_bounds__(256) void k_crossmask(
    const float4* __restrict__ gbox, const float4* __restrict__ keptb,
    const int* __restrict__ meta, u64* __restrict__ deadm,
    u64* __restrict__ smask, u64* __restrict__ smaskT, int sg)
{
  int b = blockIdx.y;
  if (meta[b * 8 + 1]) return;
  __shared__ float4 kb[256]; __shared__ float ka[256]; __shared__ u64 diag[64];
  if (blockIdx.x < 64) {
    cross_work(b, sg, blockIdx.x, gbox, keptb, meta, deadm, kb, ka);
  } else {
    segmask_tile(b, sg, blockIdx.x - 64, gbox, smask, smaskT,
                 kb, ka, diag);
  }
}

// ---------------- greedy walk: ballot fixpoint + reg-batched staging ----
__global__ __launch_bounds__(1024) void k_walk(
    const float4* __restrict__ gbox, const u64* __restrict__ smask,
    const u64* __restrict__ smaskT, const u64* __restrict__ deadm,
    int* __restrict__ meta, float4* __restrict__ keptb,
    float* __restrict__ out, int sg)
{
  int b = blockIdx.x;
  if (meta[b * 8 + 1]) return;
  int t = threadIdx.x, wv = t >> 6, lane = t & 63;

  __shared__ u64 rowbuf[2][2048];   // 32 KiB: 64 rows x 32 words, dbuf
  __shared__ u64 stbuf[2][64];
  __shared__ float4 bbox[2][64];
  __shared__ u64 sdead[2];
  __shared__ u32 remv[64];          // 2048 suppression bits (u32 halves)
  __shared__ u32 klist[64];
  __shared__ int s_stop, s_nkept, s_kcnt;

  const u64* smb = smask + (size_t)(b * NSEG + sg) * SEG * NW;
  const u64* stb = smaskT + (size_t)(b * NSEG + sg) * SEG;
  const u64* dmb = deadm + b * NDW + sg * NW;
  const float4* gb = gbox + (size_t)b * MAXC + sg * SEG;
  float4* kbuf = keptb + (size_t)b * SEG;
  float4* ob = (float4*)(out + (size_t)b * N_POST * 4);
  float* om = out + (size_t)B_SZ * N_POST * 4 + (size_t)b * N_POST;

  // prologue: group 0, batched loads (all issued before first LDS write)
  {
    u64 a = smb[t], c = smb[t + 1024];
    u64 st_ = 0; float4 bb_ = make_float4(0.f, 0.f, 0.f, 0.f);
    if (t < 64) { st_ = stb[t]; bb_ = gb[t]; }
    u64 sd_ = (t == 0) ? dmb[0] : 0;
    rowbuf[0][t] = a;
    rowbuf[0][t + 1024] = c;
    if (t < 64) { stbuf[0][t] = st_; bbox[0][t] = bb_; remv[t] = 0; }
    if (t == 0) { sdead[0] = sd_; s_stop = 0; s_nkept = meta[b * 8 + 0]; }
  }
  __syncthreads();

  int p0 = t - 64, p1 = p0 + 960, p2 = p0 + 1920;  // staging indices (wv>0)
  for (int g = 0; g < NW; ++g) {
    int cb = g & 1, nb = cb ^ 1;
    if (wv > 0) {                       // waves 1..15: stage group g+1
      if (g < NW - 1) {
        const u64* src = smb + (size_t)(g + 1) * 2048;
        // batched issue: all loads first, then LDS writes (one vmcnt window)
        u64 a  = src[p0];
        u64 c  = src[p1];
        u64 e  = (p0 < 128) ? src[p2] : 0;
        u64 st_ = 0; float4 bb_ = make_float4(0.f, 0.f, 0.f, 0.f);
        if (p0 < 64) { st_ = stb[(g + 1) * 64 + p0]; bb_ = gb[(g + 1) * 64 + p0]; }
        u64 sd_ = (t == 64) ? dmb[g + 1] : 0;
        rowbuf[nb][p0] = a;
        rowbuf[nb][p1] = c;
        if (p0 < 128) rowbuf[nb][p2] = e;
        if (p0 < 64) { stbuf[nb][p0] = st_; bbox[nb][p0] = bb_; }
        if (t == 64) sdead[nb] = sd_;
      }
    } else {                            // wave 0: resolve group g
      int l = lane;
      u64 S = stbuf[cb][l];
      u64 remg = ((u64)remv[2 * g + 1] << 32) | remv[2 * g];
      u64 avail = ~(remg | sdead[cb]);
      u64 km = 0;
      while (avail) {
        bool al = (avail >> l) & 1;
        u64 newk = __ballot(al && (S & avail) == 0ull);
        u64 nd   = __ballot(al && (S & newk) != 0ull);
        km |= newk;
        avail &= ~(newk | nd);
      }
      int nk0 = s_nkept;
      int rem = N_POST - nk0;
      int kc = __popcll(km);
      bool stop = (kc >= rem);
      int rank = __popcll(km & ((1ull << l) - 1ull));
      if (((km >> l) & 1) && rank < rem) {
        float4 bx = bbox[cb][l];
        kbuf[nk0 + rank] = bx;
        ob[nk0 + rank] = bx;            // write output directly
        om[nk0 + rank] = 1.0f;
        klist[rank] = (u32)l;
      }
      if (l == 0) {
        int eff = stop ? rem : kc;
        s_kcnt = eff;
        s_nkept = nk0 + eff;
        if (stop) s_stop = 1;
      }
    }
    __syncthreads();
    if (s_stop) break;
    if (g < NW - 1) {
      // stage C: all 1024 threads OR kept rows' future words into remv
      int kcnt = s_kcnt;
      u32* rb32 = (u32*)rowbuf[cb];
      for (int i = t; i < kcnt * 64; i += 1024) {
        int kk = i >> 6, w = i & 63;
        if ((w >> 1) > g) {
          u32 v = rb32[klist[kk] * 64 + w];
          if (v) atomicOr(&remv[w], v);
        }
      }
    }
    __syncthreads();
  }
  int nk = s_nkept;
  bool fin = s_stop || (sg == NSEG - 1);
  if (t == 0) { meta[b * 8 + 0] = nk; if (fin) meta[b * 8 + 1] = 1; }
  if (fin) {  // zero-pad tail of outputs
    float4 zero = make_float4(0.f, 0.f, 0.f, 0.f);
    for (int i = nk + t; i < N_POST; i += 1024) { ob[i] = zero; om[i] = 0.0f; }
  }
}

extern "C" void kernel_launch(void* const* d_in, const int* in_sizes, int n_in,
                              void* d_out, int out_size, void* d_ws, size_t ws_size,
                              hipStream_t stream)
{
  const int*   imh     = (const int*)d_in[0];
  const int*   imw     = (const int*)d_in[1];
  const float* anchors = (const float*)d_in[2];
  const float* loc     = (const float*)d_in[3];
  const float* obj     = (const float*)d_in[4];
  float* out = (float*)d_out;

  char* ws = (char*)d_ws;
  size_t off = 0;
  float4* boxes = (float4*)(ws + off); off += (size_t)B_SZ * N_ANC * 16;
  u64*    keys  = (u64*)   (ws + off); off += (size_t)B_SZ * N_ANC * 8;
  u64*    cand  = (u64*)   (ws + off); off += (size_t)B_SZ * MAXC * 8;
  float4* gbox  = (float4*)(ws + off); off += (size_t)B_SZ * MAXC * 16;
  float4* keptb = (float4*)(ws + off); off += (size_t)B_SZ * SEG * 16;
  off = (off + 255) & ~(size_t)255;
  char*   zr    = ws + off;  // zeroed region
  u32*    hist1 = (u32*)(zr);
  u32*    hist2 = (u32*)(zr + 65536);
  u32*    T1    = (u32*)(zr + 131072);
  u32*    Base1 = (u32*)(zr + 131072 + 32);
  u32*    T2    = (u32*)(zr + 131072 + 64);
  u32*    cnt   = (u32*)(zr + 131072 + 96);
  int*    meta  = (int*)(zr + 131072 + 128);                 // 8*8 ints
  u64*    deadm = (u64*)(zr + 131072 + 128 + 256);           // 12 KiB
  size_t  zr_sz = 131072 + 128 + 256 + (size_t)B_SZ * NDW * 8;
  off += (zr_sz + 255) & ~(size_t)255;
  u64*    smask  = (u64*)(ws + off); off += (size_t)B_SZ * NSEG * SEG * NW * 8;
  u64*    smaskT = (u64*)(ws + off); off += (size_t)B_SZ * NSEG * SEG * 8;

  hipMemsetAsync(zr, 0, zr_sz, stream);
  hipMemsetAsync(cand, 0xFF, (size_t)B_SZ * MAXC * 8, stream);

  k_decode<<<dim3(144, B_SZ), 256, 0, stream>>>(imh, imw, anchors, loc, obj,
                                                boxes, keys, hist1);
  k_pick1<<<B_SZ, 256, 0, stream>>>(hist1, T1, Base1);
  k_hist2<<<dim3(36, B_SZ), 256, 0, stream>>>(keys, T1, hist2);
  k_pick2<<<B_SZ, 256, 0, stream>>>(hist2, T1, Base1, T2);
  k_compact<<<dim3(144, B_SZ), 256, 0, stream>>>(keys, T2, cand, cnt);

  k_sort_tile<<<dim3(NSEG, B_SZ), 1024, 0, stream>>>(cand);
  k_merge_gather<<<dim3(MAXC / 256, B_SZ), 256, 0, stream>>>(cand, boxes, gbox, deadm);

  k_segmask01<<<dim3(1056, B_SZ), 256, 0, stream>>>(gbox, smask, smaskT);

  k_walk<<<B_SZ, 1024, 0, stream>>>(gbox, smask, smaskT, deadm, meta, keptb, out, 0);
  k_cross<<<dim3(64, B_SZ), 256, 0, stream>>>(gbox, keptb, meta, deadm, 1);
  k_walk<<<B_SZ, 1024, 0, stream>>>(gbox, smask, smaskT, deadm, meta, keptb, out, 1);
  for (int sg = 2; sg < NSEG; ++sg) {
    k_crossmask<<<dim3(592, B_SZ), 256, 0, stream>>>(gbox, keptb, meta, deadm,
                                                     smask, smaskT, sg);
    k_walk<<<B_SZ, 1024, 0, stream>>>(gbox, smask, smaskT, deadm, meta, keptb, out, sg);
  }
}

// Round 9
// 222.639 us; speedup vs baseline: 10.3360x; 1.2097x over previous
//
#include <hip/hip_runtime.h>

typedef unsigned long long u64;
typedef unsigned int u32;

#define B_SZ   8
#define N_ANC  36864
#define N_PRE  12000
#define N_POST 2000
#define SEG    2048
#define NSEG   6
#define MAXC   (SEG * NSEG)   // 12288
#define NW     (SEG / 64)     // 32 u64 words per mask row
#define NDW    (MAXC / 64)    // 192 dead-mask words per batch
#define NBLK   144            // decode/scatter blocks per batch

__device__ __forceinline__ float area_of(float4 p) {
  return __fmul_rn(__fsub_rn(p.z, p.x), __fsub_rn(p.w, p.y));
}

// bit-exact replication: a0 = area(first reference arg), a1 = area(second)
__device__ __forceinline__ bool iou_gt_a(float4 p, float4 q, float a0, float a1) {
  float ix1 = fmaxf(p.x, q.x), iy1 = fmaxf(p.y, q.y);
  float ix2 = fminf(p.z, q.z), iy2 = fminf(p.w, q.w);
  float iw = fmaxf(__fsub_rn(ix2, ix1), 0.0f);
  float ih = fmaxf(__fsub_rn(iy2, iy1), 0.0f);
  float inter = __fmul_rn(iw, ih);
  float den = fmaxf(__fsub_rn(__fadd_rn(a0, a1), inter), 1e-9f);
  return (inter / den) > 0.7f;
}

// ---------------- decode + score + keys + fused level-1 histogram -------
__global__ __launch_bounds__(256) void k_decode(
    const int* __restrict__ imh_p, const int* __restrict__ imw_p,
    const float* __restrict__ anchors, const float* __restrict__ loc,
    const float* __restrict__ obj, float4* __restrict__ boxes,
    u64* __restrict__ keys, u32* __restrict__ hist)
{
  __shared__ u32 lh[2048];
  int t = threadIdx.x;
#pragma unroll
  for (int i = 0; i < 8; ++i) lh[t + i * 256] = 0;
  __syncthreads();

  int n = blockIdx.x * 256 + t;
  int b = blockIdx.y;
  float a0 = anchors[n * 4 + 0], a1 = anchors[n * 4 + 1];
  float a2 = anchors[n * 4 + 2], a3 = anchors[n * 4 + 3];
  size_t off = (size_t)b * N_ANC + n;
  float l0 = loc[off * 4 + 0], l1 = loc[off * 4 + 1];
  float l2 = loc[off * 4 + 2], l3 = loc[off * 4 + 3];

  float w  = __fsub_rn(a2, a0);
  float h  = __fsub_rn(a3, a1);
  float cx = __fadd_rn(a0, __fmul_rn(0.5f, w));
  float cy = __fadd_rn(a1, __fmul_rn(0.5f, h));
  float pcx = __fadd_rn(__fmul_rn(l0, w), cx);
  float pcy = __fadd_rn(__fmul_rn(l1, h), cy);
  float pw  = __fmul_rn(expf(l2), w);
  float ph  = __fmul_rn(expf(l3), h);
  float imw = (float)imw_p[0], imh = (float)imh_p[0];
  float hx = __fmul_rn(0.5f, pw), hy = __fmul_rn(0.5f, ph);
  float x1 = fminf(fmaxf(__fsub_rn(pcx, hx), 0.0f), imw);
  float y1 = fminf(fmaxf(__fsub_rn(pcy, hy), 0.0f), imh);
  float x2 = fminf(fmaxf(__fadd_rn(pcx, hx), 0.0f), imw);
  float y2 = fminf(fmaxf(__fadd_rn(pcy, hy), 0.0f), imh);
  boxes[off] = make_float4(x1, y1, x2, y2);

  bool valid = (__fsub_rn(x2, x1) >= 16.0f) && (__fsub_rn(y2, y1) >= 16.0f);

  float o0 = obj[off * 2 + 0], o1 = obj[off * 2 + 1];
  float m  = fmaxf(o0, o1);
  float e0 = expf(__fsub_rn(o0, m));
  float e1 = expf(__fsub_rn(o1, m));
  float s  = e1 / __fadd_rn(e0, e1);
  float sc = valid ? s : -1e9f;

  u32 u  = __float_as_uint(sc);
  u32 fk = (u & 0x80000000u) ? ~u : (u | 0x80000000u);
  u32 sk = ~fk;  // ascending u64 == descending score, stable by index
  u64 key = ((u64)sk << 32) | (u32)n;
  keys[off] = key;
  atomicAdd(&lh[(u32)(key >> 53)], 1u);
  __syncthreads();
#pragma unroll
  for (int i = 0; i < 8; ++i) {
    u32 v = lh[t + i * 256];
    if (v) atomicAdd(&hist[b * 2048 + t + i * 256], v);
  }
}

// ---------------- level-1 pick ------------------------------------------
__global__ __launch_bounds__(256) void k_pick1(
    const u32* __restrict__ hist, u32* __restrict__ T1, u32* __restrict__ Base1)
{
  int b = blockIdx.x, t = threadIdx.x;
  const u32* h = hist + b * 2048;
  __shared__ u32 part[256], pre[256];
  u32 loc[8], s = 0;
#pragma unroll
  for (int i = 0; i < 8; ++i) { loc[i] = h[t * 8 + i]; s += loc[i]; }
  part[t] = s;
  __syncthreads();
  if (t == 0) { u32 acc = 0; for (int i = 0; i < 256; ++i) { pre[i] = acc; acc += part[i]; } }
  __syncthreads();
  u32 acc = pre[t];
#pragma unroll
  for (int i = 0; i < 8; ++i) {
    u32 na = acc + loc[i];
    if (acc < N_PRE && na >= N_PRE) { T1[b] = (u32)(t * 8 + i); Base1[b] = acc; }
    acc = na;
  }
}

// ---------------- level-2 histogram (always on) -------------------------
__global__ __launch_bounds__(256) void k_hist2(
    const u64* __restrict__ keys, const u32* __restrict__ T1,
    u32* __restrict__ hist)
{
  int b = blockIdx.y;
  u32 t1 = T1[b];
  __shared__ u32 lh[2048];
  int t = threadIdx.x;
#pragma unroll
  for (int i = 0; i < 8; ++i) lh[t + i * 256] = 0;
  __syncthreads();
#pragma unroll
  for (int k = 0; k < 4; ++k) {
    int i = blockIdx.x * 1024 + k * 256 + t;
    u64 key = keys[(size_t)b * N_ANC + i];
    if ((u32)(key >> 53) == t1) atomicAdd(&lh[(u32)(key >> 42) & 0x7FFu], 1u);
  }
  __syncthreads();
#pragma unroll
  for (int i = 0; i < 8; ++i) {
    u32 v = lh[t + i * 256];
    if (v) atomicAdd(&hist[b * 2048 + t + i * 256], v);
  }
}

__global__ __launch_bounds__(256) void k_pick2(
    const u32* __restrict__ hist, const u32* __restrict__ T1,
    const u32* __restrict__ Base1, u32* __restrict__ T2)
{
  int b = blockIdx.x, t = threadIdx.x;
  const u32* h = hist + b * 2048;
  __shared__ u32 part[256], pre[256];
  u32 loc[8], s = 0;
#pragma unroll
  for (int i = 0; i < 8; ++i) { loc[i] = h[t * 8 + i]; s += loc[i]; }
  part[t] = s;
  __syncthreads();
  if (t == 0) { u32 acc = Base1[b]; for (int i = 0; i < 256; ++i) { pre[i] = acc; acc += part[i]; } }
  __syncthreads();
  u32 acc = pre[t];
#pragma unroll
  for (int i = 0; i < 8; ++i) {
    u32 na = acc + loc[i];
    if (acc < N_PRE && na >= N_PRE) T2[b] = (T1[b] << 11) | (u32)(t * 8 + i);
    acc = na;
  }
}

// ---------------- compact: count -> scan -> scatter (no atomics) --------
__global__ __launch_bounds__(256) void k_count(
    const u64* __restrict__ keys, const u32* __restrict__ T2,
    u32* __restrict__ bcnt)
{
  int b = blockIdx.y;
  int i = blockIdx.x * 256 + threadIdx.x;
  u64 key = keys[(size_t)b * N_ANC + i];
  bool pred = (u32)(key >> 42) <= T2[b];
  u64 bal = __ballot(pred);
  __shared__ u32 wc[4];
  int wv = threadIdx.x >> 6, lane = threadIdx.x & 63;
  if (lane == 0) wc[wv] = (u32)__popcll(bal);
  __syncthreads();
  if (threadIdx.x == 0)
    bcnt[b * NBLK + blockIdx.x] = wc[0] + wc[1] + wc[2] + wc[3];
}

__global__ __launch_bounds__(64) void k_scan(
    const u32* __restrict__ bcnt, u32* __restrict__ boff)
{
  int b = blockIdx.x;
  if (threadIdx.x == 0) {
    u32 acc = 0;
    for (int i = 0; i < NBLK; ++i) { boff[b * NBLK + i] = acc; acc += bcnt[b * NBLK + i]; }
  }
}

__global__ __launch_bounds__(256) void k_scatter(
    const u64* __restrict__ keys, const u32* __restrict__ T2,
    const u32* __restrict__ boff, u64* __restrict__ cand)
{
  int b = blockIdx.y;
  int i = blockIdx.x * 256 + threadIdx.x;
  u64 key = keys[(size_t)b * N_ANC + i];
  bool pred = (u32)(key >> 42) <= T2[b];
  u64 bal = __ballot(pred);
  __shared__ u32 wc[4];
  int wv = threadIdx.x >> 6, lane = threadIdx.x & 63;
  if (lane == 0) wc[wv] = (u32)__popcll(bal);
  __syncthreads();
  u32 base = boff[b * NBLK + blockIdx.x];
  for (int w = 0; w < wv; ++w) base += wc[w];
  u32 rank = (u32)__popcll(bal & ((1ull << lane) - 1ull));
  if (pred) {
    u32 pos = base + rank;
    if (pos < MAXC) cand[(size_t)b * MAXC + pos] = key;
  }
}

// ---------------- tile sort: 2048-element bitonic in LDS ----------------
#define SIDX(x) ((x) + ((x) >> 5))   // pad every 32 u64 to break bank aliasing
__global__ __launch_bounds__(1024) void k_sort_tile(u64* __restrict__ a)
{
  int b = blockIdx.y, base = blockIdx.x * 2048;
  u64* p = a + (size_t)b * MAXC + base;
  __shared__ u64 lds[2048 + 64];
  int t = threadIdx.x;
  lds[SIDX(t)] = p[t];
  lds[SIDX(t + 1024)] = p[t + 1024];
  __syncthreads();
  for (int k = 2; k <= 2048; k <<= 1) {
    for (int j = k >> 1; j > 0; j >>= 1) {
      int i = ((t & ~(j - 1)) << 1) | (t & (j - 1));
      int l = i | j;
      bool asc = ((i & k) == 0);
      u64 x = lds[SIDX(i)], y = lds[SIDX(l)];
      if ((x > y) == asc) { lds[SIDX(i)] = y; lds[SIDX(l)] = x; }
      __syncthreads();
    }
  }
  p[t] = lds[SIDX(t)];
  p[t + 1024] = lds[SIDX(t + 1024)];
}

// ---------------- merge-path ranking + fused gather ---------------------
__global__ __launch_bounds__(256) void k_merge_gather(
    const u64* __restrict__ cand, const float4* __restrict__ boxes,
    float4* __restrict__ gbox, u64* __restrict__ deadm)
{
  int b = blockIdx.y;
  int p = blockIdx.x * 256 + threadIdx.x;   // [0, MAXC)
  const u64* cb = cand + (size_t)b * MAXC;
  u64 key = cb[p];
  int r = p >> 11;
  int rank = p & 2047;
#pragma unroll
  for (int s = 0; s < NSEG; ++s) {
    if (s == r) continue;
    const u64* run = cb + (s << 11);
    int lo = 0;
#pragma unroll
    for (int step = 2048; step >= 1; step >>= 1) {
      int np = lo + step;
      if (np <= 2048 && run[np - 1] < key) lo = np;
    }
    rank += lo;
  }
  bool valid = ((u32)(key >> 32) < 0x80000000u) && (rank < N_PRE);
  float4 bx = make_float4(0.f, 0.f, 0.f, 0.f);
  if (valid) bx = boxes[(size_t)b * N_ANC + (u32)key];
  gbox[(size_t)b * MAXC + rank] = bx;
  if (!valid) atomicOr(&deadm[b * NDW + (rank >> 6)], 1ull << (rank & 63));
}

// ---------------- balanced 64x64 mask tile ------------------------------
__device__ __forceinline__ void segmask_tile(
    int b, int sg, int tile, const float4* __restrict__ gbox,
    u64* __restrict__ smask, u64* __restrict__ smaskT,
    float4* rbox, float* rarea, u64* diag)
{
  int r = tile, rg = 0;
  while (r >= 32 - rg) { r -= 32 - rg; ++rg; }
  int cw = rg + r;
  const float4* gb = gbox + (size_t)b * MAXC + sg * SEG;
  int t = threadIdx.x;
  if (t < 64) { float4 bx = gb[rg * 64 + t]; rbox[t] = bx; rarea[t] = area_of(bx); }
  __syncthreads();
  int wv = t >> 6, lane = t & 63;
  u64* srow = smask + (size_t)(b * NSEG + sg) * SEG * NW + (size_t)rg * 64 * NW;
  float4 cb4 = gb[cw * 64 + lane];
  float ca = area_of(cb4);
  bool isdiag = (cw == rg);
  for (int rr = wv * 16; rr < wv * 16 + 16; ++rr) {
    bool p = iou_gt_a(rbox[rr], cb4, rarea[rr], ca);
    if (isdiag) p = p && (lane > rr);
    u64 m = __ballot(p);
    if (lane == 0) { srow[(size_t)rr * NW + cw] = m; if (isdiag) diag[rr] = m; }
  }
  if (isdiag) {
    __syncthreads();
    if (t < 64) {
      u64 s = 0;
      for (int q = 0; q < 64; ++q) s |= ((diag[q] >> t) & 1ull) << q;
      smaskT[(size_t)(b * NSEG + sg) * SEG + rg * 64 + t] = s;
    }
  }
}

__global__ __launch_bounds__(256) void k_segmask01(
    const float4* __restrict__ gbox, u64* __restrict__ smask,
    u64* __restrict__ smaskT)
{
  __shared__ float4 rbox[64]; __shared__ float rarea[64]; __shared__ u64 diag[64];
  int b = blockIdx.y;
  int sg = blockIdx.x / 528, tile = blockIdx.x % 528;
  segmask_tile(b, sg, tile, gbox, smask, smaskT, rbox, rarea, diag);
}

// cross (sg candidates vs kept list)
__device__ __forceinline__ void cross_work(
    int b, int sg, int bx, const float4* __restrict__ gbox,
    const float4* __restrict__ keptb, const int* __restrict__ meta,
    u64* __restrict__ deadm, float4* kb, float* ka)
{
  int kc = bx >> 3, cbk = bx & 7;
  int nkept = meta[b * 8 + 0];
  int kbase = kc * 256;
  if (kbase >= nkept) return;
  int kcnt = min(256, nkept - kbase);
  int t = threadIdx.x;
  if (t < kcnt) {
    float4 k4 = keptb[(size_t)b * SEG + kbase + t];
    kb[t] = k4; ka[t] = area_of(k4);
  }
  __syncthreads();
  int gi = sg * SEG + cbk * 256 + t;
  float4 my = gbox[(size_t)b * MAXC + gi];
  float ma = area_of(my);
  bool sup = false;
  for (int kk = 0; kk < kcnt; ++kk) {
    if (iou_gt_a(kb[kk], my, ka[kk], ma)) { sup = true; break; }
  }
  u64 bm = __ballot(sup);
  if ((t & 63) == 0 && bm) atomicOr(&deadm[b * NDW + (gi >> 6)], bm);
}

__global__ __launch_bounds__(256) void k_cross(
    const float4* __restrict__ gbox, const float4* __restrict__ keptb,
    const int* __restrict__ meta, u64* __restrict__ deadm, int sg)
{
  int b = blockIdx.y;
  if (meta[b * 8 + 1]) return;
  __shared__ float4 kb[256]; __shared__ float ka[256];
  cross_work(b, sg, blockIdx.x, gbox, keptb, meta, deadm, kb, ka);
}

// fused cross + gated segmask for sg>=2
__global__ __launch_bounds__(256) void k_crossmask(
    const float4* __restrict__ gbox, const float4* __restrict__ keptb,
    const int* __restrict__ meta, u64* __restrict__ deadm,
    u64* __restrict__ smask, u64* __restrict__ smaskT, int sg)
{
  int b = blockIdx.y;
  if (meta[b * 8 + 1]) return;
  __shared__ float4 kb[256]; __shared__ float ka[256]; __shared__ u64 diag[64];
  if (blockIdx.x < 64) {
    cross_work(b, sg, blockIdx.x, gbox, keptb, meta, deadm, kb, ka);
  } else {
    segmask_tile(b, sg, blockIdx.x - 64, gbox, smask, smaskT,
                 kb, ka, diag);
  }
}

// ---------------- greedy walk: ballot fixpoint + reg-batched staging ----
__global__ __launch_bounds__(1024) void k_walk(
    const float4* __restrict__ gbox, const u64* __restrict__ smask,
    const u64* __restrict__ smaskT, const u64* __restrict__ deadm,
    int* __restrict__ meta, float4* __restrict__ keptb,
    float* __restrict__ out, int sg)
{
  int b = blockIdx.x;
  if (meta[b * 8 + 1]) return;
  int t = threadIdx.x, wv = t >> 6, lane = t & 63;

  __shared__ u64 rowbuf[2][2048];   // 32 KiB: 64 rows x 32 words, dbuf
  __shared__ u64 stbuf[2][64];
  __shared__ float4 bbox[2][64];
  __shared__ u64 sdead[2];
  __shared__ u32 remv[64];          // 2048 suppression bits (u32 halves)
  __shared__ u32 klist[64];
  __shared__ int s_stop, s_nkept, s_kcnt;

  const u64* smb = smask + (size_t)(b * NSEG + sg) * SEG * NW;
  const u64* stb = smaskT + (size_t)(b * NSEG + sg) * SEG;
  const u64* dmb = deadm + b * NDW + sg * NW;
  const float4* gb = gbox + (size_t)b * MAXC + sg * SEG;
  float4* kbuf = keptb + (size_t)b * SEG;
  float4* ob = (float4*)(out + (size_t)b * N_POST * 4);
  float* om = out + (size_t)B_SZ * N_POST * 4 + (size_t)b * N_POST;

  // prologue: group 0, batched loads (all issued before first LDS write)
  {
    u64 a = smb[t], c = smb[t + 1024];
    u64 st_ = 0; float4 bb_ = make_float4(0.f, 0.f, 0.f, 0.f);
    if (t < 64) { st_ = stb[t]; bb_ = gb[t]; }
    u64 sd_ = (t == 0) ? dmb[0] : 0;
    rowbuf[0][t] = a;
    rowbuf[0][t + 1024] = c;
    if (t < 64) { stbuf[0][t] = st_; bbox[0][t] = bb_; remv[t] = 0; }
    if (t == 0) { sdead[0] = sd_; s_stop = 0; s_nkept = meta[b * 8 + 0]; }
  }
  __syncthreads();

  int p0 = t - 64, p1 = p0 + 960, p2 = p0 + 1920;  // staging indices (wv>0)
  for (int g = 0; g < NW; ++g) {
    int cb = g & 1, nb = cb ^ 1;
    if (wv > 0) {                       // waves 1..15: stage group g+1
      if (g < NW - 1) {
        const u64* src = smb + (size_t)(g + 1) * 2048;
        // batched issue: all loads first, then LDS writes (one vmcnt window)
        u64 a  = src[p0];
        u64 c  = src[p1];
        u64 e  = (p0 < 128) ? src[p2] : 0;
        u64 st_ = 0; float4 bb_ = make_float4(0.f, 0.f, 0.f, 0.f);
        if (p0 < 64) { st_ = stb[(g + 1) * 64 + p0]; bb_ = gb[(g + 1) * 64 + p0]; }
        u64 sd_ = (t == 64) ? dmb[g + 1] : 0;
        rowbuf[nb][p0] = a;
        rowbuf[nb][p1] = c;
        if (p0 < 128) rowbuf[nb][p2] = e;
        if (p0 < 64) { stbuf[nb][p0] = st_; bbox[nb][p0] = bb_; }
        if (t == 64) sdead[nb] = sd_;
      }
    } else {                            // wave 0: resolve group g
      int l = lane;
      u64 S = stbuf[cb][l];
      u64 remg = ((u64)remv[2 * g + 1] << 32) | remv[2 * g];
      u64 avail = ~(remg | sdead[cb]);
      u64 km = 0;
      while (avail) {
        bool al = (avail >> l) & 1;
        u64 newk = __ballot(al && (S & avail) == 0ull);
        u64 nd   = __ballot(al && (S & newk) != 0ull);
        km |= newk;
        avail &= ~(newk | nd);
      }
      int nk0 = s_nkept;
      int rem = N_POST - nk0;
      int kc = __popcll(km);
      bool stop = (kc >= rem);
      int rank = __popcll(km & ((1ull << l) - 1ull));
      if (((km >> l) & 1) && rank < rem) {
        float4 bx = bbox[cb][l];
        kbuf[nk0 + rank] = bx;
        ob[nk0 + rank] = bx;            // write output directly
        om[nk0 + rank] = 1.0f;
        klist[rank] = (u32)l;
      }
      if (l == 0) {
        int eff = stop ? rem : kc;
        s_kcnt = eff;
        s_nkept = nk0 + eff;
        if (stop) s_stop = 1;
      }
    }
    __syncthreads();
    if (s_stop) break;
    if (g < NW - 1) {
      // stage C: all 1024 threads OR kept rows' future words into remv
      int kcnt = s_kcnt;
      u32* rb32 = (u32*)rowbuf[cb];
      for (int i = t; i < kcnt * 64; i += 1024) {
        int kk = i >> 6, w = i & 63;
        if ((w >> 1) > g) {
          u32 v = rb32[klist[kk] * 64 + w];
          if (v) atomicOr(&remv[w], v);
        }
      }
    }
    __syncthreads();
  }
  int nk = s_nkept;
  bool fin = s_stop || (sg == NSEG - 1);
  if (t == 0) { meta[b * 8 + 0] = nk; if (fin) meta[b * 8 + 1] = 1; }
  if (fin) {  // zero-pad tail of outputs
    float4 zero = make_float4(0.f, 0.f, 0.f, 0.f);
    for (int i = nk + t; i < N_POST; i += 1024) { ob[i] = zero; om[i] = 0.0f; }
  }
}

extern "C" void kernel_launch(void* const* d_in, const int* in_sizes, int n_in,
                              void* d_out, int out_size, void* d_ws, size_t ws_size,
                              hipStream_t stream)
{
  const int*   imh     = (const int*)d_in[0];
  const int*   imw     = (const int*)d_in[1];
  const float* anchors = (const float*)d_in[2];
  const float* loc     = (const float*)d_in[3];
  const float* obj     = (const float*)d_in[4];
  float* out = (float*)d_out;

  char* ws = (char*)d_ws;
  size_t off = 0;
  float4* boxes = (float4*)(ws + off); off += (size_t)B_SZ * N_ANC * 16;
  u64*    keys  = (u64*)   (ws + off); off += (size_t)B_SZ * N_ANC * 8;
  u64*    cand  = (u64*)   (ws + off); off += (size_t)B_SZ * MAXC * 8;
  float4* gbox  = (float4*)(ws + off); off += (size_t)B_SZ * MAXC * 16;
  float4* keptb = (float4*)(ws + off); off += (size_t)B_SZ * SEG * 16;
  off = (off + 255) & ~(size_t)255;
  char*   zr    = ws + off;  // zeroed region
  u32*    hist1 = (u32*)(zr);
  u32*    hist2 = (u32*)(zr + 65536);
  u32*    T1    = (u32*)(zr + 131072);
  u32*    Base1 = (u32*)(zr + 131072 + 32);
  u32*    T2    = (u32*)(zr + 131072 + 64);
  int*    meta  = (int*)(zr + 131072 + 128);                 // 8*8 ints
  u64*    deadm = (u64*)(zr + 131072 + 128 + 256);           // 12 KiB
  u32*    bcnt  = (u32*)(zr + 131072 + 128 + 256 + (size_t)B_SZ * NDW * 8);
  u32*    boff  = bcnt + (size_t)B_SZ * NBLK;
  size_t  zr_sz = 131072 + 128 + 256 + (size_t)B_SZ * NDW * 8
                + 2 * (size_t)B_SZ * NBLK * 4;
  off += (zr_sz + 255) & ~(size_t)255;
  u64*    smask  = (u64*)(ws + off); off += (size_t)B_SZ * NSEG * SEG * NW * 8;
  u64*    smaskT = (u64*)(ws + off); off += (size_t)B_SZ * NSEG * SEG * 8;

  hipMemsetAsync(zr, 0, zr_sz, stream);
  hipMemsetAsync(cand, 0xFF, (size_t)B_SZ * MAXC * 8, stream);

  k_decode<<<dim3(NBLK, B_SZ), 256, 0, stream>>>(imh, imw, anchors, loc, obj,
                                                 boxes, keys, hist1);
  k_pick1<<<B_SZ, 256, 0, stream>>>(hist1, T1, Base1);
  k_hist2<<<dim3(36, B_SZ), 256, 0, stream>>>(keys, T1, hist2);
  k_pick2<<<B_SZ, 256, 0, stream>>>(hist2, T1, Base1, T2);

  k_count<<<dim3(NBLK, B_SZ), 256, 0, stream>>>(keys, T2, bcnt);
  k_scan<<<B_SZ, 64, 0, stream>>>(bcnt, boff);
  k_scatter<<<dim3(NBLK, B_SZ), 256, 0, stream>>>(keys, T2, boff, cand);

  k_sort_tile<<<dim3(NSEG, B_SZ), 1024, 0, stream>>>(cand);
  k_merge_gather<<<dim3(MAXC / 256, B_SZ), 256, 0, stream>>>(cand, boxes, gbox, deadm);

  k_segmask01<<<dim3(1056, B_SZ), 256, 0, stream>>>(gbox, smask, smaskT);

  k_walk<<<B_SZ, 1024, 0, stream>>>(gbox, smask, smaskT, deadm, meta, keptb, out, 0);
  k_cross<<<dim3(64, B_SZ), 256, 0, stream>>>(gbox, keptb, meta, deadm, 1);
  k_walk<<<B_SZ, 1024, 0, stream>>>(gbox, smask, smaskT, deadm, meta, keptb, out, 1);
  for (int sg = 2; sg < NSEG; ++sg) {
    k_crossmask<<<dim3(592, B_SZ), 256, 0, stream>>>(gbox, keptb, meta, deadm,
                                                     smask, smaskT, sg);
    k_walk<<<B_SZ, 1024, 0, stream>>>(gbox, smask, smaskT, deadm, meta, keptb, out, sg);
  }
}

// Round 10
// 215.336 us; speedup vs baseline: 10.6865x; 1.0339x over previous
//
#include <hip/hip_runtime.h>

typedef unsigned long long u64;
typedef unsigned int u32;

#define B_SZ   8
#define N_ANC  36864
#define N_PRE  12000
#define N_POST 2000
#define SEG    2048
#define NSEG   6
#define MAXC   (SEG * NSEG)   // 12288
#define NW     (SEG / 64)     // 32 u64 words per mask row
#define NDW    (MAXC / 64)    // 192 dead-mask words per batch
#define NBLK   144            // decode/scatter blocks per batch

__device__ __forceinline__ float area_of(float4 p) {
  return __fmul_rn(__fsub_rn(p.z, p.x), __fsub_rn(p.w, p.y));
}

// bit-exact replication: a0 = area(first reference arg), a1 = area(second)
__device__ __forceinline__ bool iou_gt_a(float4 p, float4 q, float a0, float a1) {
  float ix1 = fmaxf(p.x, q.x), iy1 = fmaxf(p.y, q.y);
  float ix2 = fminf(p.z, q.z), iy2 = fminf(p.w, q.w);
  float iw = fmaxf(__fsub_rn(ix2, ix1), 0.0f);
  float ih = fmaxf(__fsub_rn(iy2, iy1), 0.0f);
  float inter = __fmul_rn(iw, ih);
  float den = fmaxf(__fsub_rn(__fadd_rn(a0, a1), inter), 1e-9f);
  return (inter / den) > 0.7f;
}

// ---------------- decode + score + keys + fused level-1 histogram -------
__global__ __launch_bounds__(256) void k_decode(
    const int* __restrict__ imh_p, const int* __restrict__ imw_p,
    const float* __restrict__ anchors, const float* __restrict__ loc,
    const float* __restrict__ obj, float4* __restrict__ boxes,
    u64* __restrict__ keys, u32* __restrict__ hist)
{
  __shared__ u32 lh[2048];
  int t = threadIdx.x;
#pragma unroll
  for (int i = 0; i < 8; ++i) lh[t + i * 256] = 0;
  __syncthreads();

  int n = blockIdx.x * 256 + t;
  int b = blockIdx.y;
  float a0 = anchors[n * 4 + 0], a1 = anchors[n * 4 + 1];
  float a2 = anchors[n * 4 + 2], a3 = anchors[n * 4 + 3];
  size_t off = (size_t)b * N_ANC + n;
  float l0 = loc[off * 4 + 0], l1 = loc[off * 4 + 1];
  float l2 = loc[off * 4 + 2], l3 = loc[off * 4 + 3];

  float w  = __fsub_rn(a2, a0);
  float h  = __fsub_rn(a3, a1);
  float cx = __fadd_rn(a0, __fmul_rn(0.5f, w));
  float cy = __fadd_rn(a1, __fmul_rn(0.5f, h));
  float pcx = __fadd_rn(__fmul_rn(l0, w), cx);
  float pcy = __fadd_rn(__fmul_rn(l1, h), cy);
  float pw  = __fmul_rn(expf(l2), w);
  float ph  = __fmul_rn(expf(l3), h);
  float imw = (float)imw_p[0], imh = (float)imh_p[0];
  float hx = __fmul_rn(0.5f, pw), hy = __fmul_rn(0.5f, ph);
  float x1 = fminf(fmaxf(__fsub_rn(pcx, hx), 0.0f), imw);
  float y1 = fminf(fmaxf(__fsub_rn(pcy, hy), 0.0f), imh);
  float x2 = fminf(fmaxf(__fadd_rn(pcx, hx), 0.0f), imw);
  float y2 = fminf(fmaxf(__fadd_rn(pcy, hy), 0.0f), imh);
  boxes[off] = make_float4(x1, y1, x2, y2);

  bool valid = (__fsub_rn(x2, x1) >= 16.0f) && (__fsub_rn(y2, y1) >= 16.0f);

  float o0 = obj[off * 2 + 0], o1 = obj[off * 2 + 1];
  float m  = fmaxf(o0, o1);
  float e0 = expf(__fsub_rn(o0, m));
  float e1 = expf(__fsub_rn(o1, m));
  float s  = e1 / __fadd_rn(e0, e1);
  float sc = valid ? s : -1e9f;

  u32 u  = __float_as_uint(sc);
  u32 fk = (u & 0x80000000u) ? ~u : (u | 0x80000000u);
  u32 sk = ~fk;  // ascending u64 == descending score, stable by index
  u64 key = ((u64)sk << 32) | (u32)n;
  keys[off] = key;
  atomicAdd(&lh[(u32)(key >> 53)], 1u);
  __syncthreads();
#pragma unroll
  for (int i = 0; i < 8; ++i) {
    u32 v = lh[t + i * 256];
    if (v) atomicAdd(&hist[b * 2048 + t + i * 256], v);
  }
}

// ---------------- level-1 pick ------------------------------------------
__global__ __launch_bounds__(256) void k_pick1(
    const u32* __restrict__ hist, u32* __restrict__ T1, u32* __restrict__ Base1)
{
  int b = blockIdx.x, t = threadIdx.x;
  const u32* h = hist + b * 2048;
  __shared__ u32 part[256], pre[256];
  u32 loc[8], s = 0;
#pragma unroll
  for (int i = 0; i < 8; ++i) { loc[i] = h[t * 8 + i]; s += loc[i]; }
  part[t] = s;
  __syncthreads();
  if (t == 0) { u32 acc = 0; for (int i = 0; i < 256; ++i) { pre[i] = acc; acc += part[i]; } }
  __syncthreads();
  u32 acc = pre[t];
#pragma unroll
  for (int i = 0; i < 8; ++i) {
    u32 na = acc + loc[i];
    if (acc < N_PRE && na >= N_PRE) { T1[b] = (u32)(t * 8 + i); Base1[b] = acc; }
    acc = na;
  }
}

// ---------------- level-2 histogram (always on) -------------------------
__global__ __launch_bounds__(256) void k_hist2(
    const u64* __restrict__ keys, const u32* __restrict__ T1,
    u32* __restrict__ hist)
{
  int b = blockIdx.y;
  u32 t1 = T1[b];
  __shared__ u32 lh[2048];
  int t = threadIdx.x;
#pragma unroll
  for (int i = 0; i < 8; ++i) lh[t + i * 256] = 0;
  __syncthreads();
#pragma unroll
  for (int k = 0; k < 4; ++k) {
    int i = blockIdx.x * 1024 + k * 256 + t;
    u64 key = keys[(size_t)b * N_ANC + i];
    if ((u32)(key >> 53) == t1) atomicAdd(&lh[(u32)(key >> 42) & 0x7FFu], 1u);
  }
  __syncthreads();
#pragma unroll
  for (int i = 0; i < 8; ++i) {
    u32 v = lh[t + i * 256];
    if (v) atomicAdd(&hist[b * 2048 + t + i * 256], v);
  }
}

__global__ __launch_bounds__(256) void k_pick2(
    const u32* __restrict__ hist, const u32* __restrict__ T1,
    const u32* __restrict__ Base1, u32* __restrict__ T2)
{
  int b = blockIdx.x, t = threadIdx.x;
  const u32* h = hist + b * 2048;
  __shared__ u32 part[256], pre[256];
  u32 loc[8], s = 0;
#pragma unroll
  for (int i = 0; i < 8; ++i) { loc[i] = h[t * 8 + i]; s += loc[i]; }
  part[t] = s;
  __syncthreads();
  if (t == 0) { u32 acc = Base1[b]; for (int i = 0; i < 256; ++i) { pre[i] = acc; acc += part[i]; } }
  __syncthreads();
  u32 acc = pre[t];
#pragma unroll
  for (int i = 0; i < 8; ++i) {
    u32 na = acc + loc[i];
    if (acc < N_PRE && na >= N_PRE) T2[b] = (T1[b] << 11) | (u32)(t * 8 + i);
    acc = na;
  }
}

// ---------------- compact: count -> scatter (scatter self-scans) --------
__global__ __launch_bounds__(256) void k_count(
    const u64* __restrict__ keys, const u32* __restrict__ T2,
    u32* __restrict__ bcnt)
{
  int b = blockIdx.y;
  int i = blockIdx.x * 256 + threadIdx.x;
  u64 key = keys[(size_t)b * N_ANC + i];
  bool pred = (u32)(key >> 42) <= T2[b];
  u64 bal = __ballot(pred);
  __shared__ u32 wc[4];
  int wv = threadIdx.x >> 6, lane = threadIdx.x & 63;
  if (lane == 0) wc[wv] = (u32)__popcll(bal);
  __syncthreads();
  if (threadIdx.x == 0)
    bcnt[b * NBLK + blockIdx.x] = wc[0] + wc[1] + wc[2] + wc[3];
}

__global__ __launch_bounds__(256) void k_scatter(
    const u64* __restrict__ keys, const u32* __restrict__ T2,
    const u32* __restrict__ bcnt, u64* __restrict__ cand)
{
  int b = blockIdx.y, bx = blockIdx.x;
  int t = threadIdx.x;
  __shared__ u32 cnts[NBLK];
  __shared__ u32 wc[4];
  __shared__ u32 sbase;
  if (t < NBLK) cnts[t] = bcnt[b * NBLK + t];
  u64 key = keys[(size_t)b * N_ANC + bx * 256 + t];
  bool pred = (u32)(key >> 42) <= T2[b];
  u64 bal = __ballot(pred);
  int wv = t >> 6, lane = t & 63;
  if (lane == 0) wc[wv] = (u32)__popcll(bal);
  __syncthreads();
  if (t == 0) { u32 a = 0; for (int i = 0; i < bx; ++i) a += cnts[i]; sbase = a; }
  __syncthreads();
  u32 base = sbase;
  for (int w = 0; w < wv; ++w) base += wc[w];
  u32 rank = (u32)__popcll(bal & ((1ull << lane) - 1ull));
  if (pred) {
    u32 pos = base + rank;
    if (pos < MAXC) cand[(size_t)b * MAXC + pos] = key;
  }
}

// ---------------- tile sort: 2048-element bitonic in LDS ----------------
#define SIDX(x) ((x) + ((x) >> 5))   // pad every 32 u64 to break bank aliasing
__global__ __launch_bounds__(1024) void k_sort_tile(u64* __restrict__ a)
{
  int b = blockIdx.y, base = blockIdx.x * 2048;
  u64* p = a + (size_t)b * MAXC + base;
  __shared__ u64 lds[2048 + 64];
  int t = threadIdx.x;
  lds[SIDX(t)] = p[t];
  lds[SIDX(t + 1024)] = p[t + 1024];
  __syncthreads();
  for (int k = 2; k <= 2048; k <<= 1) {
    for (int j = k >> 1; j > 0; j >>= 1) {
      int i = ((t & ~(j - 1)) << 1) | (t & (j - 1));
      int l = i | j;
      bool asc = ((i & k) == 0);
      u64 x = lds[SIDX(i)], y = lds[SIDX(l)];
      if ((x > y) == asc) { lds[SIDX(i)] = y; lds[SIDX(l)] = x; }
      __syncthreads();
    }
  }
  p[t] = lds[SIDX(t)];
  p[t + 1024] = lds[SIDX(t + 1024)];
}

// ---------------- merge-path ranking + fused gather ---------------------
__global__ __launch_bounds__(256) void k_merge_gather(
    const u64* __restrict__ cand, const float4* __restrict__ boxes,
    float4* __restrict__ gbox, u64* __restrict__ deadm)
{
  int b = blockIdx.y;
  int p = blockIdx.x * 256 + threadIdx.x;   // [0, MAXC)
  const u64* cb = cand + (size_t)b * MAXC;
  u64 key = cb[p];
  int r = p >> 11;
  int rank = p & 2047;
#pragma unroll
  for (int s = 0; s < NSEG; ++s) {
    if (s == r) continue;
    const u64* run = cb + (s << 11);
    int lo = 0;
#pragma unroll
    for (int step = 2048; step >= 1; step >>= 1) {
      int np = lo + step;
      if (np <= 2048 && run[np - 1] < key) lo = np;
    }
    rank += lo;
  }
  bool valid = ((u32)(key >> 32) < 0x80000000u) && (rank < N_PRE);
  float4 bx = make_float4(0.f, 0.f, 0.f, 0.f);
  if (valid) bx = boxes[(size_t)b * N_ANC + (u32)key];
  gbox[(size_t)b * MAXC + rank] = bx;
  if (!valid) atomicOr(&deadm[b * NDW + (rank >> 6)], 1ull << (rank & 63));
}

// ---------------- balanced 64x64 mask tile ------------------------------
__device__ __forceinline__ void segmask_tile(
    int b, int sg, int tile, const float4* __restrict__ gbox,
    u64* __restrict__ smask, u64* __restrict__ smaskT,
    float4* rbox, float* rarea, u64* diag)
{
  int r = tile, rg = 0;
  while (r >= 32 - rg) { r -= 32 - rg; ++rg; }
  int cw = rg + r;
  const float4* gb = gbox + (size_t)b * MAXC + sg * SEG;
  int t = threadIdx.x;
  if (t < 64) { float4 bx = gb[rg * 64 + t]; rbox[t] = bx; rarea[t] = area_of(bx); }
  __syncthreads();
  int wv = t >> 6, lane = t & 63;
  u64* srow = smask + (size_t)(b * NSEG + sg) * SEG * NW + (size_t)rg * 64 * NW;
  float4 cb4 = gb[cw * 64 + lane];
  float ca = area_of(cb4);
  bool isdiag = (cw == rg);
  for (int rr = wv * 16; rr < wv * 16 + 16; ++rr) {
    bool p = iou_gt_a(rbox[rr], cb4, rarea[rr], ca);
    if (isdiag) p = p && (lane > rr);
    u64 m = __ballot(p);
    if (lane == 0) { srow[(size_t)rr * NW + cw] = m; if (isdiag) diag[rr] = m; }
  }
  if (isdiag) {
    __syncthreads();
    if (t < 64) {
      u64 s = 0;
      for (int q = 0; q < 64; ++q) s |= ((diag[q] >> t) & 1ull) << q;
      smaskT[(size_t)(b * NSEG + sg) * SEG + rg * 64 + t] = s;
    }
  }
}

__global__ __launch_bounds__(256) void k_segmask01(
    const float4* __restrict__ gbox, u64* __restrict__ smask,
    u64* __restrict__ smaskT)
{
  __shared__ float4 rbox[64]; __shared__ float rarea[64]; __shared__ u64 diag[64];
  int b = blockIdx.y;
  int sg = blockIdx.x / 528, tile = blockIdx.x % 528;
  segmask_tile(b, sg, tile, gbox, smask, smaskT, rbox, rarea, diag);
}

// cross (sg candidates vs kept list)
__device__ __forceinline__ void cross_work(
    int b, int sg, int bx, const float4* __restrict__ gbox,
    const float4* __restrict__ keptb, const int* __restrict__ meta,
    u64* __restrict__ deadm, float4* kb, float* ka)
{
  int kc = bx >> 3, cbk = bx & 7;
  int nkept = meta[b * 8 + 0];
  int kbase = kc * 256;
  if (kbase >= nkept) return;
  int kcnt = min(256, nkept - kbase);
  int t = threadIdx.x;
  if (t < kcnt) {
    float4 k4 = keptb[(size_t)b * SEG + kbase + t];
    kb[t] = k4; ka[t] = area_of(k4);
  }
  __syncthreads();
  int gi = sg * SEG + cbk * 256 + t;
  float4 my = gbox[(size_t)b * MAXC + gi];
  float ma = area_of(my);
  bool sup = false;
  for (int kk = 0; kk < kcnt; ++kk) {
    if (iou_gt_a(kb[kk], my, ka[kk], ma)) { sup = true; break; }
  }
  u64 bm = __ballot(sup);
  if ((t & 63) == 0 && bm) atomicOr(&deadm[b * NDW + (gi >> 6)], bm);
}

__global__ __launch_bounds__(256) void k_cross(
    const float4* __restrict__ gbox, const float4* __restrict__ keptb,
    const int* __restrict__ meta, u64* __restrict__ deadm, int sg)
{
  int b = blockIdx.y;
  if (meta[b * 8 + 1]) return;
  __shared__ float4 kb[256]; __shared__ float ka[256];
  cross_work(b, sg, blockIdx.x, gbox, keptb, meta, deadm, kb, ka);
}

// fused cross + gated segmask for sg>=2
__global__ __launch_bounds__(256) void k_crossmask(
    const float4* __restrict__ gbox, const float4* __restrict__ keptb,
    const int* __restrict__ meta, u64* __restrict__ deadm,
    u64* __restrict__ smask, u64* __restrict__ smaskT, int sg)
{
  int b = blockIdx.y;
  if (meta[b * 8 + 1]) return;
  __shared__ float4 kb[256]; __shared__ float ka[256]; __shared__ u64 diag[64];
  if (blockIdx.x < 64) {
    cross_work(b, sg, blockIdx.x, gbox, keptb, meta, deadm, kb, ka);
  } else {
    segmask_tile(b, sg, blockIdx.x - 64, gbox, smask, smaskT,
                 kb, ka, diag);
  }
}

// ---------------- greedy walk: ballot fixpoint + T14 pipelined staging --
__global__ __launch_bounds__(1024) void k_walk(
    const float4* __restrict__ gbox, const u64* __restrict__ smask,
    const u64* __restrict__ smaskT, const u64* __restrict__ deadm,
    int* __restrict__ meta, float4* __restrict__ keptb,
    float* __restrict__ out, int sg)
{
  int b = blockIdx.x;
  if (meta[b * 8 + 1]) return;
  int t = threadIdx.x, wv = t >> 6, lane = t & 63;

  __shared__ u64 rowbuf[2][2048];   // 32 KiB: 64 rows x 32 words, dbuf
  __shared__ u64 stbuf[2][64];
  __shared__ float4 bbox[2][64];
  __shared__ u64 sdead[2];
  __shared__ u32 remv[64];          // 2048 suppression bits (u32 halves)
  __shared__ u32 klist[64];
  __shared__ int s_stop, s_nkept, s_kcnt;

  const u64* smb = smask + (size_t)(b * NSEG + sg) * SEG * NW;
  const u64* stb = smaskT + (size_t)(b * NSEG + sg) * SEG;
  const u64* dmb = deadm + b * NDW + sg * NW;
  const float4* gb = gbox + (size_t)b * MAXC + sg * SEG;
  float4* kbuf = keptb + (size_t)b * SEG;
  float4* ob = (float4*)(out + (size_t)b * N_POST * 4);
  float* om = out + (size_t)B_SZ * N_POST * 4 + (size_t)b * N_POST;

  // prologue: stage group 0 directly (batched window)
  {
    u64 a = smb[t], c = smb[t + 1024];
    u64 st_ = 0; float4 bb_ = make_float4(0.f, 0.f, 0.f, 0.f);
    if (t < 64) { st_ = stb[t]; bb_ = gb[t]; }
    u64 sd_ = (t == 0) ? dmb[0] : 0;
    rowbuf[0][t] = a;
    rowbuf[0][t + 1024] = c;
    if (t < 64) { stbuf[0][t] = st_; bbox[0][t] = bb_; remv[t] = 0; }
    if (t == 0) { sdead[0] = sd_; s_stop = 0; s_nkept = meta[b * 8 + 0]; }
  }
  // issue group-1 loads into registers (staging waves), write next slot
  int p0 = t - 64, p1 = p0 + 960, p2 = p0 + 1920;
  u64 ra = 0, rc = 0, re = 0, rst = 0, rsd = 0;
  float4 rbb = make_float4(0.f, 0.f, 0.f, 0.f);
  if (wv > 0) {
    const u64* src = smb + 2048;
    ra = src[p0];
    rc = src[p1];
    if (p0 < 128) re = src[p2];
    if (p0 < 64) { rst = stb[64 + p0]; rbb = gb[64 + p0]; }
    if (t == 64) rsd = dmb[1];
  }
  __syncthreads();

  for (int g = 0; g < NW; ++g) {
    int cb = g & 1, nb = cb ^ 1;
    if (wv > 0) {
      if (g < NW - 1) {        // write group g+1 from regs (loads had 1 slot)
        rowbuf[nb][p0] = ra;
        rowbuf[nb][p1] = rc;
        if (p0 < 128) rowbuf[nb][p2] = re;
        if (p0 < 64) { stbuf[nb][p0] = rst; bbox[nb][p0] = rbb; }
        if (t == 64) sdead[nb] = rsd;
      }
      if (g < NW - 2) {        // issue group g+2 loads into regs
        const u64* src = smb + (size_t)(g + 2) * 2048;
        ra = src[p0];
        rc = src[p1];
        if (p0 < 128) re = src[p2];
        if (p0 < 64) { rst = stb[(g + 2) * 64 + p0]; rbb = gb[(g + 2) * 64 + p0]; }
        if (t == 64) rsd = dmb[g + 2];
      }
    } else {                   // wave 0: resolve group g
      int l = lane;
      u64 S = stbuf[cb][l];
      u64 remg = ((u64)remv[2 * g + 1] << 32) | remv[2 * g];
      u64 avail = ~(remg | sdead[cb]);
      u64 km = 0;
      while (avail) {
        bool al = (avail >> l) & 1;
        u64 newk = __ballot(al && (S & avail) == 0ull);
        u64 nd   = __ballot(al && (S & newk) != 0ull);
        km |= newk;
        avail &= ~(newk | nd);
      }
      int nk0 = s_nkept;
      int rem = N_POST - nk0;
      int kc = __popcll(km);
      bool stop = (kc >= rem);
      int rank = __popcll(km & ((1ull << l) - 1ull));
      if (((km >> l) & 1) && rank < rem) {
        float4 bx = bbox[cb][l];
        kbuf[nk0 + rank] = bx;
        ob[nk0 + rank] = bx;            // write output directly
        om[nk0 + rank] = 1.0f;
        klist[rank] = (u32)l;
      }
      if (l == 0) {
        int eff = stop ? rem : kc;
        s_kcnt = eff;
        s_nkept = nk0 + eff;
        if (stop) s_stop = 1;
      }
    }
    __syncthreads();
    if (s_stop) break;
    if (g < NW - 1) {
      // stage C: all 1024 threads OR kept rows' future words into remv
      int kcnt = s_kcnt;
      if (kcnt) {
        u32* rb32 = (u32*)rowbuf[cb];
        for (int i = t; i < kcnt * 64; i += 1024) {
          int kk = i >> 6, w = i & 63;
          if ((w >> 1) > g) {
            u32 v = rb32[klist[kk] * 64 + w];
            if (v) atomicOr(&remv[w], v);
          }
        }
      }
    }
    __syncthreads();
  }
  int nk = s_nkept;
  bool fin = s_stop || (sg == NSEG - 1);
  if (t == 0) { meta[b * 8 + 0] = nk; if (fin) meta[b * 8 + 1] = 1; }
  if (fin) {  // zero-pad tail of outputs
    float4 zero = make_float4(0.f, 0.f, 0.f, 0.f);
    for (int i = nk + t; i < N_POST; i += 1024) { ob[i] = zero; om[i] = 0.0f; }
  }
}

extern "C" void kernel_launch(void* const* d_in, const int* in_sizes, int n_in,
                              void* d_out, int out_size, void* d_ws, size_t ws_size,
                              hipStream_t stream)
{
  const int*   imh     = (const int*)d_in[0];
  const int*   imw     = (const int*)d_in[1];
  const float* anchors = (const float*)d_in[2];
  const float* loc     = (const float*)d_in[3];
  const float* obj     = (const float*)d_in[4];
  float* out = (float*)d_out;

  char* ws = (char*)d_ws;
  size_t off = 0;
  float4* boxes = (float4*)(ws + off); off += (size_t)B_SZ * N_ANC * 16;
  u64*    keys  = (u64*)   (ws + off); off += (size_t)B_SZ * N_ANC * 8;
  u64*    cand  = (u64*)   (ws + off); off += (size_t)B_SZ * MAXC * 8;
  float4* gbox  = (float4*)(ws + off); off += (size_t)B_SZ * MAXC * 16;
  float4* keptb = (float4*)(ws + off); off += (size_t)B_SZ * SEG * 16;
  off = (off + 255) & ~(size_t)255;
  char*   zr    = ws + off;  // zeroed region
  u32*    hist1 = (u32*)(zr);
  u32*    hist2 = (u32*)(zr + 65536);
  u32*    T1    = (u32*)(zr + 131072);
  u32*    Base1 = (u32*)(zr + 131072 + 32);
  u32*    T2    = (u32*)(zr + 131072 + 64);
  int*    meta  = (int*)(zr + 131072 + 128);                 // 8*8 ints
  u64*    deadm = (u64*)(zr + 131072 + 128 + 256);           // 12 KiB
  u32*    bcnt  = (u32*)(zr + 131072 + 128 + 256 + (size_t)B_SZ * NDW * 8);
  size_t  zr_sz = 131072 + 128 + 256 + (size_t)B_SZ * NDW * 8
                + (size_t)B_SZ * NBLK * 4;
  off += (zr_sz + 255) & ~(size_t)255;
  u64*    smask  = (u64*)(ws + off); off += (size_t)B_SZ * NSEG * SEG * NW * 8;
  u64*    smaskT = (u64*)(ws + off); off += (size_t)B_SZ * NSEG * SEG * 8;

  hipMemsetAsync(zr, 0, zr_sz, stream);
  hipMemsetAsync(cand, 0xFF, (size_t)B_SZ * MAXC * 8, stream);

  k_decode<<<dim3(NBLK, B_SZ), 256, 0, stream>>>(imh, imw, anchors, loc, obj,
                                                 boxes, keys, hist1);
  k_pick1<<<B_SZ, 256, 0, stream>>>(hist1, T1, Base1);
  k_hist2<<<dim3(36, B_SZ), 256, 0, stream>>>(keys, T1, hist2);
  k_pick2<<<B_SZ, 256, 0, stream>>>(hist2, T1, Base1, T2);

  k_count<<<dim3(NBLK, B_SZ), 256, 0, stream>>>(keys, T2, bcnt);
  k_scatter<<<dim3(NBLK, B_SZ), 256, 0, stream>>>(keys, T2, bcnt, cand);

  k_sort_tile<<<dim3(NSEG, B_SZ), 1024, 0, stream>>>(cand);
  k_merge_gather<<<dim3(MAXC / 256, B_SZ), 256, 0, stream>>>(cand, boxes, gbox, deadm);

  k_segmask01<<<dim3(1056, B_SZ), 256, 0, stream>>>(gbox, smask, smaskT);

  k_walk<<<B_SZ, 1024, 0, stream>>>(gbox, smask, smaskT, deadm, meta, keptb, out, 0);
  k_cross<<<dim3(64, B_SZ), 256, 0, stream>>>(gbox, keptb, meta, deadm, 1);
  k_walk<<<B_SZ, 1024, 0, stream>>>(gbox, smask, smaskT, deadm, meta, keptb, out, 1);
  for (int sg = 2; sg < NSEG; ++sg) {
    k_crossmask<<<dim3(592, B_SZ), 256, 0, stream>>>(gbox, keptb, meta, deadm,
                                                     smask, smaskT, sg);
    k_walk<<<B_SZ, 1024, 0, stream>>>(gbox, smask, smaskT, deadm, meta, keptb, out, sg);
  }
}